// Round 3
// baseline (3983.758 us; speedup 1.0000x reference)
//
#include <hip/hip_runtime.h>
#include <hip/hip_bf16.h>

// MILCellModel forward on MI355X. Round 3: ALL-FP32 — inputs are float32
// (reference declares jnp.float32; the round-1/2 abort is explained by reading
// fp32 cellposes as bf16 -> NaN distances -> unfilled kNN -> wild index fault).
// Output written as float32. Workspace 20.33 MB (<= measured-safe 21.3 MB).
// B=4 N=1024 E=512 D=256 H=2 C=128 FF=1024 NQ=4 NCLS=24

// ---------- block reductions (256 threads) ----------
__device__ __forceinline__ float blk_sum256(float v, float* red) {
  int t = threadIdx.x;
  red[t] = v; __syncthreads();
  #pragma unroll
  for (int off = 128; off > 0; off >>= 1) {
    if (t < off) red[t] += red[t + off];
    __syncthreads();
  }
  float r = red[0]; __syncthreads();
  return r;
}

// ---------- generic tiled GEMM ----------
// C[M,N] = act(A[M,K] @ B^T + bias), B is [N,K] row-major (PyTorch Linear W)
__global__ __launch_bounds__(256) void gemm_kernel(
    const float* __restrict__ A, int lda,
    const float* __restrict__ Bm, int ldb,
    const float* __restrict__ bias,
    float* __restrict__ C, int ldc,
    int M, int N, int K, int relu)
{
  __shared__ float As[16][65];
  __shared__ float Bs[16][65];
  int tid = threadIdx.x;
  int tx = tid & 15, ty = tid >> 4;
  int mBase = blockIdx.y * 64, nBase = blockIdx.x * 64;
  float acc[4][4] = {};

  for (int k0 = 0; k0 < K; k0 += 16) {
    {
      int m = tid >> 2, kk = (tid & 3) * 4;
      int gm = mBase + m;
      #pragma unroll
      for (int i = 0; i < 4; i++) {
        int gk = k0 + kk + i;
        As[kk + i][m] = (gm < M && gk < K) ? A[(long)gm * lda + gk] : 0.f;
      }
    }
    {
      int n = tid >> 2, kk = (tid & 3) * 4;
      int gn = nBase + n;
      #pragma unroll
      for (int i = 0; i < 4; i++) {
        int gk = k0 + kk + i;
        Bs[kk + i][n] = (gn < N && gk < K) ? Bm[(long)gn * ldb + gk] : 0.f;
      }
    }
    __syncthreads();
    #pragma unroll
    for (int kk = 0; kk < 16; kk++) {
      float a[4], b[4];
      #pragma unroll
      for (int i = 0; i < 4; i++) a[i] = As[kk][ty * 4 + i];
      #pragma unroll
      for (int j = 0; j < 4; j++) b[j] = Bs[kk][tx * 4 + j];
      #pragma unroll
      for (int i = 0; i < 4; i++)
        #pragma unroll
        for (int j = 0; j < 4; j++) acc[i][j] += a[i] * b[j];
    }
    __syncthreads();
  }
  #pragma unroll
  for (int i = 0; i < 4; i++) {
    int gm = mBase + ty * 4 + i;
    if (gm >= M) continue;
    #pragma unroll
    for (int j = 0; j < 4; j++) {
      int gn = nBase + tx * 4 + j;
      if (gn >= N) continue;
      float v = acc[i][j];
      if (bias) v += bias[gn];
      if (relu) v = fmaxf(v, 0.f);
      C[(long)gm * ldc + gn] = v;
    }
  }
}

static void gemm(hipStream_t st, const float* A, int lda, const float* B, int ldb,
                 const float* bias, float* C, int ldc, int M, int N, int K, int relu)
{
  dim3 grid((N + 63) / 64, (M + 63) / 64, 1);
  gemm_kernel<<<grid, 256, 0, st>>>(A, lda, B, ldb, bias, C, ldc, M, N, K, relu);
}

// ---------- bag stats: pn = (cellposes - mean) / (std + 1e-8) ----------
__global__ __launch_bounds__(256) void bag_stats(const float* __restrict__ cp, float* __restrict__ PN) {
  int b = blockIdx.x, tid = threadIdx.x;
  __shared__ float red[256];
  for (int c = 0; c < 2; c++) {
    float s = 0.f;
    for (int n = tid; n < 1024; n += 256) s += cp[((b << 10) + n) * 2 + c];
    float mean = blk_sum256(s, red) * (1.f / 1024.f);
    s = 0.f;
    for (int n = tid; n < 1024; n += 256) { float d = cp[((b << 10) + n) * 2 + c] - mean; s += d * d; }
    float var = blk_sum256(s, red) * (1.f / 1024.f);
    float inv = 1.f / (sqrtf(var) + 1e-8f);
    for (int n = tid; n < 1024; n += 256)
      PN[((b << 10) + n) * 2 + c] = (cp[((b << 10) + n) * 2 + c] - mean) * inv;
  }
}

// ---------- kNN: adjacency row == stable 8 nearest by (dist, index) ----------
// (local 8-NN incl self) UNION (global 7-NN excl self) == top-8 overall, always.
__global__ __launch_bounds__(256) void knn_kernel(const float* __restrict__ PN, int* __restrict__ NBR) {
  int b = blockIdx.x >> 2;
  int tbase = (blockIdx.x & 3) << 8;
  int tid = threadIdx.x;
  __shared__ float px[1024], py[1024];
  for (int i = tid; i < 1024; i += 256) {
    px[i] = PN[((b << 10) + i) * 2 + 0];
    py[i] = PN[((b << 10) + i) * 2 + 1];
  }
  __syncthreads();
  int t = tbase + tid;
  float tx = px[t], ty = py[t];
  float d8[8]; int i8[8];
  #pragma unroll
  for (int i = 0; i < 8; i++) { d8[i] = 3.4e38f; i8[i] = 0; }
  for (int s = 0; s < 1024; s++) {
    float dx = __fadd_rn(px[s], -tx), dy = __fadd_rn(py[s], -ty);
    // pin fp32 semantics (no fma contraction) to match numpy's rounding
    float d2 = __fadd_rn(__fadd_rn(__fmul_rn(dx, dx), __fmul_rn(dy, dy)), 1e-12f);
    float d = sqrtf(d2);
    if (d < d8[7]) {                              // strict compares -> index-stable like top_k
      d8[7] = d; i8[7] = s;
      #pragma unroll
      for (int p = 7; p > 0; p--) {
        if (d8[p] < d8[p - 1]) {
          float td = d8[p]; d8[p] = d8[p - 1]; d8[p - 1] = td;
          int ti = i8[p]; i8[p] = i8[p - 1]; i8[p - 1] = ti;
        }
      }
    }
  }
  #pragma unroll
  for (int i = 0; i < 8; i++) NBR[((long)((b << 10) + t)) * 8 + i] = i8[i];
}

// ---------- positional embedding MLP (per token, per coordinate) ----------
__global__ __launch_bounds__(128) void pos_embed(
    const float* __restrict__ cellp, const float* __restrict__ tab,
    const float* __restrict__ W1, const float* __restrict__ b1,
    const float* __restrict__ W2, const float* __restrict__ b2,
    float* __restrict__ X)
{
  int row = blockIdx.x;   // b*1024+n
  int c = blockIdx.y;     // coordinate
  int tid = threadIdx.x;  // 128
  __shared__ float e[128], h1[128];
  float pos = cellp[row * 2 + c];
  pos = fminf(fmaxf(pos, 0.f), 1000.f);
  int pi = (int)pos;      // trunc, matches astype(int32)
  e[tid] = tab[((long)(c * 1001 + pi)) * 128 + tid];
  __syncthreads();
  {
    const float* w1r = W1 + ((long)(c * 128 + tid)) * 128;
    float a = b1[c * 128 + tid];
    for (int i = 0; i < 128; i++) a += e[i] * w1r[i];
    h1[tid] = fmaxf(a, 0.f);
  }
  __syncthreads();
  {
    const float* w2r = W2 + ((long)(c * 128 + tid)) * 128;
    float o = b2[c * 128 + tid];
    for (int i = 0; i < 128; i++) o += h1[i] * w2r[i];
    X[(long)row * 256 + c * 128 + tid] += o;
  }
}

// ---------- GAT attention scores a_src/a_dst ----------
__global__ __launch_bounds__(256) void gat_scores(const float* __restrict__ Hh,
    const float* __restrict__ asrcW, const float* __restrict__ adstW,
    float* __restrict__ ASRC, float* __restrict__ ADST)
{
  int row = blockIdx.x, tid = threadIdx.x;
  __shared__ float red[256];
  float v = Hh[(long)row * 256 + tid];
  float s1 = v * asrcW[tid];
  float s2 = v * adstW[tid];
  red[tid] = s1; __syncthreads();
  for (int off = 64; off > 0; off >>= 1) { if ((tid & 127) < off) red[tid] += red[tid + off]; __syncthreads(); }
  if ((tid & 127) == 0) ASRC[row * 2 + (tid >> 7)] = red[tid];
  __syncthreads();
  red[tid] = s2; __syncthreads();
  for (int off = 64; off > 0; off >>= 1) { if ((tid & 127) < off) red[tid] += red[tid + off]; __syncthreads(); }
  if ((tid & 127) == 0) ADST[row * 2 + (tid >> 7)] = red[tid];
}

// ---------- GAT aggregate (8 neighbors) + bias + residual + LayerNorm ----------
__global__ __launch_bounds__(256) void gat_aggr_ln(
    const float* __restrict__ Hh, const float* __restrict__ ASRC, const float* __restrict__ ADST,
    const int* __restrict__ NBR, const float* __restrict__ gbias,
    const float* __restrict__ lng, const float* __restrict__ lnb,
    float* __restrict__ X)
{
  int row = blockIdx.x, tid = threadIdx.x;
  int b = row >> 10;
  __shared__ int nb[8];
  __shared__ float w[2][8];
  __shared__ float red[256];
  if (tid < 8) {
    int v = NBR[(long)row * 8 + tid];
    nb[tid] = min(max(v, 0), 1023);  // defensive: garbage -> clean fail, not fault
  }
  __syncthreads();
  if (tid < 16) {
    int i = tid & 7, h = tid >> 3;
    float e = ADST[row * 2 + h] + ASRC[((b << 10) + nb[i]) * 2 + h];
    w[h][i] = (e >= 0.f) ? e : 0.2f * e;  // leaky_relu 0.2
  }
  __syncthreads();
  if (tid < 2) {  // softmax over 8 neighbors (masked entries underflow to exact 0 in ref)
    float m = -3.4e38f;
    for (int i = 0; i < 8; i++) m = fmaxf(m, w[tid][i]);
    float s = 0.f;
    for (int i = 0; i < 8; i++) { float e = expf(w[tid][i] - m); w[tid][i] = e; s += e; }
    float inv = 1.f / s;
    for (int i = 0; i < 8; i++) w[tid][i] *= inv;
  }
  __syncthreads();
  int h = tid >> 7, c = tid & 127;
  float acc = 0.f;
  #pragma unroll
  for (int i = 0; i < 8; i++)
    acc += w[h][i] * Hh[((long)((b << 10) + nb[i])) * 256 + h * 128 + c];
  float v = acc + gbias[tid] + X[(long)row * 256 + tid];
  float mean = blk_sum256(v, red) * (1.f / 256.f);
  float dv = v - mean;
  float var = blk_sum256(dv * dv, red) * (1.f / 256.f);
  X[(long)row * 256 + tid] = dv * rsqrtf(var + 1e-5f) * lng[tid] + lnb[tid];
}

// ---------- residual + LayerNorm (D = 256 or 1024) ----------
__global__ __launch_bounds__(256) void add_ln(const float* __restrict__ res,
    const float* __restrict__ Yv, const float* __restrict__ g, const float* __restrict__ b,
    float* __restrict__ out, int D)
{
  int row = blockIdx.x, tid = threadIdx.x;
  __shared__ float red[256];
  float vals[4];
  int cnt = D >> 8;
  float s = 0.f;
  #pragma unroll
  for (int i = 0; i < 4; i++) {
    if (i < cnt) {
      int d = tid + (i << 8);
      float v = Yv[(long)row * D + d];
      if (res) v += res[(long)row * D + d];
      vals[i] = v; s += v;
    }
  }
  float mean = blk_sum256(s, red) / (float)D;
  s = 0.f;
  #pragma unroll
  for (int i = 0; i < 4; i++)
    if (i < cnt) { float dv = vals[i] - mean; s += dv * dv; }
  float var = blk_sum256(s, red) / (float)D;
  float rstd = rsqrtf(var + 1e-5f);
  #pragma unroll
  for (int i = 0; i < 4; i++)
    if (i < cnt) {
      int d = tid + (i << 8);
      out[(long)row * D + d] = (vals[i] - mean) * rstd * g[d] + b[d];
    }
}

// ---------- fused flash attention (online softmax, 32q x 32k tiles) ----------
// QKV: fp32 [B*N, 768] rows (q|k|v each 256 = H*C). One block per (b,h,qtile32).
// Output O: fp32 [B*N, 256] at col h*128.
__global__ __launch_bounds__(256) void flash_attn(const float* __restrict__ QKV, float* __restrict__ O)
{
  const float scale = 0.08838834764831845f;
  int blk = blockIdx.x;
  int qt = blk & 31, bh = blk >> 5;
  int b = bh >> 1, h = bh & 1;
  const float* base = QKV + (long)b * 1024 * 768 + h * 128;

  __shared__ float Qs[32][129];
  __shared__ float Ks[32][129];
  __shared__ float Vs[32][129];
  __shared__ float Ps[32][32];
  __shared__ float ms[32], ls[32], as_[32];

  int tid = threadIdx.x;
  for (int idx = tid; idx < 4096; idx += 256) {
    int q = idx >> 7, c = idx & 127;
    Qs[q][c] = base[(long)(qt * 32 + q) * 768 + c];
  }
  if (tid < 32) { ms[tid] = -3.4e38f; ls[tid] = 0.f; }
  float Oacc[16];
  #pragma unroll
  for (int i = 0; i < 16; i++) Oacc[i] = 0.f;

  int q = tid >> 3;           // 0..31 (8 threads per q-row)
  int k0 = tid & 7;
  int cb = (tid & 7) * 16;    // 16 output cols per thread

  for (int kt = 0; kt < 32; kt++) {
    __syncthreads();
    for (int idx = tid; idx < 4096; idx += 256) {
      int k = idx >> 7, c = idx & 127;
      long r = (long)(kt * 32 + k) * 768;
      Ks[k][c] = base[r + 256 + c];
      Vs[k][c] = base[r + 512 + c];
    }
    __syncthreads();
    float d0 = 0.f, d1 = 0.f, d2 = 0.f, d3 = 0.f;
    for (int c = 0; c < 128; c++) {
      float qv = Qs[q][c];
      d0 += qv * Ks[k0][c];
      d1 += qv * Ks[k0 + 8][c];
      d2 += qv * Ks[k0 + 16][c];
      d3 += qv * Ks[k0 + 24][c];
    }
    Ps[q][k0] = d0 * scale; Ps[q][k0 + 8] = d1 * scale;
    Ps[q][k0 + 16] = d2 * scale; Ps[q][k0 + 24] = d3 * scale;
    __syncthreads();
    if (tid < 32) {
      float m0 = ms[tid], mx = m0;
      for (int k = 0; k < 32; k++) mx = fmaxf(mx, Ps[tid][k]);
      float al = expf(m0 - mx);
      float s = ls[tid] * al;
      for (int k = 0; k < 32; k++) { float p = expf(Ps[tid][k] - mx); Ps[tid][k] = p; s += p; }
      ms[tid] = mx; ls[tid] = s; as_[tid] = al;
    }
    __syncthreads();
    float al = as_[q];
    #pragma unroll
    for (int i = 0; i < 16; i++) Oacc[i] *= al;
    for (int k = 0; k < 32; k++) {
      float p = Ps[q][k];
      #pragma unroll
      for (int i = 0; i < 16; i++) Oacc[i] += p * Vs[k][cb + i];
    }
  }
  float inv = 1.f / ls[q];
  long row = (long)(b * 1024 + qt * 32 + q);
  #pragma unroll
  for (int i = 0; i < 16; i++)
    O[row * 256 + h * 128 + cb + i] = Oacc[i] * inv;
}

// ---------- sparse pooling attention (learned queries) ----------
__global__ __launch_bounds__(128) void pool_attn(
    const float* __restrict__ qe, const float* __restrict__ pinW, const float* __restrict__ pinB,
    const float* __restrict__ srand, const float* __restrict__ KV, float* __restrict__ ATTP)
{
  int id = blockIdx.x;  // b*8 + nq*2 + h
  int h = id & 1, nq = (id >> 1) & 3, b = id >> 3;
  int tid = threadIdx.x;  // 128
  __shared__ float qs[128];
  __shared__ float lg[1024];
  __shared__ float red[128];
  {
    float a = pinB[h * 128 + tid];
    const float* wr = pinW + ((long)(h * 128 + tid)) * 256;  // Wq rows 0..255
    const float* qr = qe + nq * 256;
    for (int i = 0; i < 256; i++) a += qr[i] * wr[i];
    qs[tid] = a;
  }
  __syncthreads();
  const float scale = 0.08838834764831845f;
  for (int s = tid; s < 1024; s += 128) {
    const float* kr = KV + ((long)((b << 10) + s)) * 512 + h * 128;
    float d = 0.f;
    for (int c2 = 0; c2 < 128; c2++) d += qs[c2] * kr[c2];
    float mv = (srand[nq * 1024 + s] < 0.3f) ? 0.f : -1e9f;
    lg[s] = d * scale + mv;
  }
  __syncthreads();
  float m = -3.4e38f;
  for (int s = tid; s < 1024; s += 128) m = fmaxf(m, lg[s]);
  red[tid] = m; __syncthreads();
  for (int off = 64; off > 0; off >>= 1) { if (tid < off) red[tid] = fmaxf(red[tid], red[tid + off]); __syncthreads(); }
  m = red[0]; __syncthreads();
  float s0 = 0.f;
  for (int s = tid; s < 1024; s += 128) { float e = expf(lg[s] - m); lg[s] = e; s0 += e; }
  red[tid] = s0; __syncthreads();
  for (int off = 64; off > 0; off >>= 1) { if (tid < off) red[tid] += red[tid + off]; __syncthreads(); }
  float denom = red[0]; __syncthreads();
  float o = 0.f;
  for (int s = 0; s < 1024; s++) o += lg[s] * KV[((long)((b << 10) + s)) * 512 + 256 + h * 128 + tid];
  ATTP[(b * 4 + nq) * 256 + h * 128 + tid] = o / denom;
}

// ---------- combined = [mean over N of x  |  pooled_att flat] ----------
__global__ __launch_bounds__(256) void combined_kernel(const float* __restrict__ X,
    const float* __restrict__ ATTO, float* __restrict__ CMB)
{
  int b = blockIdx.x, d = threadIdx.x;
  float s = 0.f;
  for (int n = 0; n < 1024; n++) s += X[((long)((b << 10) + n)) * 256 + d];
  CMB[b * 1280 + d] = s * (1.f / 1024.f);
  for (int q = 0; q < 4; q++)
    CMB[b * 1280 + 256 + q * 256 + d] = ATTO[(b * 4 + q) * 256 + d];
}

__global__ void store_out(const float* __restrict__ src, float* __restrict__ dst, int n) {
  int i = blockIdx.x * blockDim.x + threadIdx.x;
  if (i < n) dst[i] = src[i];
}

__global__ void fill_out_zero(float* __restrict__ dst, int n) {
  int i = blockIdx.x * blockDim.x + threadIdx.x;
  if (i < n) dst[i] = 0.f;
}

extern "C" void kernel_launch(void* const* d_in, const int* in_sizes, int n_in,
                              void* d_out, int out_size, void* d_ws, size_t ws_size,
                              hipStream_t stream)
{
  const float* inp      = (const float*)d_in[0];
  const float* cellp    = (const float*)d_in[1];
  const float* srand    = (const float*)d_in[2];
  const float* emb_W    = (const float*)d_in[3];
  const float* emb_b    = (const float*)d_in[4];
  const float* pe_tab   = (const float*)d_in[5];
  const float* pe_W1    = (const float*)d_in[6];
  const float* pe_b1    = (const float*)d_in[7];
  const float* pe_W2    = (const float*)d_in[8];
  const float* pe_b2    = (const float*)d_in[9];
  const float* gat_W    = (const float*)d_in[10];
  const float* gat_asrc = (const float*)d_in[11];
  const float* gat_adst = (const float*)d_in[12];
  const float* gat_b    = (const float*)d_in[13];
  const float* ln_g     = (const float*)d_in[14];
  const float* ln_b     = (const float*)d_in[15];
  const float* qkv_W    = (const float*)d_in[16];
  const float* qkv_b    = (const float*)d_in[17];
  const float* out_W    = (const float*)d_in[18];
  const float* out_b    = (const float*)d_in[19];
  const float* ff1_W    = (const float*)d_in[20];
  const float* ff1_b    = (const float*)d_in[21];
  const float* ff2_W    = (const float*)d_in[22];
  const float* ff2_b    = (const float*)d_in[23];
  const float* ln1_g    = (const float*)d_in[24];
  const float* ln1_b    = (const float*)d_in[25];
  const float* ln2_g    = (const float*)d_in[26];
  const float* ln2_b    = (const float*)d_in[27];
  const float* q_emb    = (const float*)d_in[28];
  const float* pin_W    = (const float*)d_in[29];
  const float* pin_b    = (const float*)d_in[30];
  const float* pout_W   = (const float*)d_in[31];
  const float* pout_b   = (const float*)d_in[32];
  const float* m1_W     = (const float*)d_in[33];
  const float* m1_b     = (const float*)d_in[34];
  const float* mln1_g   = (const float*)d_in[35];
  const float* mln1_b   = (const float*)d_in[36];
  const float* m2_W     = (const float*)d_in[37];
  const float* m2_b     = (const float*)d_in[38];
  const float* mln2_g   = (const float*)d_in[39];
  const float* mln2_b   = (const float*)d_in[40];
  const float* m3_W     = (const float*)d_in[41];
  const float* m3_b     = (const float*)d_in[42];
  const float* c1_W     = (const float*)d_in[43];
  const float* c1_b     = (const float*)d_in[44];
  const float* c2_W     = (const float*)d_in[45];
  const float* c2_b     = (const float*)d_in[46];
  const float* c3_W     = (const float*)d_in[47];
  const float* c3_b     = (const float*)d_in[48];
  const float* c4_W     = (const float*)d_in[49];
  const float* c4_b     = (const float*)d_in[50];
  // d_in[51] = masks (int32, all ones) -- no effect, unused.
  (void)in_sizes; (void)n_in;

  // ---- workspace layout (20.33 MB fp32) ----
  float* fws = (float*)d_ws;
  size_t off = 0;
  auto alloc = [&](size_t n) { float* p = fws + off; off += n; return p; };
  float* PN   = alloc(4096 * 2);
  float* AS   = alloc(4096 * 2);
  float* AD   = alloc(4096 * 2);
  float* ATTP = alloc(16 * 256);
  float* ATTO = alloc(16 * 256);
  float* CMB  = alloc(4 * 1280);
  float* Ha   = alloc(4 * 1024);
  float* Hb   = alloc(4 * 1024);
  float* Hc   = alloc(4 * 1032);
  float* Hd   = alloc(4 * 512);
  float* He   = alloc(4 * 256);
  float* Hf   = alloc(4 * 24);
  int*   NBR  = (int*)alloc(4096 * 8);
  float* X    = alloc(4096 * 256);      // residual stream
  float* F1   = alloc(4096 * 256);      // GAT h / attention out
  float* R    = alloc(4096 * 768);      // shared region: Y(qkv/poolKV) aliases F2+FFB
  float* Y    = R;                      // [4096,768] qkv  OR  [4096,512] pool-KV
  float* F2   = R;                      // [4096,256] pre-LN temp (written after Y dead)
  float* FFB  = R + 4096 * 256;         // [1024,1024] FF1 chunk (written after Y dead)
  size_t need = off * 4;
  if (ws_size < need) {  // diagnostic fallback: clean absmax failure, no fault
    fill_out_zero<<<1, 128, 0, stream>>>((float*)d_out, out_size);
    return;
  }

  // ---- graph construction ----
  bag_stats<<<4, 256, 0, stream>>>(cellp, PN);
  knn_kernel<<<16, 256, 0, stream>>>(PN, NBR);

  // ---- embedding + positional MLP ----
  gemm(stream, inp, 512, emb_W, 512, emb_b, X, 256, 4096, 256, 512, 0);
  pos_embed<<<dim3(4096, 2), 128, 0, stream>>>(cellp, pe_tab, pe_W1, pe_b1, pe_W2, pe_b2, X);

  // ---- 2x GAT ----
  for (int l = 0; l < 2; l++) {
    gemm(stream, X, 256, gat_W + l * 65536, 256, nullptr, F1, 256, 4096, 256, 256, 0);
    gat_scores<<<4096, 256, 0, stream>>>(F1, gat_asrc + l * 256, gat_adst + l * 256, AS, AD);
    gat_aggr_ln<<<4096, 256, 0, stream>>>(F1, AS, AD, NBR, gat_b + l * 256, ln_g, ln_b, X);
  }

  // ---- 2x Transformer encoder layer (post-norm) ----
  for (int l = 0; l < 2; l++) {
    gemm(stream, X, 256, qkv_W + (long)l * 768 * 256, 256, qkv_b + l * 768, Y, 768,
         4096, 768, 256, 0);
    flash_attn<<<256, 256, 0, stream>>>(Y, F1);           // Y dead after this
    gemm(stream, F1, 256, out_W + l * 65536, 256, out_b + l * 256, F2, 256, 4096, 256, 256, 0);
    add_ln<<<4096, 256, 0, stream>>>(X, F2, ln1_g + l * 256, ln1_b + l * 256, X, 256);
    for (int c4 = 0; c4 < 4; c4++) {  // FFN in 1024-row chunks
      gemm(stream, X + (long)c4 * 1024 * 256, 256, ff1_W + l * 262144, 256, ff1_b + l * 1024,
           FFB, 1024, 1024, 1024, 256, 1);
      gemm(stream, FFB, 1024, ff2_W + l * 262144, 1024, ff2_b + l * 256,
           F2 + (long)c4 * 1024 * 256, 256, 1024, 256, 1024, 0);
    }
    add_ln<<<4096, 256, 0, stream>>>(X, F2, ln2_g + l * 256, ln2_b + l * 256, X, 256);
  }

  // ---- final LN ----
  add_ln<<<4096, 256, 0, stream>>>((const float*)nullptr, X, ln_g, ln_b, X, 256);

  // ---- pooling: KV projection + sparse learned-query attention ----
  gemm(stream, X, 256, pin_W + 65536, 256, pin_b + 256, Y, 512, 4096, 512, 256, 0);
  pool_attn<<<32, 128, 0, stream>>>(q_emb, pin_W, pin_b, srand, Y, ATTP);
  gemm(stream, ATTP, 256, pout_W, 256, pout_b, ATTO, 256, 16, 256, 256, 0);
  combined_kernel<<<4, 256, 0, stream>>>(X, ATTO, CMB);

  // ---- MLP head ----
  gemm(stream, CMB, 1280, m1_W, 1280, m1_b, Ha, 1024, 4, 1024, 1280, 1);
  add_ln<<<4, 256, 0, stream>>>((const float*)nullptr, Ha, mln1_g, mln1_b, Ha, 1024);
  gemm(stream, Ha, 1024, m2_W, 1024, m2_b, Hb, 1024, 4, 1024, 1024, 1);
  add_ln<<<4, 256, 0, stream>>>((const float*)nullptr, Hb, mln2_g, mln2_b, Hb, 1024);
  gemm(stream, Hb, 1024, m3_W, 1024, m3_b, Ha, 1024, 4, 1024, 1024, 0);
  gemm(stream, Ha, 1024, c1_W, 1024, c1_b, Hc, 1032, 4, 1032, 1024, 1);
  gemm(stream, Hc, 1032, c2_W, 1032, c2_b, Hd, 512, 4, 512, 1032, 1);
  gemm(stream, Hd, 512, c3_W, 512, c3_b, He, 256, 4, 256, 512, 1);
  gemm(stream, He, 256, c4_W, 256, c4_b, Hf, 24, 4, 24, 256, 0);
  store_out<<<1, 128, 0, stream>>>(Hf, (float*)d_out, out_size);
}

// Round 4
// 2118.578 us; speedup vs baseline: 1.8804x; 1.8804x over previous
//
#include <hip/hip_runtime.h>
#include <hip/hip_bf16.h>

// MILCellModel forward on MI355X. Round 4: bf16 MFMA for the 7 big GEMMs
// (fp32 accumulate, fp32 residual/LN/softmax), flash attention with bf16 I/O
// + conflict-free LDS layout. Head MLP and small ops stay fp32.
// B=4 N=1024 E=512 D=256 H=2 C=128 FF=1024 NQ=4 NCLS=24

typedef __bf16 bf16x8 __attribute__((ext_vector_type(8)));
typedef float  f32x4  __attribute__((ext_vector_type(4)));

__device__ __forceinline__ ushort f2b(float f) {
  __hip_bfloat16 h = __float2bfloat16(f);
  return *(ushort*)&h;
}
__device__ __forceinline__ float b2f(ushort u) {
  union { unsigned i; float f; } v; v.i = ((unsigned)u) << 16; return v.f;
}
__device__ __forceinline__ float b2f_lo(unsigned u) { union { unsigned i; float f; } v; v.i = u << 16; return v.f; }
__device__ __forceinline__ float b2f_hi(unsigned u) { union { unsigned i; float f; } v; v.i = u & 0xffff0000u; return v.f; }

// ---------- block reductions (256 threads) ----------
__device__ __forceinline__ float blk_sum256(float v, float* red) {
  int t = threadIdx.x;
  red[t] = v; __syncthreads();
  #pragma unroll
  for (int off = 128; off > 0; off >>= 1) {
    if (t < off) red[t] += red[t + off];
    __syncthreads();
  }
  float r = red[0]; __syncthreads();
  return r;
}

// ---------- fp32 -> bf16 convert (n multiple of 4) ----------
__global__ __launch_bounds__(256) void cvt_f2b(const float* __restrict__ src,
                                               ushort* __restrict__ dst, int n) {
  int i = (blockIdx.x * 256 + threadIdx.x) * 4;
  if (i >= n) return;
  float4 v = *(const float4*)(src + i);
  ushort4 o;
  o.x = f2b(v.x); o.y = f2b(v.y); o.z = f2b(v.z); o.w = f2b(v.w);
  *(ushort4*)(dst + i) = o;
}

// ---------- bf16 MFMA GEMM: C[M,N] = act(A[M,K] @ B^T + bias) ----------
// A bf16 [M,K] row-major, B bf16 [N,K] row-major. Tile 64x128, BK=32.
// M % 64 == 0, N % 128 == 0, K % 32 == 0 (all call sites satisfy this).
template<typename CT>
__global__ __launch_bounds__(256) void mfma_gemm(
    const ushort* __restrict__ A, int lda,
    const ushort* __restrict__ Bw, int ldb,
    const float* __restrict__ bias,
    CT* __restrict__ C, int ldc, int K, int relu)
{
  __shared__ ushort As[64][40];    // +8 pad: conflict-free b128 frag reads
  __shared__ ushort Bs[128][40];
  int tid = threadIdx.x;
  int lane = tid & 63, wave = tid >> 6;
  int wm = wave >> 1, wn = wave & 1;      // 2x2 waves; wave tile = 32x64
  int quad = lane >> 4, l16 = lane & 15;
  long mBase = blockIdx.y * 64, nBase = blockIdx.x * 128;

  f32x4 zero4 = {0.f, 0.f, 0.f, 0.f};
  f32x4 acc[2][4];
  #pragma unroll
  for (int i = 0; i < 2; i++)
    #pragma unroll
    for (int j = 0; j < 4; j++) acc[i][j] = zero4;

  for (int k0 = 0; k0 < K; k0 += 32) {
    {
      int r = tid >> 2, sg = (tid & 3) * 8;          // 64 rows x 32 cols
      *(uint4*)&As[r][sg] = *(const uint4*)(A + (mBase + r) * lda + k0 + sg);
    }
    #pragma unroll
    for (int p = 0; p < 2; p++) {
      int idx = p * 256 + tid;
      int r = idx >> 2, sg = (idx & 3) * 8;          // 128 rows x 32 cols
      *(uint4*)&Bs[r][sg] = *(const uint4*)(Bw + (nBase + r) * ldb + k0 + sg);
    }
    __syncthreads();
    bf16x8 af[2], bfr[4];
    #pragma unroll
    for (int i = 0; i < 2; i++)
      af[i] = *(const bf16x8*)&As[wm * 32 + i * 16 + l16][quad * 8];
    #pragma unroll
    for (int j = 0; j < 4; j++)
      bfr[j] = *(const bf16x8*)&Bs[wn * 64 + j * 16 + l16][quad * 8];
    #pragma unroll
    for (int i = 0; i < 2; i++)
      #pragma unroll
      for (int j = 0; j < 4; j++)
        acc[i][j] = __builtin_amdgcn_mfma_f32_16x16x32_bf16(af[i], bfr[j], acc[i][j], 0, 0, 0);
    __syncthreads();
  }
  // C/D layout: col = lane&15, row = quad*4 + reg
  #pragma unroll
  for (int i = 0; i < 2; i++) {
    #pragma unroll
    for (int j = 0; j < 4; j++) {
      long col = nBase + wn * 64 + j * 16 + l16;
      float bv = bias ? bias[col] : 0.f;
      #pragma unroll
      for (int r = 0; r < 4; r++) {
        long row = mBase + wm * 32 + i * 16 + quad * 4 + r;
        float v = acc[i][j][r] + bv;
        if (relu) v = fmaxf(v, 0.f);
        if constexpr (sizeof(CT) == 2) C[row * ldc + col] = f2b(v);
        else                           C[row * ldc + col] = v;
      }
    }
  }
}

template<typename CT>
static void mgemm(hipStream_t st, const ushort* A, int lda, const ushort* B, int ldb,
                  const float* bias, CT* C, int ldc, int M, int N, int K, int relu) {
  dim3 grid(N / 128, M / 64);
  mfma_gemm<CT><<<grid, 256, 0, st>>>(A, lda, B, ldb, bias, C, ldc, K, relu);
}

// ---------- fp32 tiled GEMM (small/head matmuls) ----------
__global__ __launch_bounds__(256) void gemm_kernel(
    const float* __restrict__ A, int lda,
    const float* __restrict__ Bm, int ldb,
    const float* __restrict__ bias,
    float* __restrict__ C, int ldc,
    int M, int N, int K, int relu)
{
  __shared__ float As[16][65];
  __shared__ float Bs[16][65];
  int tid = threadIdx.x;
  int tx = tid & 15, ty = tid >> 4;
  int mBase = blockIdx.y * 64, nBase = blockIdx.x * 64;
  float acc[4][4] = {};

  for (int k0 = 0; k0 < K; k0 += 16) {
    {
      int m = tid >> 2, kk = (tid & 3) * 4;
      int gm = mBase + m;
      #pragma unroll
      for (int i = 0; i < 4; i++) {
        int gk = k0 + kk + i;
        As[kk + i][m] = (gm < M && gk < K) ? A[(long)gm * lda + gk] : 0.f;
      }
    }
    {
      int n = tid >> 2, kk = (tid & 3) * 4;
      int gn = nBase + n;
      #pragma unroll
      for (int i = 0; i < 4; i++) {
        int gk = k0 + kk + i;
        Bs[kk + i][n] = (gn < N && gk < K) ? Bm[(long)gn * ldb + gk] : 0.f;
      }
    }
    __syncthreads();
    #pragma unroll
    for (int kk = 0; kk < 16; kk++) {
      float a[4], b[4];
      #pragma unroll
      for (int i = 0; i < 4; i++) a[i] = As[kk][ty * 4 + i];
      #pragma unroll
      for (int j = 0; j < 4; j++) b[j] = Bs[kk][tx * 4 + j];
      #pragma unroll
      for (int i = 0; i < 4; i++)
        #pragma unroll
        for (int j = 0; j < 4; j++) acc[i][j] += a[i] * b[j];
    }
    __syncthreads();
  }
  #pragma unroll
  for (int i = 0; i < 4; i++) {
    int gm = mBase + ty * 4 + i;
    if (gm >= M) continue;
    #pragma unroll
    for (int j = 0; j < 4; j++) {
      int gn = nBase + tx * 4 + j;
      if (gn >= N) continue;
      float v = acc[i][j];
      if (bias) v += bias[gn];
      if (relu) v = fmaxf(v, 0.f);
      C[(long)gm * ldc + gn] = v;
    }
  }
}

static void gemm(hipStream_t st, const float* A, int lda, const float* B, int ldb,
                 const float* bias, float* C, int ldc, int M, int N, int K, int relu)
{
  dim3 grid((N + 63) / 64, (M + 63) / 64, 1);
  gemm_kernel<<<grid, 256, 0, st>>>(A, lda, B, ldb, bias, C, ldc, M, N, K, relu);
}

// ---------- bag stats ----------
__global__ __launch_bounds__(256) void bag_stats(const float* __restrict__ cp, float* __restrict__ PN) {
  int b = blockIdx.x, tid = threadIdx.x;
  __shared__ float red[256];
  for (int c = 0; c < 2; c++) {
    float s = 0.f;
    for (int n = tid; n < 1024; n += 256) s += cp[((b << 10) + n) * 2 + c];
    float mean = blk_sum256(s, red) * (1.f / 1024.f);
    s = 0.f;
    for (int n = tid; n < 1024; n += 256) { float d = cp[((b << 10) + n) * 2 + c] - mean; s += d * d; }
    float var = blk_sum256(s, red) * (1.f / 1024.f);
    float inv = 1.f / (sqrtf(var) + 1e-8f);
    for (int n = tid; n < 1024; n += 256)
      PN[((b << 10) + n) * 2 + c] = (cp[((b << 10) + n) * 2 + c] - mean) * inv;
  }
}

// ---------- kNN (stable top-8 by (dist, index)) ----------
__global__ __launch_bounds__(256) void knn_kernel(const float* __restrict__ PN, int* __restrict__ NBR) {
  int b = blockIdx.x >> 2;
  int tbase = (blockIdx.x & 3) << 8;
  int tid = threadIdx.x;
  __shared__ float px[1024], py[1024];
  for (int i = tid; i < 1024; i += 256) {
    px[i] = PN[((b << 10) + i) * 2 + 0];
    py[i] = PN[((b << 10) + i) * 2 + 1];
  }
  __syncthreads();
  int t = tbase + tid;
  float tx = px[t], ty = py[t];
  float d8[8]; int i8[8];
  #pragma unroll
  for (int i = 0; i < 8; i++) { d8[i] = 3.4e38f; i8[i] = 0; }
  for (int s = 0; s < 1024; s++) {
    float dx = __fadd_rn(px[s], -tx), dy = __fadd_rn(py[s], -ty);
    float d2 = __fadd_rn(__fadd_rn(__fmul_rn(dx, dx), __fmul_rn(dy, dy)), 1e-12f);
    float d = sqrtf(d2);
    if (d < d8[7]) {
      d8[7] = d; i8[7] = s;
      #pragma unroll
      for (int p = 7; p > 0; p--) {
        if (d8[p] < d8[p - 1]) {
          float td = d8[p]; d8[p] = d8[p - 1]; d8[p - 1] = td;
          int ti = i8[p]; i8[p] = i8[p - 1]; i8[p - 1] = ti;
        }
      }
    }
  }
  #pragma unroll
  for (int i = 0; i < 8; i++) NBR[((long)((b << 10) + t)) * 8 + i] = i8[i];
}

// ---------- positional embedding MLP ----------
__global__ __launch_bounds__(128) void pos_embed(
    const float* __restrict__ cellp, const float* __restrict__ tab,
    const float* __restrict__ W1, const float* __restrict__ b1,
    const float* __restrict__ W2, const float* __restrict__ b2,
    float* __restrict__ X)
{
  int row = blockIdx.x, c = blockIdx.y, tid = threadIdx.x;
  __shared__ float e[128], h1[128];
  float pos = cellp[row * 2 + c];
  pos = fminf(fmaxf(pos, 0.f), 1000.f);
  int pi = (int)pos;
  e[tid] = tab[((long)(c * 1001 + pi)) * 128 + tid];
  __syncthreads();
  {
    const float* w1r = W1 + ((long)(c * 128 + tid)) * 128;
    float a = b1[c * 128 + tid];
    for (int i = 0; i < 128; i++) a += e[i] * w1r[i];
    h1[tid] = fmaxf(a, 0.f);
  }
  __syncthreads();
  {
    const float* w2r = W2 + ((long)(c * 128 + tid)) * 128;
    float o = b2[c * 128 + tid];
    for (int i = 0; i < 128; i++) o += h1[i] * w2r[i];
    X[(long)row * 256 + c * 128 + tid] += o;
  }
}

// ---------- GAT scores ----------
__global__ __launch_bounds__(256) void gat_scores(const float* __restrict__ Hh,
    const float* __restrict__ asrcW, const float* __restrict__ adstW,
    float* __restrict__ ASRC, float* __restrict__ ADST)
{
  int row = blockIdx.x, tid = threadIdx.x;
  __shared__ float red[256];
  float v = Hh[(long)row * 256 + tid];
  float s1 = v * asrcW[tid];
  float s2 = v * adstW[tid];
  red[tid] = s1; __syncthreads();
  for (int off = 64; off > 0; off >>= 1) { if ((tid & 127) < off) red[tid] += red[tid + off]; __syncthreads(); }
  if ((tid & 127) == 0) ASRC[row * 2 + (tid >> 7)] = red[tid];
  __syncthreads();
  red[tid] = s2; __syncthreads();
  for (int off = 64; off > 0; off >>= 1) { if ((tid & 127) < off) red[tid] += red[tid + off]; __syncthreads(); }
  if ((tid & 127) == 0) ADST[row * 2 + (tid >> 7)] = red[tid];
}

// ---------- GAT aggregate + residual + LN (emits fp32 X and bf16 Xb) ----------
__global__ __launch_bounds__(256) void gat_aggr_ln(
    const float* __restrict__ Hh, const float* __restrict__ ASRC, const float* __restrict__ ADST,
    const int* __restrict__ NBR, const float* __restrict__ gbias,
    const float* __restrict__ lng, const float* __restrict__ lnb,
    float* __restrict__ X, ushort* __restrict__ Xb)
{
  int row = blockIdx.x, tid = threadIdx.x;
  int b = row >> 10;
  __shared__ int nb[8];
  __shared__ float w[2][8];
  __shared__ float red[256];
  if (tid < 8) {
    int v = NBR[(long)row * 8 + tid];
    nb[tid] = min(max(v, 0), 1023);
  }
  __syncthreads();
  if (tid < 16) {
    int i = tid & 7, h = tid >> 3;
    float e = ADST[row * 2 + h] + ASRC[((b << 10) + nb[i]) * 2 + h];
    w[h][i] = (e >= 0.f) ? e : 0.2f * e;
  }
  __syncthreads();
  if (tid < 2) {
    float m = -3.4e38f;
    for (int i = 0; i < 8; i++) m = fmaxf(m, w[tid][i]);
    float s = 0.f;
    for (int i = 0; i < 8; i++) { float e = expf(w[tid][i] - m); w[tid][i] = e; s += e; }
    float inv = 1.f / s;
    for (int i = 0; i < 8; i++) w[tid][i] *= inv;
  }
  __syncthreads();
  int h = tid >> 7, c = tid & 127;
  float acc = 0.f;
  #pragma unroll
  for (int i = 0; i < 8; i++)
    acc += w[h][i] * Hh[((long)((b << 10) + nb[i])) * 256 + h * 128 + c];
  float v = acc + gbias[tid] + X[(long)row * 256 + tid];
  float mean = blk_sum256(v, red) * (1.f / 256.f);
  float dv = v - mean;
  float var = blk_sum256(dv * dv, red) * (1.f / 256.f);
  float o = dv * rsqrtf(var + 1e-5f) * lng[tid] + lnb[tid];
  X[(long)row * 256 + tid] = o;
  Xb[(long)row * 256 + tid] = f2b(o);
}

// ---------- residual + LayerNorm (optional bf16 shadow) ----------
__global__ __launch_bounds__(256) void add_ln(const float* __restrict__ res,
    const float* __restrict__ Yv, const float* __restrict__ g, const float* __restrict__ b,
    float* __restrict__ out, ushort* __restrict__ outb, int D)
{
  int row = blockIdx.x, tid = threadIdx.x;
  __shared__ float red[256];
  float vals[4];
  int cnt = D >> 8;
  float s = 0.f;
  #pragma unroll
  for (int i = 0; i < 4; i++) {
    if (i < cnt) {
      int d = tid + (i << 8);
      float v = Yv[(long)row * D + d];
      if (res) v += res[(long)row * D + d];
      vals[i] = v; s += v;
    }
  }
  float mean = blk_sum256(s, red) / (float)D;
  s = 0.f;
  #pragma unroll
  for (int i = 0; i < 4; i++)
    if (i < cnt) { float dv = vals[i] - mean; s += dv * dv; }
  float var = blk_sum256(s, red) / (float)D;
  float rstd = rsqrtf(var + 1e-5f);
  #pragma unroll
  for (int i = 0; i < 4; i++)
    if (i < cnt) {
      int d = tid + (i << 8);
      float o = (vals[i] - mean) * rstd * g[d] + b[d];
      out[(long)row * D + d] = o;
      if (outb) outb[(long)row * D + d] = f2b(o);
    }
}

// ---------- flash attention: bf16 QKV in, bf16 O out, fp32 math ----------
// QKV [B*N,768] bf16 (q|k|v). grid = (b,h,qtile32) = 256 blocks x 256 thr.
__global__ __launch_bounds__(256) void flash_attn(const ushort* __restrict__ QKV,
                                                  ushort* __restrict__ O)
{
  const float scale = 0.08838834764831845f;
  int blk = blockIdx.x;
  int qt = blk & 31, bh = blk >> 5;
  int b = bh >> 1, h = bh & 1;
  const ushort* base = QKV + (long)b * 1024 * 768 + h * 128;

  __shared__ float Qs[32][132];
  __shared__ float Ks[32][132];
  __shared__ float Vs[32][132];
  __shared__ float Ps[32][33];
  __shared__ float ms[32], ls[32], as_[32];

  int tid = threadIdx.x;
  // stage Q (bf16 -> fp32)
  #pragma unroll
  for (int p = 0; p < 2; p++) {
    int idx = p * 256 + tid;              // 512 x uint4 = 4096 bf16
    int r = idx >> 4, c8 = (idx & 15) * 8;
    uint4 v = *(const uint4*)(base + (long)(qt * 32 + r) * 768 + c8);
    float* dst = &Qs[r][c8];
    dst[0] = b2f_lo(v.x); dst[1] = b2f_hi(v.x);
    dst[2] = b2f_lo(v.y); dst[3] = b2f_hi(v.y);
    dst[4] = b2f_lo(v.z); dst[5] = b2f_hi(v.z);
    dst[6] = b2f_lo(v.w); dst[7] = b2f_hi(v.w);
  }
  if (tid < 32) { ms[tid] = -3.4e38f; ls[tid] = 0.f; }
  float4 Oacc[4];
  #pragma unroll
  for (int j = 0; j < 4; j++) Oacc[j] = make_float4(0.f, 0.f, 0.f, 0.f);

  int q = tid >> 3;          // 0..31
  int k0 = tid & 7;

  for (int kt = 0; kt < 32; kt++) {
    __syncthreads();
    #pragma unroll
    for (int p = 0; p < 2; p++) {
      int idx = p * 256 + tid;
      int r = idx >> 4, c8 = (idx & 15) * 8;
      long gr = (long)(kt * 32 + r) * 768 + c8;
      uint4 vk = *(const uint4*)(base + gr + 256);
      uint4 vv = *(const uint4*)(base + gr + 512);
      float* dk = &Ks[r][c8];
      dk[0] = b2f_lo(vk.x); dk[1] = b2f_hi(vk.x); dk[2] = b2f_lo(vk.y); dk[3] = b2f_hi(vk.y);
      dk[4] = b2f_lo(vk.z); dk[5] = b2f_hi(vk.z); dk[6] = b2f_lo(vk.w); dk[7] = b2f_hi(vk.w);
      float* dv = &Vs[r][c8];
      dv[0] = b2f_lo(vv.x); dv[1] = b2f_hi(vv.x); dv[2] = b2f_lo(vv.y); dv[3] = b2f_hi(vv.y);
      dv[4] = b2f_lo(vv.z); dv[5] = b2f_hi(vv.z); dv[6] = b2f_lo(vv.w); dv[7] = b2f_hi(vv.w);
    }
    __syncthreads();
    // QK^T: thread (q, k0) does 4 dot-products of length 128, float4 LDS reads
    {
      const float4* q4 = (const float4*)&Qs[q][0];
      const float4* ka = (const float4*)&Ks[k0][0];
      const float4* kb = (const float4*)&Ks[k0 + 8][0];
      const float4* kc = (const float4*)&Ks[k0 + 16][0];
      const float4* kd = (const float4*)&Ks[k0 + 24][0];
      float d0 = 0.f, d1 = 0.f, d2 = 0.f, d3 = 0.f;
      for (int c = 0; c < 32; c++) {
        float4 qv = q4[c];
        float4 a = ka[c]; d0 += qv.x * a.x + qv.y * a.y + qv.z * a.z + qv.w * a.w;
        float4 e = kb[c]; d1 += qv.x * e.x + qv.y * e.y + qv.z * e.z + qv.w * e.w;
        float4 f = kc[c]; d2 += qv.x * f.x + qv.y * f.y + qv.z * f.z + qv.w * f.w;
        float4 g = kd[c]; d3 += qv.x * g.x + qv.y * g.y + qv.z * g.z + qv.w * g.w;
      }
      Ps[q][k0] = d0 * scale; Ps[q][k0 + 8] = d1 * scale;
      Ps[q][k0 + 16] = d2 * scale; Ps[q][k0 + 24] = d3 * scale;
    }
    __syncthreads();
    if (tid < 32) {  // online softmax, one lane per q-row
      float m0 = ms[tid], mx = m0;
      for (int k = 0; k < 32; k++) mx = fmaxf(mx, Ps[tid][k]);
      float al = expf(m0 - mx);
      float s = ls[tid] * al;
      for (int k = 0; k < 32; k++) { float p = expf(Ps[tid][k] - mx); Ps[tid][k] = p; s += p; }
      ms[tid] = mx; ls[tid] = s; as_[tid] = al;
    }
    __syncthreads();
    float al = as_[q];
    #pragma unroll
    for (int j = 0; j < 4; j++) {
      Oacc[j].x *= al; Oacc[j].y *= al; Oacc[j].z *= al; Oacc[j].w *= al;
    }
    for (int k = 0; k < 32; k++) {
      float p = Ps[q][k];
      const float4* v4 = (const float4*)&Vs[k][0];
      #pragma unroll
      for (int j = 0; j < 4; j++) {
        float4 v = v4[k0 + 8 * j];
        Oacc[j].x += p * v.x; Oacc[j].y += p * v.y; Oacc[j].z += p * v.z; Oacc[j].w += p * v.w;
      }
    }
  }
  float inv = 1.f / ls[q];
  long row = (long)(b * 1024 + qt * 32 + q);
  #pragma unroll
  for (int j = 0; j < 4; j++) {
    int c0 = (k0 + 8 * j) * 4;
    ushort4 o;
    o.x = f2b(Oacc[j].x * inv); o.y = f2b(Oacc[j].y * inv);
    o.z = f2b(Oacc[j].z * inv); o.w = f2b(Oacc[j].w * inv);
    *(ushort4*)&O[row * 256 + h * 128 + c0] = o;
  }
}

// ---------- sparse pooling attention (bf16 KV) ----------
__global__ __launch_bounds__(128) void pool_attn(
    const float* __restrict__ qe, const float* __restrict__ pinW, const float* __restrict__ pinB,
    const float* __restrict__ srand, const ushort* __restrict__ KV, float* __restrict__ ATTP)
{
  int id = blockIdx.x;
  int h = id & 1, nq = (id >> 1) & 3, b = id >> 3;
  int tid = threadIdx.x;
  __shared__ float qs[128];
  __shared__ float lg[1024];
  __shared__ float red[128];
  {
    float a = pinB[h * 128 + tid];
    const float* wr = pinW + ((long)(h * 128 + tid)) * 256;
    const float* qr = qe + nq * 256;
    for (int i = 0; i < 256; i++) a += qr[i] * wr[i];
    qs[tid] = a;
  }
  __syncthreads();
  const float scale = 0.08838834764831845f;
  for (int s = tid; s < 1024; s += 128) {
    const ushort* kr = KV + ((long)((b << 10) + s)) * 512 + h * 128;
    float d = 0.f;
    for (int c2 = 0; c2 < 128; c2++) d += qs[c2] * b2f(kr[c2]);
    float mv = (srand[nq * 1024 + s] < 0.3f) ? 0.f : -1e9f;
    lg[s] = d * scale + mv;
  }
  __syncthreads();
  float m = -3.4e38f;
  for (int s = tid; s < 1024; s += 128) m = fmaxf(m, lg[s]);
  red[tid] = m; __syncthreads();
  for (int off = 64; off > 0; off >>= 1) { if (tid < off) red[tid] = fmaxf(red[tid], red[tid + off]); __syncthreads(); }
  m = red[0]; __syncthreads();
  float s0 = 0.f;
  for (int s = tid; s < 1024; s += 128) { float e = expf(lg[s] - m); lg[s] = e; s0 += e; }
  red[tid] = s0; __syncthreads();
  for (int off = 64; off > 0; off >>= 1) { if (tid < off) red[tid] += red[tid + off]; __syncthreads(); }
  float denom = red[0]; __syncthreads();
  float o = 0.f;
  for (int s = 0; s < 1024; s++) o += lg[s] * b2f(KV[((long)((b << 10) + s)) * 512 + 256 + h * 128 + tid]);
  ATTP[(b * 4 + nq) * 256 + h * 128 + tid] = o / denom;
}

// ---------- combined = [mean over N | pooled_att] ----------
__global__ __launch_bounds__(256) void combined_kernel(const float* __restrict__ X,
    const float* __restrict__ ATTO, float* __restrict__ CMB)
{
  int b = blockIdx.x, d = threadIdx.x;
  float s = 0.f;
  for (int n = 0; n < 1024; n++) s += X[((long)((b << 10) + n)) * 256 + d];
  CMB[b * 1280 + d] = s * (1.f / 1024.f);
  for (int q = 0; q < 4; q++)
    CMB[b * 1280 + 256 + q * 256 + d] = ATTO[(b * 4 + q) * 256 + d];
}

__global__ void store_out(const float* __restrict__ src, float* __restrict__ dst, int n) {
  int i = blockIdx.x * blockDim.x + threadIdx.x;
  if (i < n) dst[i] = src[i];
}
__global__ void fill_out_zero(float* __restrict__ dst, int n) {
  int i = blockIdx.x * blockDim.x + threadIdx.x;
  if (i < n) dst[i] = 0.f;
}

static void cvt(hipStream_t st, const float* src, ushort* dst, int n) {
  cvt_f2b<<<(n / 4 + 255) / 256, 256, 0, st>>>(src, dst, n);
}

extern "C" void kernel_launch(void* const* d_in, const int* in_sizes, int n_in,
                              void* d_out, int out_size, void* d_ws, size_t ws_size,
                              hipStream_t stream)
{
  const float* inp      = (const float*)d_in[0];
  const float* cellp    = (const float*)d_in[1];
  const float* srand    = (const float*)d_in[2];
  const float* emb_W    = (const float*)d_in[3];
  const float* emb_b    = (const float*)d_in[4];
  const float* pe_tab   = (const float*)d_in[5];
  const float* pe_W1    = (const float*)d_in[6];
  const float* pe_b1    = (const float*)d_in[7];
  const float* pe_W2    = (const float*)d_in[8];
  const float* pe_b2    = (const float*)d_in[9];
  const float* gat_W    = (const float*)d_in[10];
  const float* gat_asrc = (const float*)d_in[11];
  const float* gat_adst = (const float*)d_in[12];
  const float* gat_b    = (const float*)d_in[13];
  const float* ln_g     = (const float*)d_in[14];
  const float* ln_b     = (const float*)d_in[15];
  const float* qkv_W    = (const float*)d_in[16];
  const float* qkv_b    = (const float*)d_in[17];
  const float* out_W    = (const float*)d_in[18];
  const float* out_b    = (const float*)d_in[19];
  const float* ff1_W    = (const float*)d_in[20];
  const float* ff1_b    = (const float*)d_in[21];
  const float* ff2_W    = (const float*)d_in[22];
  const float* ff2_b    = (const float*)d_in[23];
  const float* ln1_g    = (const float*)d_in[24];
  const float* ln1_b    = (const float*)d_in[25];
  const float* ln2_g    = (const float*)d_in[26];
  const float* ln2_b    = (const float*)d_in[27];
  const float* q_emb    = (const float*)d_in[28];
  const float* pin_W    = (const float*)d_in[29];
  const float* pin_b    = (const float*)d_in[30];
  const float* pout_W   = (const float*)d_in[31];
  const float* pout_b   = (const float*)d_in[32];
  const float* m1_W     = (const float*)d_in[33];
  const float* m1_b     = (const float*)d_in[34];
  const float* mln1_g   = (const float*)d_in[35];
  const float* mln1_b   = (const float*)d_in[36];
  const float* m2_W     = (const float*)d_in[37];
  const float* m2_b     = (const float*)d_in[38];
  const float* mln2_g   = (const float*)d_in[39];
  const float* mln2_b   = (const float*)d_in[40];
  const float* m3_W     = (const float*)d_in[41];
  const float* m3_b     = (const float*)d_in[42];
  const float* c1_W     = (const float*)d_in[43];
  const float* c1_b     = (const float*)d_in[44];
  const float* c2_W     = (const float*)d_in[45];
  const float* c2_b     = (const float*)d_in[46];
  const float* c3_W     = (const float*)d_in[47];
  const float* c3_b     = (const float*)d_in[48];
  const float* c4_W     = (const float*)d_in[49];
  const float* c4_b     = (const float*)d_in[50];
  (void)in_sizes; (void)n_in;

  // ---- workspace (bytes, 256-aligned chunks; total ~17.7 MB) ----
  char* base = (char*)d_ws;
  size_t off = 0;
  auto alloc = [&](size_t bytes) { void* p = base + off; off += (bytes + 255) & ~size_t(255); return p; };
  float* PN    = (float*)alloc(32768);
  float* AS    = (float*)alloc(32768);
  float* AD    = (float*)alloc(32768);
  float* ATTP  = (float*)alloc(16384);
  float* ATTO  = (float*)alloc(16384);
  float* CMB   = (float*)alloc(20480);
  float* Ha    = (float*)alloc(16384);
  float* Hb    = (float*)alloc(16384);
  float* Hc    = (float*)alloc(16640);
  float* Hd    = (float*)alloc(8192);
  float* He    = (float*)alloc(4096);
  float* Hf    = (float*)alloc(512);
  int*   NBR   = (int*)alloc(131072);
  float* X     = (float*)alloc(4194304);          // fp32 residual stream [4096,256]
  ushort* Xb   = (ushort*)alloc(2097152);         // bf16 shadow of X
  ushort* Wb   = (ushort*)alloc(524288);          // rotating bf16 weight buffer (max 262144 el)
  char*  Rq    = (char*)alloc(6291456);           // QKVb bf16 | F2 fp32 | KVb bf16
  char*  Rf    = (char*)alloc(4194304);           // inpb bf16 | Ob bf16 | FFBb bf16 (2048-row chunk)
  ushort* QKVb = (ushort*)Rq;                     // [4096,768]
  float*  F2   = (float*)Rq;                      // [4096,256]
  ushort* KVb  = (ushort*)Rq;                     // [4096,512]
  ushort* inpb = (ushort*)Rf;                     // [4096,512]
  ushort* Ob   = (ushort*)Rf;                     // [4096,256]
  ushort* FFBb = (ushort*)Rf;                     // [2048,1024]
  float*  F1   = (float*)alloc(4194304);          // GAT h fp32 [4096,256]
  if (ws_size < off) { fill_out_zero<<<1, 128, 0, stream>>>((float*)d_out, out_size); return; }

  // ---- graph construction ----
  bag_stats<<<4, 256, 0, stream>>>(cellp, PN);
  knn_kernel<<<16, 256, 0, stream>>>(PN, NBR);

  // ---- embedding + positional MLP ----
  cvt(stream, inp, inpb, 4096 * 512);
  cvt(stream, emb_W, Wb, 256 * 512);
  mgemm<float>(stream, inpb, 512, Wb, 512, emb_b, X, 256, 4096, 256, 512, 0);
  pos_embed<<<dim3(4096, 2), 128, 0, stream>>>(cellp, pe_tab, pe_W1, pe_b1, pe_W2, pe_b2, X);
  cvt(stream, X, Xb, 4096 * 256);

  // ---- 2x GAT ----
  for (int l = 0; l < 2; l++) {
    cvt(stream, gat_W + l * 65536, Wb, 65536);
    mgemm<float>(stream, Xb, 256, Wb, 256, nullptr, F1, 256, 4096, 256, 256, 0);
    gat_scores<<<4096, 256, 0, stream>>>(F1, gat_asrc + l * 256, gat_adst + l * 256, AS, AD);
    gat_aggr_ln<<<4096, 256, 0, stream>>>(F1, AS, AD, NBR, gat_b + l * 256, ln_g, ln_b, X, Xb);
  }

  // ---- 2x Transformer encoder layer ----
  for (int l = 0; l < 2; l++) {
    cvt(stream, qkv_W + (long)l * 768 * 256, Wb, 768 * 256);
    mgemm<ushort>(stream, Xb, 256, Wb, 256, qkv_b + l * 768, QKVb, 768, 4096, 768, 256, 0);
    flash_attn<<<256, 256, 0, stream>>>(QKVb, Ob);      // QKVb dead after this
    cvt(stream, out_W + l * 65536, Wb, 65536);
    mgemm<float>(stream, Ob, 256, Wb, 256, out_b + l * 256, F2, 256, 4096, 256, 256, 0);
    add_ln<<<4096, 256, 0, stream>>>(X, F2, ln1_g + l * 256, ln1_b + l * 256, X, Xb, 256);
    for (int ch = 0; ch < 2; ch++) {                    // FFN in 2048-row chunks
      cvt(stream, ff1_W + l * 262144, Wb, 262144);
      mgemm<ushort>(stream, Xb + (long)ch * 2048 * 256, 256, Wb, 256, ff1_b + l * 1024,
                    FFBb, 1024, 2048, 1024, 256, 1);
      cvt(stream, ff2_W + l * 262144, Wb, 262144);
      mgemm<float>(stream, FFBb, 1024, Wb, 1024, ff2_b + l * 256,
                   F2 + (long)ch * 2048 * 256, 256, 2048, 256, 1024, 0);
    }
    add_ln<<<4096, 256, 0, stream>>>(X, F2, ln2_g + l * 256, ln2_b + l * 256, X, Xb, 256);
  }

  // ---- final LN ----
  add_ln<<<4096, 256, 0, stream>>>((const float*)nullptr, X, ln_g, ln_b, X, Xb, 256);

  // ---- pooling ----
  cvt(stream, pin_W + 65536, Wb, 512 * 256);            // Wk|Wv rows
  mgemm<ushort>(stream, Xb, 256, Wb, 256, pin_b + 256, KVb, 512, 4096, 512, 256, 0);
  pool_attn<<<32, 128, 0, stream>>>(q_emb, pin_W, pin_b, srand, KVb, ATTP);
  gemm(stream, ATTP, 256, pout_W, 256, pout_b, ATTO, 256, 16, 256, 256, 0);
  combined_kernel<<<4, 256, 0, stream>>>(X, ATTO, CMB);

  // ---- MLP head (fp32) ----
  gemm(stream, CMB, 1280, m1_W, 1280, m1_b, Ha, 1024, 4, 1024, 1280, 1);
  add_ln<<<4, 256, 0, stream>>>((const float*)nullptr, Ha, mln1_g, mln1_b, Ha, (ushort*)nullptr, 1024);
  gemm(stream, Ha, 1024, m2_W, 1024, m2_b, Hb, 1024, 4, 1024, 1024, 1);
  add_ln<<<4, 256, 0, stream>>>((const float*)nullptr, Hb, mln2_g, mln2_b, Hb, (ushort*)nullptr, 1024);
  gemm(stream, Hb, 1024, m3_W, 1024, m3_b, Ha, 1024, 4, 1024, 1024, 0);
  gemm(stream, Ha, 1024, c1_W, 1024, c1_b, Hc, 1032, 4, 1032, 1024, 1);
  gemm(stream, Hc, 1032, c2_W, 1032, c2_b, Hd, 512, 4, 512, 1032, 1);
  gemm(stream, Hd, 512, c3_W, 512, c3_b, He, 256, 4, 256, 512, 1);
  gemm(stream, He, 256, c4_W, 256, c4_b, Hf, 24, 4, 24, 256, 0);
  store_out<<<1, 128, 0, stream>>>(Hf, (float*)d_out, out_size);
}

// Round 5
// 2053.058 us; speedup vs baseline: 1.9404x; 1.0319x over previous
//
#include <hip/hip_runtime.h>
#include <hip/hip_bf16.h>

// MILCellModel forward on MI355X. Round 5: parallel kNN (8 thr/target + exact
// lexicographic merge), fp32->bf16 conversion fused into MFMA GEMM staging
// (no separate weight cvt dispatches), 256-thread pool_attn, wave-per-row LN.
// B=4 N=1024 E=512 D=256 H=2 C=128 FF=1024 NQ=4 NCLS=24

typedef __bf16 bf16x8 __attribute__((ext_vector_type(8)));
typedef float  f32x4  __attribute__((ext_vector_type(4)));

__device__ __forceinline__ ushort f2b(float f) {
  __hip_bfloat16 h = __float2bfloat16(f);
  return *(ushort*)&h;
}
__device__ __forceinline__ float b2f(ushort u) {
  union { unsigned i; float f; } v; v.i = ((unsigned)u) << 16; return v.f;
}
__device__ __forceinline__ float b2f_lo(unsigned u) { union { unsigned i; float f; } v; v.i = u << 16; return v.f; }
__device__ __forceinline__ float b2f_hi(unsigned u) { union { unsigned i; float f; } v; v.i = u & 0xffff0000u; return v.f; }

// ---------- block reductions (256 threads) ----------
__device__ __forceinline__ float blk_sum256(float v, float* red) {
  int t = threadIdx.x;
  red[t] = v; __syncthreads();
  #pragma unroll
  for (int off = 128; off > 0; off >>= 1) {
    if (t < off) red[t] += red[t + off];
    __syncthreads();
  }
  float r = red[0]; __syncthreads();
  return r;
}

// ---------- fp32 -> bf16 convert ----------
__global__ __launch_bounds__(256) void cvt_f2b(const float* __restrict__ src,
                                               ushort* __restrict__ dst, int n) {
  int i = (blockIdx.x * 256 + threadIdx.x) * 4;
  if (i >= n) return;
  float4 v = *(const float4*)(src + i);
  ushort4 o;
  o.x = f2b(v.x); o.y = f2b(v.y); o.z = f2b(v.z); o.w = f2b(v.w);
  *(ushort4*)(dst + i) = o;
}

// ---------- staging helpers: 8 contiguous elements -> bf16 LDS ----------
__device__ __forceinline__ void stage8(const ushort* __restrict__ src, ushort* dst) {
  *(uint4*)dst = *(const uint4*)src;
}
__device__ __forceinline__ void stage8(const float* __restrict__ src, ushort* dst) {
  float4 a = ((const float4*)src)[0];
  float4 b = ((const float4*)src)[1];
  ushort4 o0, o1;
  o0.x = f2b(a.x); o0.y = f2b(a.y); o0.z = f2b(a.z); o0.w = f2b(a.w);
  o1.x = f2b(b.x); o1.y = f2b(b.y); o1.z = f2b(b.z); o1.w = f2b(b.w);
  *(ushort4*)dst = o0;
  *(ushort4*)(dst + 4) = o1;
}

// ---------- bf16 MFMA GEMM: C[M,N] = act(A[M,K] @ B^T + bias) ----------
// A [M,K] row-major (bf16 or fp32), B [N,K] row-major (bf16 or fp32; fp32 is
// converted to bf16 during staging -- numerically identical to pre-convert).
// Tile 64x128, BK=32. M%64==0, N%128==0, K%32==0 at all call sites.
template<typename CT, typename AT, typename WT>
__global__ __launch_bounds__(256) void mfma_gemm(
    const AT* __restrict__ A, int lda,
    const WT* __restrict__ Bw, int ldb,
    const float* __restrict__ bias,
    CT* __restrict__ C, int ldc, int K, int relu)
{
  __shared__ ushort As[64][40];    // +8 pad: conflict-free b128 frag reads
  __shared__ ushort Bs[128][40];
  int tid = threadIdx.x;
  int lane = tid & 63, wave = tid >> 6;
  int wm = wave >> 1, wn = wave & 1;      // 2x2 waves; wave tile = 32x64
  int quad = lane >> 4, l16 = lane & 15;
  long mBase = blockIdx.y * 64, nBase = blockIdx.x * 128;

  f32x4 zero4 = {0.f, 0.f, 0.f, 0.f};
  f32x4 acc[2][4];
  #pragma unroll
  for (int i = 0; i < 2; i++)
    #pragma unroll
    for (int j = 0; j < 4; j++) acc[i][j] = zero4;

  for (int k0 = 0; k0 < K; k0 += 32) {
    {
      int r = tid >> 2, sg = (tid & 3) * 8;          // 64 rows x 32 cols
      stage8(A + (mBase + r) * lda + k0 + sg, &As[r][sg]);
    }
    #pragma unroll
    for (int p = 0; p < 2; p++) {
      int idx = p * 256 + tid;
      int r = idx >> 2, sg = (idx & 3) * 8;          // 128 rows x 32 cols
      stage8(Bw + (nBase + r) * ldb + k0 + sg, &Bs[r][sg]);
    }
    __syncthreads();
    bf16x8 af[2], bfr[4];
    #pragma unroll
    for (int i = 0; i < 2; i++)
      af[i] = *(const bf16x8*)&As[wm * 32 + i * 16 + l16][quad * 8];
    #pragma unroll
    for (int j = 0; j < 4; j++)
      bfr[j] = *(const bf16x8*)&Bs[wn * 64 + j * 16 + l16][quad * 8];
    #pragma unroll
    for (int i = 0; i < 2; i++)
      #pragma unroll
      for (int j = 0; j < 4; j++)
        acc[i][j] = __builtin_amdgcn_mfma_f32_16x16x32_bf16(af[i], bfr[j], acc[i][j], 0, 0, 0);
    __syncthreads();
  }
  // C/D layout: col = lane&15, row = quad*4 + reg
  #pragma unroll
  for (int i = 0; i < 2; i++) {
    #pragma unroll
    for (int j = 0; j < 4; j++) {
      long col = nBase + wn * 64 + j * 16 + l16;
      float bv = bias ? bias[col] : 0.f;
      #pragma unroll
      for (int r = 0; r < 4; r++) {
        long row = mBase + wm * 32 + i * 16 + quad * 4 + r;
        float v = acc[i][j][r] + bv;
        if (relu) v = fmaxf(v, 0.f);
        if constexpr (sizeof(CT) == 2) C[row * ldc + col] = f2b(v);
        else                           C[row * ldc + col] = v;
      }
    }
  }
}

template<typename CT, typename AT, typename WT>
static void mgemm(hipStream_t st, const AT* A, int lda, const WT* B, int ldb,
                  const float* bias, CT* C, int ldc, int M, int N, int K, int relu) {
  dim3 grid(N / 128, M / 64);
  mfma_gemm<CT, AT, WT><<<grid, 256, 0, st>>>(A, lda, B, ldb, bias, C, ldc, K, relu);
}

// ---------- fp32 tiled GEMM (head matmuls, M=4..16) ----------
__global__ __launch_bounds__(256) void gemm_kernel(
    const float* __restrict__ A, int lda,
    const float* __restrict__ Bm, int ldb,
    const float* __restrict__ bias,
    float* __restrict__ C, int ldc,
    int M, int N, int K, int relu)
{
  __shared__ float As[16][65];
  __shared__ float Bs[16][65];
  int tid = threadIdx.x;
  int tx = tid & 15, ty = tid >> 4;
  int mBase = blockIdx.y * 64, nBase = blockIdx.x * 64;
  float acc[4][4] = {};

  for (int k0 = 0; k0 < K; k0 += 16) {
    {
      int m = tid >> 2, kk = (tid & 3) * 4;
      int gm = mBase + m;
      #pragma unroll
      for (int i = 0; i < 4; i++) {
        int gk = k0 + kk + i;
        As[kk + i][m] = (gm < M && gk < K) ? A[(long)gm * lda + gk] : 0.f;
      }
    }
    {
      int n = tid >> 2, kk = (tid & 3) * 4;
      int gn = nBase + n;
      #pragma unroll
      for (int i = 0; i < 4; i++) {
        int gk = k0 + kk + i;
        Bs[kk + i][n] = (gn < N && gk < K) ? Bm[(long)gn * ldb + gk] : 0.f;
      }
    }
    __syncthreads();
    #pragma unroll
    for (int kk = 0; kk < 16; kk++) {
      float a[4], b[4];
      #pragma unroll
      for (int i = 0; i < 4; i++) a[i] = As[kk][ty * 4 + i];
      #pragma unroll
      for (int j = 0; j < 4; j++) b[j] = Bs[kk][tx * 4 + j];
      #pragma unroll
      for (int i = 0; i < 4; i++)
        #pragma unroll
        for (int j = 0; j < 4; j++) acc[i][j] += a[i] * b[j];
    }
    __syncthreads();
  }
  #pragma unroll
  for (int i = 0; i < 4; i++) {
    int gm = mBase + ty * 4 + i;
    if (gm >= M) continue;
    #pragma unroll
    for (int j = 0; j < 4; j++) {
      int gn = nBase + tx * 4 + j;
      if (gn >= N) continue;
      float v = acc[i][j];
      if (bias) v += bias[gn];
      if (relu) v = fmaxf(v, 0.f);
      C[(long)gm * ldc + gn] = v;
    }
  }
}

static void gemm(hipStream_t st, const float* A, int lda, const float* B, int ldb,
                 const float* bias, float* C, int ldc, int M, int N, int K, int relu)
{
  dim3 grid((N + 63) / 64, (M + 63) / 64, 1);
  gemm_kernel<<<grid, 256, 0, st>>>(A, lda, B, ldb, bias, C, ldc, M, N, K, relu);
}

// ---------- bag stats ----------
__global__ __launch_bounds__(256) void bag_stats(const float* __restrict__ cp, float* __restrict__ PN) {
  int b = blockIdx.x, tid = threadIdx.x;
  __shared__ float red[256];
  for (int c = 0; c < 2; c++) {
    float s = 0.f;
    for (int n = tid; n < 1024; n += 256) s += cp[((b << 10) + n) * 2 + c];
    float mean = blk_sum256(s, red) * (1.f / 1024.f);
    s = 0.f;
    for (int n = tid; n < 1024; n += 256) { float d = cp[((b << 10) + n) * 2 + c] - mean; s += d * d; }
    float var = blk_sum256(s, red) * (1.f / 1024.f);
    float inv = 1.f / (sqrtf(var) + 1e-8f);
    for (int n = tid; n < 1024; n += 256)
      PN[((b << 10) + n) * 2 + c] = (cp[((b << 10) + n) * 2 + c] - mean) * inv;
  }
}

// ---------- kNN: parallel stable top-8 ----------
// 8 threads/target, each scans a 128-source chunk (ascending index -> within-
// chunk lists are (d,idx)-lexicographic); single lexicographic merge of 64
// candidates reproduces jax.lax.top_k tie-breaking exactly.
__global__ __launch_bounds__(256) void knn_kernel(const float* __restrict__ PN, int* __restrict__ NBR) {
  int blk = blockIdx.x;              // 128 blocks
  int b = blk >> 5, tg = blk & 31;   // 32 targets per block
  int tid = threadIdx.x;
  int tl = tid >> 3, chunk = tid & 7;
  __shared__ float px[1024], py[1024];
  __shared__ float candD[32][64];
  __shared__ int   candI[32][64];
  for (int i = tid; i < 1024; i += 256) {
    px[i] = PN[((b << 10) + i) * 2 + 0];
    py[i] = PN[((b << 10) + i) * 2 + 1];
  }
  __syncthreads();
  int t = tg * 32 + tl;
  float tx = px[t], ty = py[t];
  float d8[8]; int i8[8];
  #pragma unroll
  for (int i = 0; i < 8; i++) { d8[i] = 3.4e38f; i8[i] = 0x7fffffff; }
  int s0 = chunk * 128;
  for (int s = s0; s < s0 + 128; s++) {
    float dx = __fadd_rn(px[s], -tx), dy = __fadd_rn(py[s], -ty);
    float d2 = __fadd_rn(__fadd_rn(__fmul_rn(dx, dx), __fmul_rn(dy, dy)), 1e-12f);
    float d = sqrtf(d2);
    if (d < d8[7]) {   // strict -> ascending-index stability within chunk
      d8[7] = d; i8[7] = s;
      #pragma unroll
      for (int p = 7; p > 0; p--) {
        if (d8[p] < d8[p - 1]) {
          float td = d8[p]; d8[p] = d8[p - 1]; d8[p - 1] = td;
          int ti = i8[p]; i8[p] = i8[p - 1]; i8[p - 1] = ti;
        }
      }
    }
  }
  #pragma unroll
  for (int i = 0; i < 8; i++) { candD[tl][chunk * 8 + i] = d8[i]; candI[tl][chunk * 8 + i] = i8[i]; }
  __syncthreads();
  if (chunk == 0) {
    float D[8]; int I[8];
    #pragma unroll
    for (int i = 0; i < 8; i++) { D[i] = candD[tl][i]; I[i] = candI[tl][i]; }
    for (int c = 1; c < 8; c++) {
      for (int j = 0; j < 8; j++) {
        float d = candD[tl][c * 8 + j]; int idx = candI[tl][c * 8 + j];
        bool better = (d < D[7]) || (d == D[7] && idx < I[7]);
        if (!better) break;  // chunk list sorted lexicographic -> rest also fail
        D[7] = d; I[7] = idx;
        #pragma unroll
        for (int p = 7; p > 0; p--) {
          bool sw = (D[p] < D[p - 1]) || (D[p] == D[p - 1] && I[p] < I[p - 1]);
          if (sw) {
            float td = D[p]; D[p] = D[p - 1]; D[p - 1] = td;
            int ti = I[p]; I[p] = I[p - 1]; I[p - 1] = ti;
          }
        }
      }
    }
    #pragma unroll
    for (int i = 0; i < 8; i++) NBR[((long)((b << 10) + t)) * 8 + i] = I[i];
  }
}

// ---------- positional embedding MLP ----------
__global__ __launch_bounds__(128) void pos_embed(
    const float* __restrict__ cellp, const float* __restrict__ tab,
    const float* __restrict__ W1, const float* __restrict__ b1,
    const float* __restrict__ W2, const float* __restrict__ b2,
    float* __restrict__ X)
{
  int row = blockIdx.x, c = blockIdx.y, tid = threadIdx.x;
  __shared__ float e[128], h1[128];
  float pos = cellp[row * 2 + c];
  pos = fminf(fmaxf(pos, 0.f), 1000.f);
  int pi = (int)pos;
  e[tid] = tab[((long)(c * 1001 + pi)) * 128 + tid];
  __syncthreads();
  {
    const float* w1r = W1 + ((long)(c * 128 + tid)) * 128;
    float a = b1[c * 128 + tid];
    for (int i = 0; i < 128; i++) a += e[i] * w1r[i];
    h1[tid] = fmaxf(a, 0.f);
  }
  __syncthreads();
  {
    const float* w2r = W2 + ((long)(c * 128 + tid)) * 128;
    float o = b2[c * 128 + tid];
    for (int i = 0; i < 128; i++) o += h1[i] * w2r[i];
    X[(long)row * 256 + c * 128 + tid] += o;
  }
}

// ---------- GAT scores ----------
__global__ __launch_bounds__(256) void gat_scores(const float* __restrict__ Hh,
    const float* __restrict__ asrcW, const float* __restrict__ adstW,
    float* __restrict__ ASRC, float* __restrict__ ADST)
{
  int row = blockIdx.x, tid = threadIdx.x;
  __shared__ float red[256];
  float v = Hh[(long)row * 256 + tid];
  float s1 = v * asrcW[tid];
  float s2 = v * adstW[tid];
  red[tid] = s1; __syncthreads();
  for (int off = 64; off > 0; off >>= 1) { if ((tid & 127) < off) red[tid] += red[tid + off]; __syncthreads(); }
  if ((tid & 127) == 0) ASRC[row * 2 + (tid >> 7)] = red[tid];
  __syncthreads();
  red[tid] = s2; __syncthreads();
  for (int off = 64; off > 0; off >>= 1) { if ((tid & 127) < off) red[tid] += red[tid + off]; __syncthreads(); }
  if ((tid & 127) == 0) ADST[row * 2 + (tid >> 7)] = red[tid];
}

// ---------- GAT aggregate + residual + LN (emits fp32 X and bf16 Xb) ----------
__global__ __launch_bounds__(256) void gat_aggr_ln(
    const float* __restrict__ Hh, const float* __restrict__ ASRC, const float* __restrict__ ADST,
    const int* __restrict__ NBR, const float* __restrict__ gbias,
    const float* __restrict__ lng, const float* __restrict__ lnb,
    float* __restrict__ X, ushort* __restrict__ Xb)
{
  int row = blockIdx.x, tid = threadIdx.x;
  int b = row >> 10;
  __shared__ int nb[8];
  __shared__ float w[2][8];
  __shared__ float red[256];
  if (tid < 8) {
    int v = NBR[(long)row * 8 + tid];
    nb[tid] = min(max(v, 0), 1023);
  }
  __syncthreads();
  if (tid < 16) {
    int i = tid & 7, h = tid >> 3;
    float e = ADST[row * 2 + h] + ASRC[((b << 10) + nb[i]) * 2 + h];
    w[h][i] = (e >= 0.f) ? e : 0.2f * e;
  }
  __syncthreads();
  if (tid < 2) {
    float m = -3.4e38f;
    for (int i = 0; i < 8; i++) m = fmaxf(m, w[tid][i]);
    float s = 0.f;
    for (int i = 0; i < 8; i++) { float e = expf(w[tid][i] - m); w[tid][i] = e; s += e; }
    float inv = 1.f / s;
    for (int i = 0; i < 8; i++) w[tid][i] *= inv;
  }
  __syncthreads();
  int h = tid >> 7, c = tid & 127;
  float acc = 0.f;
  #pragma unroll
  for (int i = 0; i < 8; i++)
    acc += w[h][i] * Hh[((long)((b << 10) + nb[i])) * 256 + h * 128 + c];
  float v = acc + gbias[tid] + X[(long)row * 256 + tid];
  float mean = blk_sum256(v, red) * (1.f / 256.f);
  float dv = v - mean;
  float var = blk_sum256(dv * dv, red) * (1.f / 256.f);
  float o = dv * rsqrtf(var + 1e-5f) * lng[tid] + lnb[tid];
  X[(long)row * 256 + tid] = o;
  Xb[(long)row * 256 + tid] = f2b(o);
}

// ---------- residual + LayerNorm, D=256, one wave per row ----------
__global__ __launch_bounds__(256) void add_ln4(const float* __restrict__ res,
    const float* __restrict__ Yv, const float* __restrict__ g, const float* __restrict__ b,
    float* __restrict__ out, ushort* __restrict__ outb)
{
  int wave = threadIdx.x >> 6, lane = threadIdx.x & 63;
  long row = blockIdx.x * 4 + wave;
  const float* yr = Yv + row * 256;
  const float* rr = res ? res + row * 256 : nullptr;
  float v[4];
  float s = 0.f;
  #pragma unroll
  for (int i = 0; i < 4; i++) {
    int d = lane + i * 64;
    float x = yr[d];
    if (rr) x += rr[d];
    v[i] = x; s += x;
  }
  #pragma unroll
  for (int off = 32; off > 0; off >>= 1) s += __shfl_xor(s, off);
  float mean = s * (1.f / 256.f);
  float vs = 0.f;
  #pragma unroll
  for (int i = 0; i < 4; i++) { float dv = v[i] - mean; vs += dv * dv; }
  #pragma unroll
  for (int off = 32; off > 0; off >>= 1) vs += __shfl_xor(vs, off);
  float rstd = rsqrtf(vs * (1.f / 256.f) + 1e-5f);
  #pragma unroll
  for (int i = 0; i < 4; i++) {
    int d = lane + i * 64;
    float o = (v[i] - mean) * rstd * g[d] + b[d];
    out[row * 256 + d] = o;
    if (outb) outb[row * 256 + d] = f2b(o);
  }
}

// ---------- residual + LayerNorm (D=1024, head rows) ----------
__global__ __launch_bounds__(256) void add_ln_big(const float* __restrict__ Yv,
    const float* __restrict__ g, const float* __restrict__ b,
    float* __restrict__ out)
{
  int row = blockIdx.x, tid = threadIdx.x;
  __shared__ float red[256];
  float vals[4];
  float s = 0.f;
  #pragma unroll
  for (int i = 0; i < 4; i++) {
    int d = tid + (i << 8);
    float v = Yv[(long)row * 1024 + d];
    vals[i] = v; s += v;
  }
  float mean = blk_sum256(s, red) * (1.f / 1024.f);
  s = 0.f;
  #pragma unroll
  for (int i = 0; i < 4; i++) { float dv = vals[i] - mean; s += dv * dv; }
  float var = blk_sum256(s, red) * (1.f / 1024.f);
  float rstd = rsqrtf(var + 1e-5f);
  #pragma unroll
  for (int i = 0; i < 4; i++) {
    int d = tid + (i << 8);
    out[(long)row * 1024 + d] = (vals[i] - mean) * rstd * g[d] + b[d];
  }
}

// ---------- flash attention: bf16 QKV in, bf16 O out, fp32 math ----------
__global__ __launch_bounds__(256) void flash_attn(const ushort* __restrict__ QKV,
                                                  ushort* __restrict__ O)
{
  const float scale = 0.08838834764831845f;
  int blk = blockIdx.x;
  int qt = blk & 31, bh = blk >> 5;
  int b = bh >> 1, h = bh & 1;
  const ushort* base = QKV + (long)b * 1024 * 768 + h * 128;

  __shared__ float Qs[32][132];
  __shared__ float Ks[32][132];
  __shared__ float Vs[32][132];
  __shared__ float Ps[32][33];
  __shared__ float ms[32], ls[32], as_[32];

  int tid = threadIdx.x;
  #pragma unroll
  for (int p = 0; p < 2; p++) {
    int idx = p * 256 + tid;
    int r = idx >> 4, c8 = (idx & 15) * 8;
    uint4 v = *(const uint4*)(base + (long)(qt * 32 + r) * 768 + c8);
    float* dst = &Qs[r][c8];
    dst[0] = b2f_lo(v.x); dst[1] = b2f_hi(v.x);
    dst[2] = b2f_lo(v.y); dst[3] = b2f_hi(v.y);
    dst[4] = b2f_lo(v.z); dst[5] = b2f_hi(v.z);
    dst[6] = b2f_lo(v.w); dst[7] = b2f_hi(v.w);
  }
  if (tid < 32) { ms[tid] = -3.4e38f; ls[tid] = 0.f; }
  float4 Oacc[4];
  #pragma unroll
  for (int j = 0; j < 4; j++) Oacc[j] = make_float4(0.f, 0.f, 0.f, 0.f);

  int q = tid >> 3;
  int k0 = tid & 7;

  for (int kt = 0; kt < 32; kt++) {
    __syncthreads();
    #pragma unroll
    for (int p = 0; p < 2; p++) {
      int idx = p * 256 + tid;
      int r = idx >> 4, c8 = (idx & 15) * 8;
      long gr = (long)(kt * 32 + r) * 768 + c8;
      uint4 vk = *(const uint4*)(base + gr + 256);
      uint4 vv = *(const uint4*)(base + gr + 512);
      float* dk = &Ks[r][c8];
      dk[0] = b2f_lo(vk.x); dk[1] = b2f_hi(vk.x); dk[2] = b2f_lo(vk.y); dk[3] = b2f_hi(vk.y);
      dk[4] = b2f_lo(vk.z); dk[5] = b2f_hi(vk.z); dk[6] = b2f_lo(vk.w); dk[7] = b2f_hi(vk.w);
      float* dv = &Vs[r][c8];
      dv[0] = b2f_lo(vv.x); dv[1] = b2f_hi(vv.x); dv[2] = b2f_lo(vv.y); dv[3] = b2f_hi(vv.y);
      dv[4] = b2f_lo(vv.z); dv[5] = b2f_hi(vv.z); dv[6] = b2f_lo(vv.w); dv[7] = b2f_hi(vv.w);
    }
    __syncthreads();
    {
      const float4* q4 = (const float4*)&Qs[q][0];
      const float4* ka = (const float4*)&Ks[k0][0];
      const float4* kb = (const float4*)&Ks[k0 + 8][0];
      const float4* kc = (const float4*)&Ks[k0 + 16][0];
      const float4* kd = (const float4*)&Ks[k0 + 24][0];
      float d0 = 0.f, d1 = 0.f, d2 = 0.f, d3 = 0.f;
      for (int c = 0; c < 32; c++) {
        float4 qv = q4[c];
        float4 a = ka[c]; d0 += qv.x * a.x + qv.y * a.y + qv.z * a.z + qv.w * a.w;
        float4 e = kb[c]; d1 += qv.x * e.x + qv.y * e.y + qv.z * e.z + qv.w * e.w;
        float4 f = kc[c]; d2 += qv.x * f.x + qv.y * f.y + qv.z * f.z + qv.w * f.w;
        float4 g = kd[c]; d3 += qv.x * g.x + qv.y * g.y + qv.z * g.z + qv.w * g.w;
      }
      Ps[q][k0] = d0 * scale; Ps[q][k0 + 8] = d1 * scale;
      Ps[q][k0 + 16] = d2 * scale; Ps[q][k0 + 24] = d3 * scale;
    }
    __syncthreads();
    if (tid < 32) {
      float m0 = ms[tid], mx = m0;
      for (int k = 0; k < 32; k++) mx = fmaxf(mx, Ps[tid][k]);
      float al = expf(m0 - mx);
      float s = ls[tid] * al;
      for (int k = 0; k < 32; k++) { float p = expf(Ps[tid][k] - mx); Ps[tid][k] = p; s += p; }
      ms[tid] = mx; ls[tid] = s; as_[tid] = al;
    }
    __syncthreads();
    float al = as_[q];
    #pragma unroll
    for (int j = 0; j < 4; j++) {
      Oacc[j].x *= al; Oacc[j].y *= al; Oacc[j].z *= al; Oacc[j].w *= al;
    }
    for (int k = 0; k < 32; k++) {
      float p = Ps[q][k];
      const float4* v4 = (const float4*)&Vs[k][0];
      #pragma unroll
      for (int j = 0; j < 4; j++) {
        float4 v = v4[k0 + 8 * j];
        Oacc[j].x += p * v.x; Oacc[j].y += p * v.y; Oacc[j].z += p * v.z; Oacc[j].w += p * v.w;
      }
    }
  }
  float inv = 1.f / ls[q];
  long row = (long)(b * 1024 + qt * 32 + q);
  #pragma unroll
  for (int j = 0; j < 4; j++) {
    int c0 = (k0 + 8 * j) * 4;
    ushort4 o;
    o.x = f2b(Oacc[j].x * inv); o.y = f2b(Oacc[j].y * inv);
    o.z = f2b(Oacc[j].z * inv); o.w = f2b(Oacc[j].w * inv);
    *(ushort4*)&O[row * 256 + h * 128 + c0] = o;
  }
}

// ---------- sparse pooling attention (bf16 KV, 256 threads) ----------
__global__ __launch_bounds__(256) void pool_attn(
    const float* __restrict__ qe, const float* __restrict__ pinW, const float* __restrict__ pinB,
    const float* __restrict__ srand, const ushort* __restrict__ KV, float* __restrict__ ATTP)
{
  int id = blockIdx.x;   // 32 blocks: b*8 + nq*2 + h
  int h = id & 1, nq = (id >> 1) & 3, b = id >> 3;
  int tid = threadIdx.x;
  __shared__ float qs[128];
  __shared__ float lg[1024];
  __shared__ float red[256];
  if (tid < 128) {
    float a = pinB[h * 128 + tid];
    const float* wr = pinW + ((long)(h * 128 + tid)) * 256;
    const float* qr = qe + nq * 256;
    for (int i = 0; i < 256; i++) a += qr[i] * wr[i];
    qs[tid] = a;
  }
  __syncthreads();
  const float scale = 0.08838834764831845f;
  for (int s = tid; s < 1024; s += 256) {
    const ushort* kr = KV + ((long)((b << 10) + s)) * 512 + h * 128;
    float d = 0.f;
    for (int c2 = 0; c2 < 128; c2++) d += qs[c2] * b2f(kr[c2]);
    float mv = (srand[nq * 1024 + s] < 0.3f) ? 0.f : -1e9f;
    lg[s] = d * scale + mv;
  }
  __syncthreads();
  float m = -3.4e38f;
  for (int s = tid; s < 1024; s += 256) m = fmaxf(m, lg[s]);
  red[tid] = m; __syncthreads();
  for (int off = 128; off > 0; off >>= 1) { if (tid < off) red[tid] = fmaxf(red[tid], red[tid + off]); __syncthreads(); }
  m = red[0]; __syncthreads();
  float s0 = 0.f;
  for (int s = tid; s < 1024; s += 256) { float e = expf(lg[s] - m); lg[s] = e; s0 += e; }
  red[tid] = s0; __syncthreads();
  for (int off = 128; off > 0; off >>= 1) { if (tid < off) red[tid] += red[tid + off]; __syncthreads(); }
  float denom = red[0]; __syncthreads();
  // PV: two s-halves per column
  int c = tid & 127, half = tid >> 7;
  float acc = 0.f;
  int sBase = half * 512;
  for (int s = sBase; s < sBase + 512; s++)
    acc += lg[s] * b2f(KV[((long)((b << 10) + s)) * 512 + 256 + h * 128 + c]);
  red[tid] = acc; __syncthreads();
  if (tid < 128)
    ATTP[(b * 4 + nq) * 256 + h * 128 + tid] = (red[tid] + red[tid + 128]) / denom;
}

// ---------- combined = [mean over N | pooled_att], 1024 threads ----------
__global__ __launch_bounds__(1024) void combined_kernel(const float* __restrict__ X,
    const float* __restrict__ ATTO, float* __restrict__ CMB)
{
  int b = blockIdx.x, tid = threadIdx.x;
  int d = tid & 255, ch = tid >> 8;
  __shared__ float part[4][256];
  float s = 0.f;
  int n0 = ch * 256;
  for (int n = n0; n < n0 + 256; n++) s += X[((long)((b << 10) + n)) * 256 + d];
  part[ch][d] = s;
  __syncthreads();
  if (ch == 0) {
    float tot = part[0][d] + part[1][d] + part[2][d] + part[3][d];
    CMB[b * 1280 + d] = tot * (1.f / 1024.f);
    #pragma unroll
    for (int q = 0; q < 4; q++)
      CMB[b * 1280 + 256 + q * 256 + d] = ATTO[(b * 4 + q) * 256 + d];
  }
}

__global__ void store_out(const float* __restrict__ src, float* __restrict__ dst, int n) {
  int i = blockIdx.x * blockDim.x + threadIdx.x;
  if (i < n) dst[i] = src[i];
}
__global__ void fill_out_zero(float* __restrict__ dst, int n) {
  int i = blockIdx.x * blockDim.x + threadIdx.x;
  if (i < n) dst[i] = 0.f;
}

extern "C" void kernel_launch(void* const* d_in, const int* in_sizes, int n_in,
                              void* d_out, int out_size, void* d_ws, size_t ws_size,
                              hipStream_t stream)
{
  const float* inp      = (const float*)d_in[0];
  const float* cellp    = (const float*)d_in[1];
  const float* srand    = (const float*)d_in[2];
  const float* emb_W    = (const float*)d_in[3];
  const float* emb_b    = (const float*)d_in[4];
  const float* pe_tab   = (const float*)d_in[5];
  const float* pe_W1    = (const float*)d_in[6];
  const float* pe_b1    = (const float*)d_in[7];
  const float* pe_W2    = (const float*)d_in[8];
  const float* pe_b2    = (const float*)d_in[9];
  const float* gat_W    = (const float*)d_in[10];
  const float* gat_asrc = (const float*)d_in[11];
  const float* gat_adst = (const float*)d_in[12];
  const float* gat_b    = (const float*)d_in[13];
  const float* ln_g     = (const float*)d_in[14];
  const float* ln_b     = (const float*)d_in[15];
  const float* qkv_W    = (const float*)d_in[16];
  const float* qkv_b    = (const float*)d_in[17];
  const float* out_W    = (const float*)d_in[18];
  const float* out_b    = (const float*)d_in[19];
  const float* ff1_W    = (const float*)d_in[20];
  const float* ff1_b    = (const float*)d_in[21];
  const float* ff2_W    = (const float*)d_in[22];
  const float* ff2_b    = (const float*)d_in[23];
  const float* ln1_g    = (const float*)d_in[24];
  const float* ln1_b    = (const float*)d_in[25];
  const float* ln2_g    = (const float*)d_in[26];
  const float* ln2_b    = (const float*)d_in[27];
  const float* q_emb    = (const float*)d_in[28];
  const float* pin_W    = (const float*)d_in[29];
  const float* pin_b    = (const float*)d_in[30];
  const float* pout_W   = (const float*)d_in[31];
  const float* pout_b   = (const float*)d_in[32];
  const float* m1_W     = (const float*)d_in[33];
  const float* m1_b     = (const float*)d_in[34];
  const float* mln1_g   = (const float*)d_in[35];
  const float* mln1_b   = (const float*)d_in[36];
  const float* m2_W     = (const float*)d_in[37];
  const float* m2_b     = (const float*)d_in[38];
  const float* mln2_g   = (const float*)d_in[39];
  const float* mln2_b   = (const float*)d_in[40];
  const float* m3_W     = (const float*)d_in[41];
  const float* m3_b     = (const float*)d_in[42];
  const float* c1_W     = (const float*)d_in[43];
  const float* c1_b     = (const float*)d_in[44];
  const float* c2_W     = (const float*)d_in[45];
  const float* c2_b     = (const float*)d_in[46];
  const float* c3_W     = (const float*)d_in[47];
  const float* c3_b     = (const float*)d_in[48];
  const float* c4_W     = (const float*)d_in[49];
  const float* c4_b     = (const float*)d_in[50];
  (void)in_sizes; (void)n_in;

  // ---- workspace (bytes, 256-aligned; ~20.1 MB) ----
  char* base = (char*)d_ws;
  size_t off = 0;
  auto alloc = [&](size_t bytes) { void* p = base + off; off += (bytes + 255) & ~size_t(255); return p; };
  float* PN    = (float*)alloc(32768);
  float* AS    = (float*)alloc(32768);
  float* AD    = (float*)alloc(32768);
  float* ATTP  = (float*)alloc(16384);
  float* ATTO  = (float*)alloc(16384);
  float* CMB   = (float*)alloc(20480);
  float* Ha    = (float*)alloc(16384);
  float* Hb    = (float*)alloc(16384);
  float* Hc    = (float*)alloc(16640);
  float* Hd    = (float*)alloc(8192);
  float* He    = (float*)alloc(4096);
  float* Hf    = (float*)alloc(512);
  int*   NBR   = (int*)alloc(131072);
  float* X     = (float*)alloc(4194304);          // fp32 residual stream [4096,256]
  ushort* Xb   = (ushort*)alloc(2097152);         // bf16 shadow of X
  char*  Rq    = (char*)alloc(6291456);           // QKVb bf16 | F2 fp32 | KVb bf16
  char*  Rf    = (char*)alloc(4194304);           // Ob bf16 | FFBb bf16 (2048-row chunk)
  ushort* QKVb = (ushort*)Rq;                     // [4096,768]
  float*  F2   = (float*)Rq;                      // [4096,256]
  ushort* KVb  = (ushort*)Rq;                     // [4096,512]
  ushort* Ob   = (ushort*)Rf;                     // [4096,256]
  ushort* FFBb = (ushort*)Rf;                     // [2048,1024]
  float*  F1   = (float*)alloc(4194304);          // GAT h fp32 [4096,256]
  if (ws_size < off) { fill_out_zero<<<1, 128, 0, stream>>>((float*)d_out, out_size); return; }

  // ---- graph construction ----
  bag_stats<<<4, 256, 0, stream>>>(cellp, PN);
  knn_kernel<<<128, 256, 0, stream>>>(PN, NBR);

  // ---- embedding + positional MLP ----
  mgemm<float>(stream, inp, 512, emb_W, 512, emb_b, X, 256, 4096, 256, 512, 0);
  pos_embed<<<dim3(4096, 2), 128, 0, stream>>>(cellp, pe_tab, pe_W1, pe_b1, pe_W2, pe_b2, X);
  cvt_f2b<<<1024, 256, 0, stream>>>(X, Xb, 4096 * 256);

  // ---- 2x GAT ----
  for (int l = 0; l < 2; l++) {
    mgemm<float>(stream, Xb, 256, gat_W + l * 65536, 256, (const float*)nullptr, F1, 256,
                 4096, 256, 256, 0);
    gat_scores<<<4096, 256, 0, stream>>>(F1, gat_asrc + l * 256, gat_adst + l * 256, AS, AD);
    gat_aggr_ln<<<4096, 256, 0, stream>>>(F1, AS, AD, NBR, gat_b + l * 256, ln_g, ln_b, X, Xb);
  }

  // ---- 2x Transformer encoder layer ----
  for (int l = 0; l < 2; l++) {
    mgemm<ushort>(stream, Xb, 256, qkv_W + (long)l * 768 * 256, 256, qkv_b + l * 768,
                  QKVb, 768, 4096, 768, 256, 0);
    flash_attn<<<256, 256, 0, stream>>>(QKVb, Ob);      // QKVb dead after this
    mgemm<float>(stream, Ob, 256, out_W + l * 65536, 256, out_b + l * 256, F2, 256,
                 4096, 256, 256, 0);
    add_ln4<<<1024, 256, 0, stream>>>(X, F2, ln1_g + l * 256, ln1_b + l * 256, X, Xb);
    for (int ch = 0; ch < 2; ch++) {                    // FFN in 2048-row chunks
      mgemm<ushort>(stream, Xb + (long)ch * 2048 * 256, 256, ff1_W + l * 262144, 256,
                    ff1_b + l * 1024, FFBb, 1024, 2048, 1024, 256, 1);
      mgemm<float>(stream, FFBb, 1024, ff2_W + l * 262144, 1024, ff2_b + l * 256,
                   F2 + (long)ch * 2048 * 256, 256, 2048, 256, 1024, 0);
    }
    add_ln4<<<1024, 256, 0, stream>>>(X, F2, ln2_g + l * 256, ln2_b + l * 256, X, Xb);
  }

  // ---- final LN ----
  add_ln4<<<1024, 256, 0, stream>>>((const float*)nullptr, X, ln_g, ln_b, X, Xb);

  // ---- pooling ----
  mgemm<ushort>(stream, Xb, 256, pin_W + 65536, 256, pin_b + 256, KVb, 512, 4096, 512, 256, 0);
  pool_attn<<<32, 256, 0, stream>>>(q_emb, pin_W, pin_b, srand, KVb, ATTP);
  gemm(stream, ATTP, 256, pout_W, 256, pout_b, ATTO, 256, 16, 256, 256, 0);
  combined_kernel<<<4, 1024, 0, stream>>>(X, ATTO, CMB);

  // ---- MLP head (fp32) ----
  gemm(stream, CMB, 1280, m1_W, 1280, m1_b, Ha, 1024, 4, 1024, 1280, 1);
  add_ln_big<<<4, 256, 0, stream>>>(Ha, mln1_g, mln1_b, Ha);
  gemm(stream, Ha, 1024, m2_W, 1024, m2_b, Hb, 1024, 4, 1024, 1024, 1);
  add_ln_big<<<4, 256, 0, stream>>>(Hb, mln2_g, mln2_b, Hb);
  gemm(stream, Hb, 1024, m3_W, 1024, m3_b, Ha, 1024, 4, 1024, 1024, 0);
  gemm(stream, Ha, 1024, c1_W, 1024, c1_b, Hc, 1032, 4, 1032, 1024, 1);
  gemm(stream, Hc, 1032, c2_W, 1032, c2_b, Hd, 512, 4, 512, 1032, 1);
  gemm(stream, Hd, 512, c3_W, 512, c3_b, He, 256, 4, 256, 512, 1);
  gemm(stream, He, 256, c4_W, 256, c4_b, Hf, 24, 4, 24, 256, 0);
  store_out<<<1, 128, 0, stream>>>(Hf, (float*)d_out, out_size);
}

// Round 6
// 1747.316 us; speedup vs baseline: 2.2799x; 1.1750x over previous
//
#include <hip/hip_runtime.h>
#include <hip/hip_bf16.h>

// MILCellModel forward on MI355X. Round 6: MFMA flash attention (bf16 QK^T and
// PV on matrix cores, in-register online softmax via shfl_xor over the C-layout
// row groups, V^T produced by the QKV GEMM epilogue into a 2MB aliased buffer).
// B=4 N=1024 E=512 D=256 H=2 C=128 FF=1024 NQ=4 NCLS=24

typedef __bf16 bf16x8 __attribute__((ext_vector_type(8)));
typedef float  f32x4  __attribute__((ext_vector_type(4)));

__device__ __forceinline__ ushort f2b(float f) {
  __hip_bfloat16 h = __float2bfloat16(f);
  return *(ushort*)&h;
}
__device__ __forceinline__ float b2f(ushort u) {
  union { unsigned i; float f; } v; v.i = ((unsigned)u) << 16; return v.f;
}

// ---------- block reductions (256 threads) ----------
__device__ __forceinline__ float blk_sum256(float v, float* red) {
  int t = threadIdx.x;
  red[t] = v; __syncthreads();
  #pragma unroll
  for (int off = 128; off > 0; off >>= 1) {
    if (t < off) red[t] += red[t + off];
    __syncthreads();
  }
  float r = red[0]; __syncthreads();
  return r;
}

// ---------- fp32 -> bf16 convert ----------
__global__ __launch_bounds__(256) void cvt_f2b(const float* __restrict__ src,
                                               ushort* __restrict__ dst, int n) {
  int i = (blockIdx.x * 256 + threadIdx.x) * 4;
  if (i >= n) return;
  float4 v = *(const float4*)(src + i);
  ushort4 o;
  o.x = f2b(v.x); o.y = f2b(v.y); o.z = f2b(v.z); o.w = f2b(v.w);
  *(ushort4*)(dst + i) = o;
}

// ---------- staging helpers: 8 contiguous elements -> bf16 LDS ----------
__device__ __forceinline__ void stage8(const ushort* __restrict__ src, ushort* dst) {
  *(uint4*)dst = *(const uint4*)src;
}
__device__ __forceinline__ void stage8(const float* __restrict__ src, ushort* dst) {
  float4 a = ((const float4*)src)[0];
  float4 b = ((const float4*)src)[1];
  ushort4 o0, o1;
  o0.x = f2b(a.x); o0.y = f2b(a.y); o0.z = f2b(a.z); o0.w = f2b(a.w);
  o1.x = f2b(b.x); o1.y = f2b(b.y); o1.z = f2b(b.z); o1.w = f2b(b.w);
  *(ushort4*)dst = o0;
  *(ushort4*)(dst + 4) = o1;
}

// ---------- bf16 MFMA GEMM: C[M,N] = act(A[M,K] @ B^T + bias) ----------
// VSPLIT: columns >=512 (the V block of the QKV projection) are written
// TRANSPOSED to VT[b*2+h][c][n] (bf16) instead of to C.
template<typename CT, typename AT, typename WT, bool VSPLIT>
__global__ __launch_bounds__(256) void mfma_gemm(
    const AT* __restrict__ A, int lda,
    const WT* __restrict__ Bw, int ldb,
    const float* __restrict__ bias,
    CT* __restrict__ C, int ldc, int K, int relu,
    ushort* __restrict__ VT)
{
  __shared__ ushort As[64][40];    // +8 pad: conflict-free b128 frag reads
  __shared__ ushort Bs[128][40];
  int tid = threadIdx.x;
  int lane = tid & 63, wave = tid >> 6;
  int wm = wave >> 1, wn = wave & 1;      // 2x2 waves; wave tile = 32x64
  int quad = lane >> 4, l16 = lane & 15;
  long mBase = blockIdx.y * 64, nBase = blockIdx.x * 128;

  f32x4 zero4 = {0.f, 0.f, 0.f, 0.f};
  f32x4 acc[2][4];
  #pragma unroll
  for (int i = 0; i < 2; i++)
    #pragma unroll
    for (int j = 0; j < 4; j++) acc[i][j] = zero4;

  for (int k0 = 0; k0 < K; k0 += 32) {
    {
      int r = tid >> 2, sg = (tid & 3) * 8;          // 64 rows x 32 cols
      stage8(A + (mBase + r) * lda + k0 + sg, &As[r][sg]);
    }
    #pragma unroll
    for (int p = 0; p < 2; p++) {
      int idx = p * 256 + tid;
      int r = idx >> 2, sg = (idx & 3) * 8;          // 128 rows x 32 cols
      stage8(Bw + (nBase + r) * ldb + k0 + sg, &Bs[r][sg]);
    }
    __syncthreads();
    bf16x8 af[2], bfr[4];
    #pragma unroll
    for (int i = 0; i < 2; i++)
      af[i] = *(const bf16x8*)&As[wm * 32 + i * 16 + l16][quad * 8];
    #pragma unroll
    for (int j = 0; j < 4; j++)
      bfr[j] = *(const bf16x8*)&Bs[wn * 64 + j * 16 + l16][quad * 8];
    #pragma unroll
    for (int i = 0; i < 2; i++)
      #pragma unroll
      for (int j = 0; j < 4; j++)
        acc[i][j] = __builtin_amdgcn_mfma_f32_16x16x32_bf16(af[i], bfr[j], acc[i][j], 0, 0, 0);
    __syncthreads();
  }
  // C/D layout: col = lane&15, row = quad*4 + reg
  #pragma unroll
  for (int i = 0; i < 2; i++) {
    #pragma unroll
    for (int j = 0; j < 4; j++) {
      long col = nBase + wn * 64 + j * 16 + l16;
      float bv = bias ? bias[col] : 0.f;
      long row0 = mBase + wm * 32 + i * 16 + quad * 4;
      if (VSPLIT && col >= 512) {
        int cm = (int)col - 512, hh = cm >> 7, cc = cm & 127;
        long bidx = row0 >> 10, n0 = row0 & 1023;
        ushort4 o;
        o.x = f2b(acc[i][j][0] + bv);
        o.y = f2b(acc[i][j][1] + bv);
        o.z = f2b(acc[i][j][2] + bv);
        o.w = f2b(acc[i][j][3] + bv);
        *(ushort4*)&VT[(((bidx * 2 + hh) * 128 + cc) << 10) + n0] = o;
      } else {
        #pragma unroll
        for (int r = 0; r < 4; r++) {
          float v = acc[i][j][r] + bv;
          if (relu) v = fmaxf(v, 0.f);
          if constexpr (sizeof(CT) == 2) C[(row0 + r) * ldc + col] = f2b(v);
          else                           C[(row0 + r) * ldc + col] = v;
        }
      }
    }
  }
}

template<typename CT, typename AT, typename WT>
static void mgemm(hipStream_t st, const AT* A, int lda, const WT* B, int ldb,
                  const float* bias, CT* C, int ldc, int M, int N, int K, int relu) {
  dim3 grid(N / 128, M / 64);
  mfma_gemm<CT, AT, WT, false><<<grid, 256, 0, st>>>(A, lda, B, ldb, bias, C, ldc, K, relu, nullptr);
}
template<typename AT, typename WT>
static void mgemm_vt(hipStream_t st, const AT* A, int lda, const WT* B, int ldb,
                     const float* bias, ushort* C, int ldc, int M, int N, int K, ushort* VT) {
  dim3 grid(N / 128, M / 64);
  mfma_gemm<ushort, AT, WT, true><<<grid, 256, 0, st>>>(A, lda, B, ldb, bias, C, ldc, K, 0, VT);
}

// ---------- fp32 tiled GEMM (head matmuls, M=4..16) ----------
__global__ __launch_bounds__(256) void gemm_kernel(
    const float* __restrict__ A, int lda,
    const float* __restrict__ Bm, int ldb,
    const float* __restrict__ bias,
    float* __restrict__ C, int ldc,
    int M, int N, int K, int relu)
{
  __shared__ float As[16][65];
  __shared__ float Bs[16][65];
  int tid = threadIdx.x;
  int tx = tid & 15, ty = tid >> 4;
  int mBase = blockIdx.y * 64, nBase = blockIdx.x * 64;
  float acc[4][4] = {};

  for (int k0 = 0; k0 < K; k0 += 16) {
    {
      int m = tid >> 2, kk = (tid & 3) * 4;
      int gm = mBase + m;
      #pragma unroll
      for (int i = 0; i < 4; i++) {
        int gk = k0 + kk + i;
        As[kk + i][m] = (gm < M && gk < K) ? A[(long)gm * lda + gk] : 0.f;
      }
    }
    {
      int n = tid >> 2, kk = (tid & 3) * 4;
      int gn = nBase + n;
      #pragma unroll
      for (int i = 0; i < 4; i++) {
        int gk = k0 + kk + i;
        Bs[kk + i][n] = (gn < N && gk < K) ? Bm[(long)gn * ldb + gk] : 0.f;
      }
    }
    __syncthreads();
    #pragma unroll
    for (int kk = 0; kk < 16; kk++) {
      float a[4], b[4];
      #pragma unroll
      for (int i = 0; i < 4; i++) a[i] = As[kk][ty * 4 + i];
      #pragma unroll
      for (int j = 0; j < 4; j++) b[j] = Bs[kk][tx * 4 + j];
      #pragma unroll
      for (int i = 0; i < 4; i++)
        #pragma unroll
        for (int j = 0; j < 4; j++) acc[i][j] += a[i] * b[j];
    }
    __syncthreads();
  }
  #pragma unroll
  for (int i = 0; i < 4; i++) {
    int gm = mBase + ty * 4 + i;
    if (gm >= M) continue;
    #pragma unroll
    for (int j = 0; j < 4; j++) {
      int gn = nBase + tx * 4 + j;
      if (gn >= N) continue;
      float v = acc[i][j];
      if (bias) v += bias[gn];
      if (relu) v = fmaxf(v, 0.f);
      C[(long)gm * ldc + gn] = v;
    }
  }
}

static void gemm(hipStream_t st, const float* A, int lda, const float* B, int ldb,
                 const float* bias, float* C, int ldc, int M, int N, int K, int relu)
{
  dim3 grid((N + 63) / 64, (M + 63) / 64, 1);
  gemm_kernel<<<grid, 256, 0, st>>>(A, lda, B, ldb, bias, C, ldc, M, N, K, relu);
}

// ---------- bag stats ----------
__global__ __launch_bounds__(256) void bag_stats(const float* __restrict__ cp, float* __restrict__ PN) {
  int b = blockIdx.x, tid = threadIdx.x;
  __shared__ float red[256];
  for (int c = 0; c < 2; c++) {
    float s = 0.f;
    for (int n = tid; n < 1024; n += 256) s += cp[((b << 10) + n) * 2 + c];
    float mean = blk_sum256(s, red) * (1.f / 1024.f);
    s = 0.f;
    for (int n = tid; n < 1024; n += 256) { float d = cp[((b << 10) + n) * 2 + c] - mean; s += d * d; }
    float var = blk_sum256(s, red) * (1.f / 1024.f);
    float inv = 1.f / (sqrtf(var) + 1e-8f);
    for (int n = tid; n < 1024; n += 256)
      PN[((b << 10) + n) * 2 + c] = (cp[((b << 10) + n) * 2 + c] - mean) * inv;
  }
}

// ---------- kNN: parallel stable top-8 ----------
__global__ __launch_bounds__(256) void knn_kernel(const float* __restrict__ PN, int* __restrict__ NBR) {
  int blk = blockIdx.x;              // 128 blocks
  int b = blk >> 5, tg = blk & 31;   // 32 targets per block
  int tid = threadIdx.x;
  int tl = tid >> 3, chunk = tid & 7;
  __shared__ float px[1024], py[1024];
  __shared__ float candD[32][64];
  __shared__ int   candI[32][64];
  for (int i = tid; i < 1024; i += 256) {
    px[i] = PN[((b << 10) + i) * 2 + 0];
    py[i] = PN[((b << 10) + i) * 2 + 1];
  }
  __syncthreads();
  int t = tg * 32 + tl;
  float tx = px[t], ty = py[t];
  float d8[8]; int i8[8];
  #pragma unroll
  for (int i = 0; i < 8; i++) { d8[i] = 3.4e38f; i8[i] = 0x7fffffff; }
  int s0 = chunk * 128;
  for (int s = s0; s < s0 + 128; s++) {
    float dx = __fadd_rn(px[s], -tx), dy = __fadd_rn(py[s], -ty);
    float d2 = __fadd_rn(__fadd_rn(__fmul_rn(dx, dx), __fmul_rn(dy, dy)), 1e-12f);
    float d = sqrtf(d2);
    if (d < d8[7]) {
      d8[7] = d; i8[7] = s;
      #pragma unroll
      for (int p = 7; p > 0; p--) {
        if (d8[p] < d8[p - 1]) {
          float td = d8[p]; d8[p] = d8[p - 1]; d8[p - 1] = td;
          int ti = i8[p]; i8[p] = i8[p - 1]; i8[p - 1] = ti;
        }
      }
    }
  }
  #pragma unroll
  for (int i = 0; i < 8; i++) { candD[tl][chunk * 8 + i] = d8[i]; candI[tl][chunk * 8 + i] = i8[i]; }
  __syncthreads();
  if (chunk == 0) {
    float D[8]; int I[8];
    #pragma unroll
    for (int i = 0; i < 8; i++) { D[i] = candD[tl][i]; I[i] = candI[tl][i]; }
    for (int c = 1; c < 8; c++) {
      for (int j = 0; j < 8; j++) {
        float d = candD[tl][c * 8 + j]; int idx = candI[tl][c * 8 + j];
        bool better = (d < D[7]) || (d == D[7] && idx < I[7]);
        if (!better) break;
        D[7] = d; I[7] = idx;
        #pragma unroll
        for (int p = 7; p > 0; p--) {
          bool sw = (D[p] < D[p - 1]) || (D[p] == D[p - 1] && I[p] < I[p - 1]);
          if (sw) {
            float td = D[p]; D[p] = D[p - 1]; D[p - 1] = td;
            int ti = I[p]; I[p] = I[p - 1]; I[p - 1] = ti;
          }
        }
      }
    }
    #pragma unroll
    for (int i = 0; i < 8; i++) NBR[((long)((b << 10) + t)) * 8 + i] = I[i];
  }
}

// ---------- positional embedding MLP ----------
__global__ __launch_bounds__(128) void pos_embed(
    const float* __restrict__ cellp, const float* __restrict__ tab,
    const float* __restrict__ W1, const float* __restrict__ b1,
    const float* __restrict__ W2, const float* __restrict__ b2,
    float* __restrict__ X)
{
  int row = blockIdx.x, c = blockIdx.y, tid = threadIdx.x;
  __shared__ float e[128], h1[128];
  float pos = cellp[row * 2 + c];
  pos = fminf(fmaxf(pos, 0.f), 1000.f);
  int pi = (int)pos;
  e[tid] = tab[((long)(c * 1001 + pi)) * 128 + tid];
  __syncthreads();
  {
    const float* w1r = W1 + ((long)(c * 128 + tid)) * 128;
    float a = b1[c * 128 + tid];
    for (int i = 0; i < 128; i++) a += e[i] * w1r[i];
    h1[tid] = fmaxf(a, 0.f);
  }
  __syncthreads();
  {
    const float* w2r = W2 + ((long)(c * 128 + tid)) * 128;
    float o = b2[c * 128 + tid];
    for (int i = 0; i < 128; i++) o += h1[i] * w2r[i];
    X[(long)row * 256 + c * 128 + tid] += o;
  }
}

// ---------- GAT scores ----------
__global__ __launch_bounds__(256) void gat_scores(const float* __restrict__ Hh,
    const float* __restrict__ asrcW, const float* __restrict__ adstW,
    float* __restrict__ ASRC, float* __restrict__ ADST)
{
  int row = blockIdx.x, tid = threadIdx.x;
  __shared__ float red[256];
  float v = Hh[(long)row * 256 + tid];
  float s1 = v * asrcW[tid];
  float s2 = v * adstW[tid];
  red[tid] = s1; __syncthreads();
  for (int off = 64; off > 0; off >>= 1) { if ((tid & 127) < off) red[tid] += red[tid + off]; __syncthreads(); }
  if ((tid & 127) == 0) ASRC[row * 2 + (tid >> 7)] = red[tid];
  __syncthreads();
  red[tid] = s2; __syncthreads();
  for (int off = 64; off > 0; off >>= 1) { if ((tid & 127) < off) red[tid] += red[tid + off]; __syncthreads(); }
  if ((tid & 127) == 0) ADST[row * 2 + (tid >> 7)] = red[tid];
}

// ---------- GAT aggregate + residual + LN (emits fp32 X and bf16 Xb) ----------
__global__ __launch_bounds__(256) void gat_aggr_ln(
    const float* __restrict__ Hh, const float* __restrict__ ASRC, const float* __restrict__ ADST,
    const int* __restrict__ NBR, const float* __restrict__ gbias,
    const float* __restrict__ lng, const float* __restrict__ lnb,
    float* __restrict__ X, ushort* __restrict__ Xb)
{
  int row = blockIdx.x, tid = threadIdx.x;
  int b = row >> 10;
  __shared__ int nb[8];
  __shared__ float w[2][8];
  __shared__ float red[256];
  if (tid < 8) {
    int v = NBR[(long)row * 8 + tid];
    nb[tid] = min(max(v, 0), 1023);
  }
  __syncthreads();
  if (tid < 16) {
    int i = tid & 7, h = tid >> 3;
    float e = ADST[row * 2 + h] + ASRC[((b << 10) + nb[i]) * 2 + h];
    w[h][i] = (e >= 0.f) ? e : 0.2f * e;
  }
  __syncthreads();
  if (tid < 2) {
    float m = -3.4e38f;
    for (int i = 0; i < 8; i++) m = fmaxf(m, w[tid][i]);
    float s = 0.f;
    for (int i = 0; i < 8; i++) { float e = expf(w[tid][i] - m); w[tid][i] = e; s += e; }
    float inv = 1.f / s;
    for (int i = 0; i < 8; i++) w[tid][i] *= inv;
  }
  __syncthreads();
  int h = tid >> 7, c = tid & 127;
  float acc = 0.f;
  #pragma unroll
  for (int i = 0; i < 8; i++)
    acc += w[h][i] * Hh[((long)((b << 10) + nb[i])) * 256 + h * 128 + c];
  float v = acc + gbias[tid] + X[(long)row * 256 + tid];
  float mean = blk_sum256(v, red) * (1.f / 256.f);
  float dv = v - mean;
  float var = blk_sum256(dv * dv, red) * (1.f / 256.f);
  float o = dv * rsqrtf(var + 1e-5f) * lng[tid] + lnb[tid];
  X[(long)row * 256 + tid] = o;
  Xb[(long)row * 256 + tid] = f2b(o);
}

// ---------- residual + LayerNorm, D=256, one wave per row ----------
__global__ __launch_bounds__(256) void add_ln4(const float* __restrict__ res,
    const float* __restrict__ Yv, const float* __restrict__ g, const float* __restrict__ b,
    float* __restrict__ out, ushort* __restrict__ outb)
{
  int wave = threadIdx.x >> 6, lane = threadIdx.x & 63;
  long row = blockIdx.x * 4 + wave;
  const float* yr = Yv + row * 256;
  const float* rr = res ? res + row * 256 : nullptr;
  float v[4];
  float s = 0.f;
  #pragma unroll
  for (int i = 0; i < 4; i++) {
    int d = lane + i * 64;
    float x = yr[d];
    if (rr) x += rr[d];
    v[i] = x; s += x;
  }
  #pragma unroll
  for (int off = 32; off > 0; off >>= 1) s += __shfl_xor(s, off);
  float mean = s * (1.f / 256.f);
  float vs = 0.f;
  #pragma unroll
  for (int i = 0; i < 4; i++) { float dv = v[i] - mean; vs += dv * dv; }
  #pragma unroll
  for (int off = 32; off > 0; off >>= 1) vs += __shfl_xor(vs, off);
  float rstd = rsqrtf(vs * (1.f / 256.f) + 1e-5f);
  #pragma unroll
  for (int i = 0; i < 4; i++) {
    int d = lane + i * 64;
    float o = (v[i] - mean) * rstd * g[d] + b[d];
    out[row * 256 + d] = o;
    if (outb) outb[row * 256 + d] = f2b(o);
  }
}

// ---------- LayerNorm (D=1024, head rows) ----------
__global__ __launch_bounds__(256) void add_ln_big(const float* __restrict__ Yv,
    const float* __restrict__ g, const float* __restrict__ b,
    float* __restrict__ out)
{
  int row = blockIdx.x, tid = threadIdx.x;
  __shared__ float red[256];
  float vals[4];
  float s = 0.f;
  #pragma unroll
  for (int i = 0; i < 4; i++) {
    int d = tid + (i << 8);
    float v = Yv[(long)row * 1024 + d];
    vals[i] = v; s += v;
  }
  float mean = blk_sum256(s, red) * (1.f / 1024.f);
  s = 0.f;
  #pragma unroll
  for (int i = 0; i < 4; i++) { float dv = vals[i] - mean; s += dv * dv; }
  float var = blk_sum256(s, red) * (1.f / 1024.f);
  float rstd = rsqrtf(var + 1e-5f);
  #pragma unroll
  for (int i = 0; i < 4; i++) {
    int d = tid + (i << 8);
    out[(long)row * 1024 + d] = (vals[i] - mean) * rstd * g[d] + b[d];
  }
}

// ---------- MFMA flash attention ----------
// QKV [B*N,768] bf16 (q|k cols 0..511, V comes from VT). VT [B*H][128][1024].
// Block = (b,h,qtile64): grid 256, 4 waves x 16 q-rows. Online softmax in
// registers (row = quad*4+reg; col-group reduce via shfl_xor 1/2/4/8).
__global__ __launch_bounds__(256) void flash_mfma(const ushort* __restrict__ QKV,
                                                  const ushort* __restrict__ VT,
                                                  ushort* __restrict__ O)
{
  const float scale = 0.08838834764831845f;
  int blk = blockIdx.x;
  int qt = blk & 15, bh = blk >> 4;
  int b = bh >> 1, h = bh & 1;
  const ushort* qkg = QKV + (long)b * 1024 * 768 + h * 128;
  const ushort* vtg = VT + ((long)bh << 17);   // bh*128*1024

  __shared__ ushort Qs[64][136];
  __shared__ ushort Ks[64][136];
  __shared__ ushort Vt[128][72];
  __shared__ ushort Ps[4][16][72];

  int tid = threadIdx.x;
  int wave = tid >> 6, lane = tid & 63;
  int quad = lane >> 4, l16 = lane & 15;

  // stage Q tile (64 rows x 128)
  #pragma unroll
  for (int p = 0; p < 4; p++) {
    int idx = p * 256 + tid;
    int r = idx >> 4, c8 = (idx & 15) * 8;
    *(uint4*)&Qs[r][c8] = *(const uint4*)(qkg + (long)(qt * 64 + r) * 768 + c8);
  }
  __syncthreads();
  bf16x8 af[4];
  #pragma unroll
  for (int ks = 0; ks < 4; ks++)
    af[ks] = *(const bf16x8*)&Qs[wave * 16 + l16][ks * 32 + quad * 8];

  f32x4 Oacc[8];
  f32x4 zero4 = {0.f, 0.f, 0.f, 0.f};
  #pragma unroll
  for (int j = 0; j < 8; j++) Oacc[j] = zero4;
  float mr[4], lr[4];
  #pragma unroll
  for (int r = 0; r < 4; r++) { mr[r] = -3.4e38f; lr[r] = 0.f; }

  for (int kt = 0; kt < 16; kt++) {
    __syncthreads();   // prior tile's reads done before overwrite
    // stage K tile (64 x 128) and V^T tile (128 x 64)
    #pragma unroll
    for (int p = 0; p < 4; p++) {
      int idx = p * 256 + tid;
      int r = idx >> 4, c8 = (idx & 15) * 8;
      *(uint4*)&Ks[r][c8] = *(const uint4*)(qkg + (long)(kt * 64 + r) * 768 + 256 + c8);
      int c = idx >> 3, k8 = (idx & 7) * 8;
      *(uint4*)&Vt[c][k8] = *(const uint4*)(vtg + ((long)c << 10) + kt * 64 + k8);
    }
    __syncthreads();
    // S = Q K^T  (16 q-rows x 64 k per wave)
    f32x4 acc[4];
    #pragma unroll
    for (int j = 0; j < 4; j++) acc[j] = zero4;
    #pragma unroll
    for (int ks = 0; ks < 4; ks++) {
      #pragma unroll
      for (int j = 0; j < 4; j++) {
        bf16x8 kb = *(const bf16x8*)&Ks[j * 16 + l16][ks * 32 + quad * 8];
        acc[j] = __builtin_amdgcn_mfma_f32_16x16x32_bf16(af[ks], kb, acc[j], 0, 0, 0);
      }
    }
    // online softmax: row = quad*4+r, cols spread over l16 (16 lanes) x 4 regs
    float sv[4][4], tmax[4];
    #pragma unroll
    for (int r = 0; r < 4; r++) tmax[r] = -3.4e38f;
    #pragma unroll
    for (int j = 0; j < 4; j++)
      #pragma unroll
      for (int r = 0; r < 4; r++) {
        float x = acc[j][r] * scale;
        sv[j][r] = x;
        tmax[r] = fmaxf(tmax[r], x);
      }
    #pragma unroll
    for (int off = 1; off < 16; off <<= 1)
      #pragma unroll
      for (int r = 0; r < 4; r++) tmax[r] = fmaxf(tmax[r], __shfl_xor(tmax[r], off));
    float alpha[4], rsum[4];
    #pragma unroll
    for (int r = 0; r < 4; r++) {
      float mn = fmaxf(mr[r], tmax[r]);
      alpha[r] = expf(mr[r] - mn);
      mr[r] = mn;
      rsum[r] = 0.f;
    }
    #pragma unroll
    for (int j = 0; j < 4; j++)
      #pragma unroll
      for (int r = 0; r < 4; r++) {
        float p = expf(sv[j][r] - mr[r]);
        sv[j][r] = p;
        rsum[r] += p;
      }
    #pragma unroll
    for (int off = 1; off < 16; off <<= 1)
      #pragma unroll
      for (int r = 0; r < 4; r++) rsum[r] += __shfl_xor(rsum[r], off);
    #pragma unroll
    for (int r = 0; r < 4; r++) lr[r] = lr[r] * alpha[r] + rsum[r];
    // P (C layout) -> LDS -> A layout; rescale O
    #pragma unroll
    for (int j = 0; j < 4; j++)
      #pragma unroll
      for (int r = 0; r < 4; r++)
        Ps[wave][quad * 4 + r][j * 16 + l16] = f2b(sv[j][r]);
    #pragma unroll
    for (int jj = 0; jj < 8; jj++)
      #pragma unroll
      for (int r = 0; r < 4; r++) Oacc[jj][r] *= alpha[r];
    __syncthreads();   // P write -> read ordering (uniform; also drains lgkm)
    // O += P V  (A = P [16 x 64], B = Vt [c][k])
    #pragma unroll
    for (int s = 0; s < 2; s++) {
      bf16x8 pa = *(const bf16x8*)&Ps[wave][l16][s * 32 + quad * 8];
      #pragma unroll
      for (int jj = 0; jj < 8; jj++) {
        bf16x8 vb = *(const bf16x8*)&Vt[jj * 16 + l16][s * 32 + quad * 8];
        Oacc[jj] = __builtin_amdgcn_mfma_f32_16x16x32_bf16(pa, vb, Oacc[jj], 0, 0, 0);
      }
    }
  }
  // epilogue: divide by l, store bf16
  long row0 = (long)b * 1024 + qt * 64 + wave * 16 + quad * 4;
  #pragma unroll
  for (int jj = 0; jj < 8; jj++) {
    int col = h * 128 + jj * 16 + l16;
    #pragma unroll
    for (int r = 0; r < 4; r++)
      O[(row0 + r) * 256 + col] = f2b(Oacc[jj][r] / lr[r]);
  }
}

// ---------- sparse pooling attention (bf16 KV, 256 threads) ----------
__global__ __launch_bounds__(256) void pool_attn(
    const float* __restrict__ qe, const float* __restrict__ pinW, const float* __restrict__ pinB,
    const float* __restrict__ srand, const ushort* __restrict__ KV, float* __restrict__ ATTP)
{
  int id = blockIdx.x;   // 32 blocks: b*8 + nq*2 + h
  int h = id & 1, nq = (id >> 1) & 3, b = id >> 3;
  int tid = threadIdx.x;
  __shared__ float qs[128];
  __shared__ float lg[1024];
  __shared__ float red[256];
  if (tid < 128) {
    float a = pinB[h * 128 + tid];
    const float* wr = pinW + ((long)(h * 128 + tid)) * 256;
    const float* qr = qe + nq * 256;
    for (int i = 0; i < 256; i++) a += qr[i] * wr[i];
    qs[tid] = a;
  }
  __syncthreads();
  const float scale = 0.08838834764831845f;
  for (int s = tid; s < 1024; s += 256) {
    const ushort* kr = KV + ((long)((b << 10) + s)) * 512 + h * 128;
    float d = 0.f;
    for (int c2 = 0; c2 < 128; c2++) d += qs[c2] * b2f(kr[c2]);
    float mv = (srand[nq * 1024 + s] < 0.3f) ? 0.f : -1e9f;
    lg[s] = d * scale + mv;
  }
  __syncthreads();
  float m = -3.4e38f;
  for (int s = tid; s < 1024; s += 256) m = fmaxf(m, lg[s]);
  red[tid] = m; __syncthreads();
  for (int off = 128; off > 0; off >>= 1) { if (tid < off) red[tid] = fmaxf(red[tid], red[tid + off]); __syncthreads(); }
  m = red[0]; __syncthreads();
  float s0 = 0.f;
  for (int s = tid; s < 1024; s += 256) { float e = expf(lg[s] - m); lg[s] = e; s0 += e; }
  red[tid] = s0; __syncthreads();
  for (int off = 128; off > 0; off >>= 1) { if (tid < off) red[tid] += red[tid + off]; __syncthreads(); }
  float denom = red[0]; __syncthreads();
  int c = tid & 127, half = tid >> 7;
  float acc = 0.f;
  int sBase = half * 512;
  for (int s = sBase; s < sBase + 512; s++)
    acc += lg[s] * b2f(KV[((long)((b << 10) + s)) * 512 + 256 + h * 128 + c]);
  red[tid] = acc; __syncthreads();
  if (tid < 128)
    ATTP[(b * 4 + nq) * 256 + h * 128 + tid] = (red[tid] + red[tid + 128]) / denom;
}

// ---------- combined = [mean over N | pooled_att], 1024 threads ----------
__global__ __launch_bounds__(1024) void combined_kernel(const float* __restrict__ X,
    const float* __restrict__ ATTO, float* __restrict__ CMB)
{
  int b = blockIdx.x, tid = threadIdx.x;
  int d = tid & 255, ch = tid >> 8;
  __shared__ float part[4][256];
  float s = 0.f;
  int n0 = ch * 256;
  for (int n = n0; n < n0 + 256; n++) s += X[((long)((b << 10) + n)) * 256 + d];
  part[ch][d] = s;
  __syncthreads();
  if (ch == 0) {
    float tot = part[0][d] + part[1][d] + part[2][d] + part[3][d];
    CMB[b * 1280 + d] = tot * (1.f / 1024.f);
    #pragma unroll
    for (int q = 0; q < 4; q++)
      CMB[b * 1280 + 256 + q * 256 + d] = ATTO[(b * 4 + q) * 256 + d];
  }
}

__global__ void store_out(const float* __restrict__ src, float* __restrict__ dst, int n) {
  int i = blockIdx.x * blockDim.x + threadIdx.x;
  if (i < n) dst[i] = src[i];
}
__global__ void fill_out_zero(float* __restrict__ dst, int n) {
  int i = blockIdx.x * blockDim.x + threadIdx.x;
  if (i < n) dst[i] = 0.f;
}

extern "C" void kernel_launch(void* const* d_in, const int* in_sizes, int n_in,
                              void* d_out, int out_size, void* d_ws, size_t ws_size,
                              hipStream_t stream)
{
  const float* inp      = (const float*)d_in[0];
  const float* cellp    = (const float*)d_in[1];
  const float* srand    = (const float*)d_in[2];
  const float* emb_W    = (const float*)d_in[3];
  const float* emb_b    = (const float*)d_in[4];
  const float* pe_tab   = (const float*)d_in[5];
  const float* pe_W1    = (const float*)d_in[6];
  const float* pe_b1    = (const float*)d_in[7];
  const float* pe_W2    = (const float*)d_in[8];
  const float* pe_b2    = (const float*)d_in[9];
  const float* gat_W    = (const float*)d_in[10];
  const float* gat_asrc = (const float*)d_in[11];
  const float* gat_adst = (const float*)d_in[12];
  const float* gat_b    = (const float*)d_in[13];
  const float* ln_g     = (const float*)d_in[14];
  const float* ln_b     = (const float*)d_in[15];
  const float* qkv_W    = (const float*)d_in[16];
  const float* qkv_b    = (const float*)d_in[17];
  const float* out_W    = (const float*)d_in[18];
  const float* out_b    = (const float*)d_in[19];
  const float* ff1_W    = (const float*)d_in[20];
  const float* ff1_b    = (const float*)d_in[21];
  const float* ff2_W    = (const float*)d_in[22];
  const float* ff2_b    = (const float*)d_in[23];
  const float* ln1_g    = (const float*)d_in[24];
  const float* ln1_b    = (const float*)d_in[25];
  const float* ln2_g    = (const float*)d_in[26];
  const float* ln2_b    = (const float*)d_in[27];
  const float* q_emb    = (const float*)d_in[28];
  const float* pin_W    = (const float*)d_in[29];
  const float* pin_b    = (const float*)d_in[30];
  const float* pout_W   = (const float*)d_in[31];
  const float* pout_b   = (const float*)d_in[32];
  const float* m1_W     = (const float*)d_in[33];
  const float* m1_b     = (const float*)d_in[34];
  const float* mln1_g   = (const float*)d_in[35];
  const float* mln1_b   = (const float*)d_in[36];
  const float* m2_W     = (const float*)d_in[37];
  const float* m2_b     = (const float*)d_in[38];
  const float* mln2_g   = (const float*)d_in[39];
  const float* mln2_b   = (const float*)d_in[40];
  const float* m3_W     = (const float*)d_in[41];
  const float* m3_b     = (const float*)d_in[42];
  const float* c1_W     = (const float*)d_in[43];
  const float* c1_b     = (const float*)d_in[44];
  const float* c2_W     = (const float*)d_in[45];
  const float* c2_b     = (const float*)d_in[46];
  const float* c3_W     = (const float*)d_in[47];
  const float* c3_b     = (const float*)d_in[48];
  const float* c4_W     = (const float*)d_in[49];
  const float* c4_b     = (const float*)d_in[50];
  (void)in_sizes; (void)n_in;

  // ---- workspace (bytes, 256-aligned; ~20.1 MB) ----
  char* base = (char*)d_ws;
  size_t off = 0;
  auto alloc = [&](size_t bytes) { void* p = base + off; off += (bytes + 255) & ~size_t(255); return p; };
  float* PN    = (float*)alloc(32768);
  float* AS    = (float*)alloc(32768);
  float* AD    = (float*)alloc(32768);
  float* ATTP  = (float*)alloc(16384);
  float* ATTO  = (float*)alloc(16384);
  float* CMB   = (float*)alloc(20480);
  float* Ha    = (float*)alloc(16384);
  float* Hb    = (float*)alloc(16384);
  float* Hc    = (float*)alloc(16640);
  float* Hd    = (float*)alloc(8192);
  float* He    = (float*)alloc(4096);
  float* Hf    = (float*)alloc(512);
  int*   NBR   = (int*)alloc(131072);
  float* X     = (float*)alloc(4194304);          // fp32 residual stream [4096,256]
  ushort* Xb   = (ushort*)alloc(2097152);         // bf16 shadow of X
  char*  Rq    = (char*)alloc(6291456);           // QKVb bf16 | F2 fp32 | KVb bf16
  char*  Rf    = (char*)alloc(4194304);           // Ob | VT | FFBb (time-sliced)
  ushort* QKVb = (ushort*)Rq;                     // [4096,768] (V cols stale/unused)
  float*  F2   = (float*)Rq;                      // [4096,256]
  ushort* KVb  = (ushort*)Rq;                     // [4096,512]
  ushort* Ob   = (ushort*)Rf;                     // [4096,256]  (2 MB)
  ushort* VT   = (ushort*)(Rf + 2097152);         // [8][128][1024] (2 MB)
  ushort* FFBb = (ushort*)Rf;                     // [2048,1024] (4 MB, after flash)
  float*  F1   = (float*)alloc(4194304);          // GAT h fp32 [4096,256]
  if (ws_size < off) { fill_out_zero<<<1, 128, 0, stream>>>((float*)d_out, out_size); return; }

  // ---- graph construction ----
  bag_stats<<<4, 256, 0, stream>>>(cellp, PN);
  knn_kernel<<<128, 256, 0, stream>>>(PN, NBR);

  // ---- embedding + positional MLP ----
  mgemm<float>(stream, inp, 512, emb_W, 512, emb_b, X, 256, 4096, 256, 512, 0);
  pos_embed<<<dim3(4096, 2), 128, 0, stream>>>(cellp, pe_tab, pe_W1, pe_b1, pe_W2, pe_b2, X);
  cvt_f2b<<<1024, 256, 0, stream>>>(X, Xb, 4096 * 256);

  // ---- 2x GAT ----
  for (int l = 0; l < 2; l++) {
    mgemm<float>(stream, Xb, 256, gat_W + l * 65536, 256, (const float*)nullptr, F1, 256,
                 4096, 256, 256, 0);
    gat_scores<<<4096, 256, 0, stream>>>(F1, gat_asrc + l * 256, gat_adst + l * 256, AS, AD);
    gat_aggr_ln<<<4096, 256, 0, stream>>>(F1, AS, AD, NBR, gat_b + l * 256, ln_g, ln_b, X, Xb);
  }

  // ---- 2x Transformer encoder layer ----
  for (int l = 0; l < 2; l++) {
    mgemm_vt(stream, Xb, 256, qkv_W + (long)l * 768 * 256, 256, qkv_b + l * 768,
             QKVb, 768, 4096, 768, 256, VT);
    flash_mfma<<<256, 256, 0, stream>>>(QKVb, VT, Ob);
    mgemm<float>(stream, Ob, 256, out_W + l * 65536, 256, out_b + l * 256, F2, 256,
                 4096, 256, 256, 0);
    add_ln4<<<1024, 256, 0, stream>>>(X, F2, ln1_g + l * 256, ln1_b + l * 256, X, Xb);
    for (int ch = 0; ch < 2; ch++) {                    // FFN in 2048-row chunks
      mgemm<ushort>(stream, Xb + (long)ch * 2048 * 256, 256, ff1_W + l * 262144, 256,
                    ff1_b + l * 1024, FFBb, 1024, 2048, 1024, 256, 1);
      mgemm<float>(stream, FFBb, 1024, ff2_W + l * 262144, 1024, ff2_b + l * 256,
                   F2 + (long)ch * 2048 * 256, 256, 2048, 256, 1024, 0);
    }
    add_ln4<<<1024, 256, 0, stream>>>(X, F2, ln2_g + l * 256, ln2_b + l * 256, X, Xb);
  }

  // ---- final LN ----
  add_ln4<<<1024, 256, 0, stream>>>((const float*)nullptr, X, ln_g, ln_b, X, Xb);

  // ---- pooling ----
  mgemm<ushort>(stream, Xb, 256, pin_W + 65536, 256, pin_b + 256, KVb, 512, 4096, 512, 256, 0);
  pool_attn<<<32, 256, 0, stream>>>(q_emb, pin_W, pin_b, srand, KVb, ATTP);
  gemm(stream, ATTP, 256, pout_W, 256, pout_b, ATTO, 256, 16, 256, 256, 0);
  combined_kernel<<<4, 1024, 0, stream>>>(X, ATTO, CMB);

  // ---- MLP head (fp32) ----
  gemm(stream, CMB, 1280, m1_W, 1280, m1_b, Ha, 1024, 4, 1024, 1280, 1);
  add_ln_big<<<4, 256, 0, stream>>>(Ha, mln1_g, mln1_b, Ha);
  gemm(stream, Ha, 1024, m2_W, 1024, m2_b, Hb, 1024, 4, 1024, 1024, 1);
  add_ln_big<<<4, 256, 0, stream>>>(Hb, mln2_g, mln2_b, Hb);
  gemm(stream, Hb, 1024, m3_W, 1024, m3_b, Ha, 1024, 4, 1024, 1024, 0);
  gemm(stream, Ha, 1024, c1_W, 1024, c1_b, Hc, 1032, 4, 1032, 1024, 1);
  gemm(stream, Hc, 1032, c2_W, 1032, c2_b, Hd, 512, 4, 512, 1032, 1);
  gemm(stream, Hd, 512, c3_W, 512, c3_b, He, 256, 4, 256, 512, 1);
  gemm(stream, He, 256, c4_W, 256, c4_b, Hf, 24, 4, 24, 256, 0);
  store_out<<<1, 128, 0, stream>>>(Hf, (float*)d_out, out_size);
}

// Round 7
// 1055.836 us; speedup vs baseline: 3.7731x; 1.6549x over previous
//
#include <hip/hip_runtime.h>
#include <hip/hip_bf16.h>

// MILCellModel forward on MI355X. Round 7: split-K skinny GEMM for the head
// MLP (M=4) and pool-out (M=16) -- the R6 profile showed these latency-bound
// at 167us each with 16 blocks / 0.8% VALUBusy. Everything else as R6.
// B=4 N=1024 E=512 D=256 H=2 C=128 FF=1024 NQ=4 NCLS=24

typedef __bf16 bf16x8 __attribute__((ext_vector_type(8)));
typedef float  f32x4  __attribute__((ext_vector_type(4)));

__device__ __forceinline__ ushort f2b(float f) {
  __hip_bfloat16 h = __float2bfloat16(f);
  return *(ushort*)&h;
}
__device__ __forceinline__ float b2f(ushort u) {
  union { unsigned i; float f; } v; v.i = ((unsigned)u) << 16; return v.f;
}

// ---------- block reductions (256 threads) ----------
__device__ __forceinline__ float blk_sum256(float v, float* red) {
  int t = threadIdx.x;
  red[t] = v; __syncthreads();
  #pragma unroll
  for (int off = 128; off > 0; off >>= 1) {
    if (t < off) red[t] += red[t + off];
    __syncthreads();
  }
  float r = red[0]; __syncthreads();
  return r;
}

// ---------- fp32 -> bf16 convert ----------
__global__ __launch_bounds__(256) void cvt_f2b(const float* __restrict__ src,
                                               ushort* __restrict__ dst, int n) {
  int i = (blockIdx.x * 256 + threadIdx.x) * 4;
  if (i >= n) return;
  float4 v = *(const float4*)(src + i);
  ushort4 o;
  o.x = f2b(v.x); o.y = f2b(v.y); o.z = f2b(v.z); o.w = f2b(v.w);
  *(ushort4*)(dst + i) = o;
}

// ---------- staging helpers: 8 contiguous elements -> bf16 LDS ----------
__device__ __forceinline__ void stage8(const ushort* __restrict__ src, ushort* dst) {
  *(uint4*)dst = *(const uint4*)src;
}
__device__ __forceinline__ void stage8(const float* __restrict__ src, ushort* dst) {
  float4 a = ((const float4*)src)[0];
  float4 b = ((const float4*)src)[1];
  ushort4 o0, o1;
  o0.x = f2b(a.x); o0.y = f2b(a.y); o0.z = f2b(a.z); o0.w = f2b(a.w);
  o1.x = f2b(b.x); o1.y = f2b(b.y); o1.z = f2b(b.z); o1.w = f2b(b.w);
  *(ushort4*)dst = o0;
  *(ushort4*)(dst + 4) = o1;
}

// ---------- bf16 MFMA GEMM: C[M,N] = act(A[M,K] @ B^T + bias) ----------
// VSPLIT: columns >=512 (the V block of the QKV projection) are written
// TRANSPOSED to VT[b*2+h][c][n] (bf16) instead of to C.
template<typename CT, typename AT, typename WT, bool VSPLIT>
__global__ __launch_bounds__(256) void mfma_gemm(
    const AT* __restrict__ A, int lda,
    const WT* __restrict__ Bw, int ldb,
    const float* __restrict__ bias,
    CT* __restrict__ C, int ldc, int K, int relu,
    ushort* __restrict__ VT)
{
  __shared__ ushort As[64][40];    // +8 pad: conflict-free b128 frag reads
  __shared__ ushort Bs[128][40];
  int tid = threadIdx.x;
  int lane = tid & 63, wave = tid >> 6;
  int wm = wave >> 1, wn = wave & 1;      // 2x2 waves; wave tile = 32x64
  int quad = lane >> 4, l16 = lane & 15;
  long mBase = blockIdx.y * 64, nBase = blockIdx.x * 128;

  f32x4 zero4 = {0.f, 0.f, 0.f, 0.f};
  f32x4 acc[2][4];
  #pragma unroll
  for (int i = 0; i < 2; i++)
    #pragma unroll
    for (int j = 0; j < 4; j++) acc[i][j] = zero4;

  for (int k0 = 0; k0 < K; k0 += 32) {
    {
      int r = tid >> 2, sg = (tid & 3) * 8;          // 64 rows x 32 cols
      stage8(A + (mBase + r) * lda + k0 + sg, &As[r][sg]);
    }
    #pragma unroll
    for (int p = 0; p < 2; p++) {
      int idx = p * 256 + tid;
      int r = idx >> 2, sg = (idx & 3) * 8;          // 128 rows x 32 cols
      stage8(Bw + (nBase + r) * ldb + k0 + sg, &Bs[r][sg]);
    }
    __syncthreads();
    bf16x8 af[2], bfr[4];
    #pragma unroll
    for (int i = 0; i < 2; i++)
      af[i] = *(const bf16x8*)&As[wm * 32 + i * 16 + l16][quad * 8];
    #pragma unroll
    for (int j = 0; j < 4; j++)
      bfr[j] = *(const bf16x8*)&Bs[wn * 64 + j * 16 + l16][quad * 8];
    #pragma unroll
    for (int i = 0; i < 2; i++)
      #pragma unroll
      for (int j = 0; j < 4; j++)
        acc[i][j] = __builtin_amdgcn_mfma_f32_16x16x32_bf16(af[i], bfr[j], acc[i][j], 0, 0, 0);
    __syncthreads();
  }
  // C/D layout: col = lane&15, row = quad*4 + reg
  #pragma unroll
  for (int i = 0; i < 2; i++) {
    #pragma unroll
    for (int j = 0; j < 4; j++) {
      long col = nBase + wn * 64 + j * 16 + l16;
      float bv = bias ? bias[col] : 0.f;
      long row0 = mBase + wm * 32 + i * 16 + quad * 4;
      if (VSPLIT && col >= 512) {
        int cm = (int)col - 512, hh = cm >> 7, cc = cm & 127;
        long bidx = row0 >> 10, n0 = row0 & 1023;
        ushort4 o;
        o.x = f2b(acc[i][j][0] + bv);
        o.y = f2b(acc[i][j][1] + bv);
        o.z = f2b(acc[i][j][2] + bv);
        o.w = f2b(acc[i][j][3] + bv);
        *(ushort4*)&VT[(((bidx * 2 + hh) * 128 + cc) << 10) + n0] = o;
      } else {
        #pragma unroll
        for (int r = 0; r < 4; r++) {
          float v = acc[i][j][r] + bv;
          if (relu) v = fmaxf(v, 0.f);
          if constexpr (sizeof(CT) == 2) C[(row0 + r) * ldc + col] = f2b(v);
          else                           C[(row0 + r) * ldc + col] = v;
        }
      }
    }
  }
}

template<typename CT, typename AT, typename WT>
static void mgemm(hipStream_t st, const AT* A, int lda, const WT* B, int ldb,
                  const float* bias, CT* C, int ldc, int M, int N, int K, int relu) {
  dim3 grid(N / 128, M / 64);
  mfma_gemm<CT, AT, WT, false><<<grid, 256, 0, st>>>(A, lda, B, ldb, bias, C, ldc, K, relu, nullptr);
}
template<typename AT, typename WT>
static void mgemm_vt(hipStream_t st, const AT* A, int lda, const WT* B, int ldb,
                     const float* bias, ushort* C, int ldc, int M, int N, int K, ushort* VT) {
  dim3 grid(N / 128, M / 64);
  mfma_gemm<ushort, AT, WT, true><<<grid, 256, 0, st>>>(A, lda, B, ldb, bias, C, ldc, K, 0, VT);
}

// ---------- split-K skinny GEMM (M rows <= 16): P[ks][m][n] partials ----------
// A [M,K] fp32 (lda), W [N,K] fp32 row-major. grid = (ceil(N/64), KS).
// Thread t: column n = blk*64 + (t&63); wave sub = t>>6 takes a K-subslice.
// A-slice lives in LDS (wave-broadcast reads = conflict-free).
template<int M_>
__global__ __launch_bounds__(256) void skinny_gemm(
    const float* __restrict__ A, int lda,
    const float* __restrict__ W, int K,
    float* __restrict__ P, int N, int slice)
{
  __shared__ float Asl[M_ * 192];
  __shared__ float Pr[4][M_][64];
  int tid = threadIdx.x;
  int ks = blockIdx.y;
  int kbeg = ks * slice;
  int kend = min(K, kbeg + slice);
  int sl = kend - kbeg;
  for (int idx = tid; idx < M_ * sl; idx += 256) {
    int m = idx / sl, k = idx - m * sl;
    Asl[m * sl + k] = A[(long)m * lda + kbeg + k];
  }
  __syncthreads();
  int n = blockIdx.x * 64 + (tid & 63);
  int sub = tid >> 6;
  int sl4 = (sl + 3) >> 2;
  int k0 = kbeg + sub * sl4;
  int k1 = min(kend, k0 + sl4);
  float acc[M_];
  #pragma unroll
  for (int m = 0; m < M_; m++) acc[m] = 0.f;
  if (n < N) {
    const float* wr = W + (long)n * K;
    for (int k = k0; k < k1; k++) {
      float w = wr[k];
      int kl = k - kbeg;
      #pragma unroll
      for (int m = 0; m < M_; m++) acc[m] += w * Asl[m * sl + kl];
    }
  }
  #pragma unroll
  for (int m = 0; m < M_; m++) Pr[sub][m][tid & 63] = acc[m];
  __syncthreads();
  if (sub == 0 && n < N) {
    #pragma unroll
    for (int m = 0; m < M_; m++) {
      float s = Pr[0][m][tid] + Pr[1][m][tid] + Pr[2][m][tid] + Pr[3][m][tid];
      P[((long)(ks * M_ + m)) * N + n] = s;
    }
  }
}

// epilogue: out[m][n] = act(bias[n] + sum_ks P[ks][m][n])
__global__ __launch_bounds__(256) void skinny_epi(
    const float* __restrict__ P, const float* __restrict__ bias,
    float* __restrict__ out, int M, int N, int KS, int relu)
{
  int idx = blockIdx.x * 256 + threadIdx.x;
  if (idx >= M * N) return;
  int m = idx / N, n = idx - m * N;
  float s = bias[n];
  for (int ks = 0; ks < KS; ks++) s += P[((long)(ks * M + m)) * N + n];
  if (relu) s = fmaxf(s, 0.f);
  out[(long)m * N + n] = s;
}

template<int M_>
static void sgemm(hipStream_t st, const float* A, int lda, const float* W, int K,
                  const float* bias, float* out, float* P, int N, int KS, int relu) {
  int slice = (K + KS - 1) / KS;
  dim3 grid((N + 63) / 64, KS);
  skinny_gemm<M_><<<grid, 256, 0, st>>>(A, lda, W, K, P, N, slice);
  skinny_epi<<<(M_ * N + 255) / 256, 256, 0, st>>>(P, bias, out, M_, N, KS, relu);
}

// ---------- bag stats ----------
__global__ __launch_bounds__(256) void bag_stats(const float* __restrict__ cp, float* __restrict__ PN) {
  int b = blockIdx.x, tid = threadIdx.x;
  __shared__ float red[256];
  for (int c = 0; c < 2; c++) {
    float s = 0.f;
    for (int n = tid; n < 1024; n += 256) s += cp[((b << 10) + n) * 2 + c];
    float mean = blk_sum256(s, red) * (1.f / 1024.f);
    s = 0.f;
    for (int n = tid; n < 1024; n += 256) { float d = cp[((b << 10) + n) * 2 + c] - mean; s += d * d; }
    float var = blk_sum256(s, red) * (1.f / 1024.f);
    float inv = 1.f / (sqrtf(var) + 1e-8f);
    for (int n = tid; n < 1024; n += 256)
      PN[((b << 10) + n) * 2 + c] = (cp[((b << 10) + n) * 2 + c] - mean) * inv;
  }
}

// ---------- kNN: parallel stable top-8 ----------
__global__ __launch_bounds__(256) void knn_kernel(const float* __restrict__ PN, int* __restrict__ NBR) {
  int blk = blockIdx.x;              // 128 blocks
  int b = blk >> 5, tg = blk & 31;   // 32 targets per block
  int tid = threadIdx.x;
  int tl = tid >> 3, chunk = tid & 7;
  __shared__ float px[1024], py[1024];
  __shared__ float candD[32][64];
  __shared__ int   candI[32][64];
  for (int i = tid; i < 1024; i += 256) {
    px[i] = PN[((b << 10) + i) * 2 + 0];
    py[i] = PN[((b << 10) + i) * 2 + 1];
  }
  __syncthreads();
  int t = tg * 32 + tl;
  float tx = px[t], ty = py[t];
  float d8[8]; int i8[8];
  #pragma unroll
  for (int i = 0; i < 8; i++) { d8[i] = 3.4e38f; i8[i] = 0x7fffffff; }
  int s0 = chunk * 128;
  for (int s = s0; s < s0 + 128; s++) {
    float dx = __fadd_rn(px[s], -tx), dy = __fadd_rn(py[s], -ty);
    float d2 = __fadd_rn(__fadd_rn(__fmul_rn(dx, dx), __fmul_rn(dy, dy)), 1e-12f);
    float d = sqrtf(d2);
    if (d < d8[7]) {
      d8[7] = d; i8[7] = s;
      #pragma unroll
      for (int p = 7; p > 0; p--) {
        if (d8[p] < d8[p - 1]) {
          float td = d8[p]; d8[p] = d8[p - 1]; d8[p - 1] = td;
          int ti = i8[p]; i8[p] = i8[p - 1]; i8[p - 1] = ti;
        }
      }
    }
  }
  #pragma unroll
  for (int i = 0; i < 8; i++) { candD[tl][chunk * 8 + i] = d8[i]; candI[tl][chunk * 8 + i] = i8[i]; }
  __syncthreads();
  if (chunk == 0) {
    float D[8]; int I[8];
    #pragma unroll
    for (int i = 0; i < 8; i++) { D[i] = candD[tl][i]; I[i] = candI[tl][i]; }
    for (int c = 1; c < 8; c++) {
      for (int j = 0; j < 8; j++) {
        float d = candD[tl][c * 8 + j]; int idx = candI[tl][c * 8 + j];
        bool better = (d < D[7]) || (d == D[7] && idx < I[7]);
        if (!better) break;
        D[7] = d; I[7] = idx;
        #pragma unroll
        for (int p = 7; p > 0; p--) {
          bool sw = (D[p] < D[p - 1]) || (D[p] == D[p - 1] && I[p] < I[p - 1]);
          if (sw) {
            float td = D[p]; D[p] = D[p - 1]; D[p - 1] = td;
            int ti = I[p]; I[p] = I[p - 1]; I[p - 1] = ti;
          }
        }
      }
    }
    #pragma unroll
    for (int i = 0; i < 8; i++) NBR[((long)((b << 10) + t)) * 8 + i] = I[i];
  }
}

// ---------- positional embedding MLP ----------
__global__ __launch_bounds__(128) void pos_embed(
    const float* __restrict__ cellp, const float* __restrict__ tab,
    const float* __restrict__ W1, const float* __restrict__ b1,
    const float* __restrict__ W2, const float* __restrict__ b2,
    float* __restrict__ X)
{
  int row = blockIdx.x, c = blockIdx.y, tid = threadIdx.x;
  __shared__ float e[128], h1[128];
  float pos = cellp[row * 2 + c];
  pos = fminf(fmaxf(pos, 0.f), 1000.f);
  int pi = (int)pos;
  e[tid] = tab[((long)(c * 1001 + pi)) * 128 + tid];
  __syncthreads();
  {
    const float* w1r = W1 + ((long)(c * 128 + tid)) * 128;
    float a = b1[c * 128 + tid];
    for (int i = 0; i < 128; i++) a += e[i] * w1r[i];
    h1[tid] = fmaxf(a, 0.f);
  }
  __syncthreads();
  {
    const float* w2r = W2 + ((long)(c * 128 + tid)) * 128;
    float o = b2[c * 128 + tid];
    for (int i = 0; i < 128; i++) o += h1[i] * w2r[i];
    X[(long)row * 256 + c * 128 + tid] += o;
  }
}

// ---------- GAT scores ----------
__global__ __launch_bounds__(256) void gat_scores(const float* __restrict__ Hh,
    const float* __restrict__ asrcW, const float* __restrict__ adstW,
    float* __restrict__ ASRC, float* __restrict__ ADST)
{
  int row = blockIdx.x, tid = threadIdx.x;
  __shared__ float red[256];
  float v = Hh[(long)row * 256 + tid];
  float s1 = v * asrcW[tid];
  float s2 = v * adstW[tid];
  red[tid] = s1; __syncthreads();
  for (int off = 64; off > 0; off >>= 1) { if ((tid & 127) < off) red[tid] += red[tid + off]; __syncthreads(); }
  if ((tid & 127) == 0) ASRC[row * 2 + (tid >> 7)] = red[tid];
  __syncthreads();
  red[tid] = s2; __syncthreads();
  for (int off = 64; off > 0; off >>= 1) { if ((tid & 127) < off) red[tid] += red[tid + off]; __syncthreads(); }
  if ((tid & 127) == 0) ADST[row * 2 + (tid >> 7)] = red[tid];
}

// ---------- GAT aggregate + residual + LN (emits fp32 X and bf16 Xb) ----------
__global__ __launch_bounds__(256) void gat_aggr_ln(
    const float* __restrict__ Hh, const float* __restrict__ ASRC, const float* __restrict__ ADST,
    const int* __restrict__ NBR, const float* __restrict__ gbias,
    const float* __restrict__ lng, const float* __restrict__ lnb,
    float* __restrict__ X, ushort* __restrict__ Xb)
{
  int row = blockIdx.x, tid = threadIdx.x;
  int b = row >> 10;
  __shared__ int nb[8];
  __shared__ float w[2][8];
  __shared__ float red[256];
  if (tid < 8) {
    int v = NBR[(long)row * 8 + tid];
    nb[tid] = min(max(v, 0), 1023);
  }
  __syncthreads();
  if (tid < 16) {
    int i = tid & 7, h = tid >> 3;
    float e = ADST[row * 2 + h] + ASRC[((b << 10) + nb[i]) * 2 + h];
    w[h][i] = (e >= 0.f) ? e : 0.2f * e;
  }
  __syncthreads();
  if (tid < 2) {
    float m = -3.4e38f;
    for (int i = 0; i < 8; i++) m = fmaxf(m, w[tid][i]);
    float s = 0.f;
    for (int i = 0; i < 8; i++) { float e = expf(w[tid][i] - m); w[tid][i] = e; s += e; }
    float inv = 1.f / s;
    for (int i = 0; i < 8; i++) w[tid][i] *= inv;
  }
  __syncthreads();
  int h = tid >> 7, c = tid & 127;
  float acc = 0.f;
  #pragma unroll
  for (int i = 0; i < 8; i++)
    acc += w[h][i] * Hh[((long)((b << 10) + nb[i])) * 256 + h * 128 + c];
  float v = acc + gbias[tid] + X[(long)row * 256 + tid];
  float mean = blk_sum256(v, red) * (1.f / 256.f);
  float dv = v - mean;
  float var = blk_sum256(dv * dv, red) * (1.f / 256.f);
  float o = dv * rsqrtf(var + 1e-5f) * lng[tid] + lnb[tid];
  X[(long)row * 256 + tid] = o;
  Xb[(long)row * 256 + tid] = f2b(o);
}

// ---------- residual + LayerNorm, D=256, one wave per row ----------
__global__ __launch_bounds__(256) void add_ln4(const float* __restrict__ res,
    const float* __restrict__ Yv, const float* __restrict__ g, const float* __restrict__ b,
    float* __restrict__ out, ushort* __restrict__ outb)
{
  int wave = threadIdx.x >> 6, lane = threadIdx.x & 63;
  long row = blockIdx.x * 4 + wave;
  const float* yr = Yv + row * 256;
  const float* rr = res ? res + row * 256 : nullptr;
  float v[4];
  float s = 0.f;
  #pragma unroll
  for (int i = 0; i < 4; i++) {
    int d = lane + i * 64;
    float x = yr[d];
    if (rr) x += rr[d];
    v[i] = x; s += x;
  }
  #pragma unroll
  for (int off = 32; off > 0; off >>= 1) s += __shfl_xor(s, off);
  float mean = s * (1.f / 256.f);
  float vs = 0.f;
  #pragma unroll
  for (int i = 0; i < 4; i++) { float dv = v[i] - mean; vs += dv * dv; }
  #pragma unroll
  for (int off = 32; off > 0; off >>= 1) vs += __shfl_xor(vs, off);
  float rstd = rsqrtf(vs * (1.f / 256.f) + 1e-5f);
  #pragma unroll
  for (int i = 0; i < 4; i++) {
    int d = lane + i * 64;
    float o = (v[i] - mean) * rstd * g[d] + b[d];
    out[row * 256 + d] = o;
    if (outb) outb[row * 256 + d] = f2b(o);
  }
}

// ---------- LayerNorm (D=1024, head rows) ----------
__global__ __launch_bounds__(256) void add_ln_big(const float* __restrict__ Yv,
    const float* __restrict__ g, const float* __restrict__ b,
    float* __restrict__ out)
{
  int row = blockIdx.x, tid = threadIdx.x;
  __shared__ float red[256];
  float vals[4];
  float s = 0.f;
  #pragma unroll
  for (int i = 0; i < 4; i++) {
    int d = tid + (i << 8);
    float v = Yv[(long)row * 1024 + d];
    vals[i] = v; s += v;
  }
  float mean = blk_sum256(s, red) * (1.f / 1024.f);
  s = 0.f;
  #pragma unroll
  for (int i = 0; i < 4; i++) { float dv = vals[i] - mean; s += dv * dv; }
  float var = blk_sum256(s, red) * (1.f / 1024.f);
  float rstd = rsqrtf(var + 1e-5f);
  #pragma unroll
  for (int i = 0; i < 4; i++) {
    int d = tid + (i << 8);
    out[(long)row * 1024 + d] = (vals[i] - mean) * rstd * g[d] + b[d];
  }
}

// ---------- MFMA flash attention ----------
__global__ __launch_bounds__(256) void flash_mfma(const ushort* __restrict__ QKV,
                                                  const ushort* __restrict__ VT,
                                                  ushort* __restrict__ O)
{
  const float scale = 0.08838834764831845f;
  int blk = blockIdx.x;
  int qt = blk & 15, bh = blk >> 4;
  int b = bh >> 1, h = bh & 1;
  const ushort* qkg = QKV + (long)b * 1024 * 768 + h * 128;
  const ushort* vtg = VT + ((long)bh << 17);   // bh*128*1024

  __shared__ ushort Qs[64][136];
  __shared__ ushort Ks[64][136];
  __shared__ ushort Vt[128][72];
  __shared__ ushort Ps[4][16][72];

  int tid = threadIdx.x;
  int wave = tid >> 6, lane = tid & 63;
  int quad = lane >> 4, l16 = lane & 15;

  #pragma unroll
  for (int p = 0; p < 4; p++) {
    int idx = p * 256 + tid;
    int r = idx >> 4, c8 = (idx & 15) * 8;
    *(uint4*)&Qs[r][c8] = *(const uint4*)(qkg + (long)(qt * 64 + r) * 768 + c8);
  }
  __syncthreads();
  bf16x8 af[4];
  #pragma unroll
  for (int ks = 0; ks < 4; ks++)
    af[ks] = *(const bf16x8*)&Qs[wave * 16 + l16][ks * 32 + quad * 8];

  f32x4 Oacc[8];
  f32x4 zero4 = {0.f, 0.f, 0.f, 0.f};
  #pragma unroll
  for (int j = 0; j < 8; j++) Oacc[j] = zero4;
  float mr[4], lr[4];
  #pragma unroll
  for (int r = 0; r < 4; r++) { mr[r] = -3.4e38f; lr[r] = 0.f; }

  for (int kt = 0; kt < 16; kt++) {
    __syncthreads();
    #pragma unroll
    for (int p = 0; p < 4; p++) {
      int idx = p * 256 + tid;
      int r = idx >> 4, c8 = (idx & 15) * 8;
      *(uint4*)&Ks[r][c8] = *(const uint4*)(qkg + (long)(kt * 64 + r) * 768 + 256 + c8);
      int c = idx >> 3, k8 = (idx & 7) * 8;
      *(uint4*)&Vt[c][k8] = *(const uint4*)(vtg + ((long)c << 10) + kt * 64 + k8);
    }
    __syncthreads();
    f32x4 acc[4];
    #pragma unroll
    for (int j = 0; j < 4; j++) acc[j] = zero4;
    #pragma unroll
    for (int ks = 0; ks < 4; ks++) {
      #pragma unroll
      for (int j = 0; j < 4; j++) {
        bf16x8 kb = *(const bf16x8*)&Ks[j * 16 + l16][ks * 32 + quad * 8];
        acc[j] = __builtin_amdgcn_mfma_f32_16x16x32_bf16(af[ks], kb, acc[j], 0, 0, 0);
      }
    }
    float sv[4][4], tmax[4];
    #pragma unroll
    for (int r = 0; r < 4; r++) tmax[r] = -3.4e38f;
    #pragma unroll
    for (int j = 0; j < 4; j++)
      #pragma unroll
      for (int r = 0; r < 4; r++) {
        float x = acc[j][r] * scale;
        sv[j][r] = x;
        tmax[r] = fmaxf(tmax[r], x);
      }
    #pragma unroll
    for (int off = 1; off < 16; off <<= 1)
      #pragma unroll
      for (int r = 0; r < 4; r++) tmax[r] = fmaxf(tmax[r], __shfl_xor(tmax[r], off));
    float alpha[4], rsum[4];
    #pragma unroll
    for (int r = 0; r < 4; r++) {
      float mn = fmaxf(mr[r], tmax[r]);
      alpha[r] = expf(mr[r] - mn);
      mr[r] = mn;
      rsum[r] = 0.f;
    }
    #pragma unroll
    for (int j = 0; j < 4; j++)
      #pragma unroll
      for (int r = 0; r < 4; r++) {
        float p = expf(sv[j][r] - mr[r]);
        sv[j][r] = p;
        rsum[r] += p;
      }
    #pragma unroll
    for (int off = 1; off < 16; off <<= 1)
      #pragma unroll
      for (int r = 0; r < 4; r++) rsum[r] += __shfl_xor(rsum[r], off);
    #pragma unroll
    for (int r = 0; r < 4; r++) lr[r] = lr[r] * alpha[r] + rsum[r];
    #pragma unroll
    for (int j = 0; j < 4; j++)
      #pragma unroll
      for (int r = 0; r < 4; r++)
        Ps[wave][quad * 4 + r][j * 16 + l16] = f2b(sv[j][r]);
    #pragma unroll
    for (int jj = 0; jj < 8; jj++)
      #pragma unroll
      for (int r = 0; r < 4; r++) Oacc[jj][r] *= alpha[r];
    __syncthreads();
    #pragma unroll
    for (int s = 0; s < 2; s++) {
      bf16x8 pa = *(const bf16x8*)&Ps[wave][l16][s * 32 + quad * 8];
      #pragma unroll
      for (int jj = 0; jj < 8; jj++) {
        bf16x8 vb = *(const bf16x8*)&Vt[jj * 16 + l16][s * 32 + quad * 8];
        Oacc[jj] = __builtin_amdgcn_mfma_f32_16x16x32_bf16(pa, vb, Oacc[jj], 0, 0, 0);
      }
    }
  }
  long row0 = (long)b * 1024 + qt * 64 + wave * 16 + quad * 4;
  #pragma unroll
  for (int jj = 0; jj < 8; jj++) {
    int col = h * 128 + jj * 16 + l16;
    #pragma unroll
    for (int r = 0; r < 4; r++)
      O[(row0 + r) * 256 + col] = f2b(Oacc[jj][r] / lr[r]);
  }
}

// ---------- sparse pooling attention (bf16 KV, 256 threads) ----------
__global__ __launch_bounds__(256) void pool_attn(
    const float* __restrict__ qe, const float* __restrict__ pinW, const float* __restrict__ pinB,
    const float* __restrict__ srand, const ushort* __restrict__ KV, float* __restrict__ ATTP)
{
  int id = blockIdx.x;   // 32 blocks: b*8 + nq*2 + h
  int h = id & 1, nq = (id >> 1) & 3, b = id >> 3;
  int tid = threadIdx.x;
  __shared__ float qs[128];
  __shared__ float lg[1024];
  __shared__ float red[256];
  if (tid < 128) {
    float a = pinB[h * 128 + tid];
    const float* wr = pinW + ((long)(h * 128 + tid)) * 256;
    const float* qr = qe + nq * 256;
    for (int i = 0; i < 256; i++) a += qr[i] * wr[i];
    qs[tid] = a;
  }
  __syncthreads();
  const float scale = 0.08838834764831845f;
  for (int s = tid; s < 1024; s += 256) {
    const ushort* kr = KV + ((long)((b << 10) + s)) * 512 + h * 128;
    float d = 0.f;
    for (int c2 = 0; c2 < 128; c2++) d += qs[c2] * b2f(kr[c2]);
    float mv = (srand[nq * 1024 + s] < 0.3f) ? 0.f : -1e9f;
    lg[s] = d * scale + mv;
  }
  __syncthreads();
  float m = -3.4e38f;
  for (int s = tid; s < 1024; s += 256) m = fmaxf(m, lg[s]);
  red[tid] = m; __syncthreads();
  for (int off = 128; off > 0; off >>= 1) { if (tid < off) red[tid] = fmaxf(red[tid], red[tid + off]); __syncthreads(); }
  m = red[0]; __syncthreads();
  float s0 = 0.f;
  for (int s = tid; s < 1024; s += 256) { float e = expf(lg[s] - m); lg[s] = e; s0 += e; }
  red[tid] = s0; __syncthreads();
  for (int off = 128; off > 0; off >>= 1) { if (tid < off) red[tid] += red[tid + off]; __syncthreads(); }
  float denom = red[0]; __syncthreads();
  int c = tid & 127, half = tid >> 7;
  float acc = 0.f;
  int sBase = half * 512;
  for (int s = sBase; s < sBase + 512; s++)
    acc += lg[s] * b2f(KV[((long)((b << 10) + s)) * 512 + 256 + h * 128 + c]);
  red[tid] = acc; __syncthreads();
  if (tid < 128)
    ATTP[(b * 4 + nq) * 256 + h * 128 + tid] = (red[tid] + red[tid + 128]) / denom;
}

// ---------- combined = [mean over N | pooled_att], 1024 threads ----------
__global__ __launch_bounds__(1024) void combined_kernel(const float* __restrict__ X,
    const float* __restrict__ ATTO, float* __restrict__ CMB)
{
  int b = blockIdx.x, tid = threadIdx.x;
  int d = tid & 255, ch = tid >> 8;
  __shared__ float part[4][256];
  float s = 0.f;
  int n0 = ch * 256;
  for (int n = n0; n < n0 + 256; n++) s += X[((long)((b << 10) + n)) * 256 + d];
  part[ch][d] = s;
  __syncthreads();
  if (ch == 0) {
    float tot = part[0][d] + part[1][d] + part[2][d] + part[3][d];
    CMB[b * 1280 + d] = tot * (1.f / 1024.f);
    #pragma unroll
    for (int q = 0; q < 4; q++)
      CMB[b * 1280 + 256 + q * 256 + d] = ATTO[(b * 4 + q) * 256 + d];
  }
}

__global__ void store_out(const float* __restrict__ src, float* __restrict__ dst, int n) {
  int i = blockIdx.x * blockDim.x + threadIdx.x;
  if (i < n) dst[i] = src[i];
}
__global__ void fill_out_zero(float* __restrict__ dst, int n) {
  int i = blockIdx.x * blockDim.x + threadIdx.x;
  if (i < n) dst[i] = 0.f;
}

extern "C" void kernel_launch(void* const* d_in, const int* in_sizes, int n_in,
                              void* d_out, int out_size, void* d_ws, size_t ws_size,
                              hipStream_t stream)
{
  const float* inp      = (const float*)d_in[0];
  const float* cellp    = (const float*)d_in[1];
  const float* srand    = (const float*)d_in[2];
  const float* emb_W    = (const float*)d_in[3];
  const float* emb_b    = (const float*)d_in[4];
  const float* pe_tab   = (const float*)d_in[5];
  const float* pe_W1    = (const float*)d_in[6];
  const float* pe_b1    = (const float*)d_in[7];
  const float* pe_W2    = (const float*)d_in[8];
  const float* pe_b2    = (const float*)d_in[9];
  const float* gat_W    = (const float*)d_in[10];
  const float* gat_asrc = (const float*)d_in[11];
  const float* gat_adst = (const float*)d_in[12];
  const float* gat_b    = (const float*)d_in[13];
  const float* ln_g     = (const float*)d_in[14];
  const float* ln_b     = (const float*)d_in[15];
  const float* qkv_W    = (const float*)d_in[16];
  const float* qkv_b    = (const float*)d_in[17];
  const float* out_W    = (const float*)d_in[18];
  const float* out_b    = (const float*)d_in[19];
  const float* ff1_W    = (const float*)d_in[20];
  const float* ff1_b    = (const float*)d_in[21];
  const float* ff2_W    = (const float*)d_in[22];
  const float* ff2_b    = (const float*)d_in[23];
  const float* ln1_g    = (const float*)d_in[24];
  const float* ln1_b    = (const float*)d_in[25];
  const float* ln2_g    = (const float*)d_in[26];
  const float* ln2_b    = (const float*)d_in[27];
  const float* q_emb    = (const float*)d_in[28];
  const float* pin_W    = (const float*)d_in[29];
  const float* pin_b    = (const float*)d_in[30];
  const float* pout_W   = (const float*)d_in[31];
  const float* pout_b   = (const float*)d_in[32];
  const float* m1_W     = (const float*)d_in[33];
  const float* m1_b     = (const float*)d_in[34];
  const float* mln1_g   = (const float*)d_in[35];
  const float* mln1_b   = (const float*)d_in[36];
  const float* m2_W     = (const float*)d_in[37];
  const float* m2_b     = (const float*)d_in[38];
  const float* mln2_g   = (const float*)d_in[39];
  const float* mln2_b   = (const float*)d_in[40];
  const float* m3_W     = (const float*)d_in[41];
  const float* m3_b     = (const float*)d_in[42];
  const float* c1_W     = (const float*)d_in[43];
  const float* c1_b     = (const float*)d_in[44];
  const float* c2_W     = (const float*)d_in[45];
  const float* c2_b     = (const float*)d_in[46];
  const float* c3_W     = (const float*)d_in[47];
  const float* c3_b     = (const float*)d_in[48];
  const float* c4_W     = (const float*)d_in[49];
  const float* c4_b     = (const float*)d_in[50];
  (void)in_sizes; (void)n_in;

  // ---- workspace (bytes, 256-aligned; ~20.4 MB) ----
  char* base = (char*)d_ws;
  size_t off = 0;
  auto alloc = [&](size_t bytes) { void* p = base + off; off += (bytes + 255) & ~size_t(255); return p; };
  float* PN    = (float*)alloc(32768);
  float* AS    = (float*)alloc(32768);
  float* AD    = (float*)alloc(32768);
  float* ATTP  = (float*)alloc(16384);
  float* ATTO  = (float*)alloc(16384);
  float* CMB   = (float*)alloc(20480);
  float* Ha    = (float*)alloc(16384);
  float* Hb    = (float*)alloc(16384);
  float* Hc    = (float*)alloc(16640);
  float* Hd    = (float*)alloc(8192);
  float* He    = (float*)alloc(4096);
  float* Hf    = (float*)alloc(512);
  float* Pk    = (float*)alloc(262144);           // split-K partials (max 8*16*1032 fl)
  int*   NBR   = (int*)alloc(131072);
  float* X     = (float*)alloc(4194304);          // fp32 residual stream [4096,256]
  ushort* Xb   = (ushort*)alloc(2097152);         // bf16 shadow of X
  char*  Rq    = (char*)alloc(6291456);           // QKVb bf16 | F2 fp32 | KVb bf16
  char*  Rf    = (char*)alloc(4194304);           // Ob | VT | FFBb (time-sliced)
  ushort* QKVb = (ushort*)Rq;                     // [4096,768] (V cols stale/unused)
  float*  F2   = (float*)Rq;                      // [4096,256]
  ushort* KVb  = (ushort*)Rq;                     // [4096,512]
  ushort* Ob   = (ushort*)Rf;                     // [4096,256]  (2 MB)
  ushort* VT   = (ushort*)(Rf + 2097152);         // [8][128][1024] (2 MB)
  ushort* FFBb = (ushort*)Rf;                     // [2048,1024] (4 MB, after flash)
  float*  F1   = (float*)alloc(4194304);          // GAT h fp32 [4096,256]
  if (ws_size < off) { fill_out_zero<<<1, 128, 0, stream>>>((float*)d_out, out_size); return; }

  // ---- graph construction ----
  bag_stats<<<4, 256, 0, stream>>>(cellp, PN);
  knn_kernel<<<128, 256, 0, stream>>>(PN, NBR);

  // ---- embedding + positional MLP ----
  mgemm<float>(stream, inp, 512, emb_W, 512, emb_b, X, 256, 4096, 256, 512, 0);
  pos_embed<<<dim3(4096, 2), 128, 0, stream>>>(cellp, pe_tab, pe_W1, pe_b1, pe_W2, pe_b2, X);
  cvt_f2b<<<1024, 256, 0, stream>>>(X, Xb, 4096 * 256);

  // ---- 2x GAT ----
  for (int l = 0; l < 2; l++) {
    mgemm<float>(stream, Xb, 256, gat_W + l * 65536, 256, (const float*)nullptr, F1, 256,
                 4096, 256, 256, 0);
    gat_scores<<<4096, 256, 0, stream>>>(F1, gat_asrc + l * 256, gat_adst + l * 256, AS, AD);
    gat_aggr_ln<<<4096, 256, 0, stream>>>(F1, AS, AD, NBR, gat_b + l * 256, ln_g, ln_b, X, Xb);
  }

  // ---- 2x Transformer encoder layer ----
  for (int l = 0; l < 2; l++) {
    mgemm_vt(stream, Xb, 256, qkv_W + (long)l * 768 * 256, 256, qkv_b + l * 768,
             QKVb, 768, 4096, 768, 256, VT);
    flash_mfma<<<256, 256, 0, stream>>>(QKVb, VT, Ob);
    mgemm<float>(stream, Ob, 256, out_W + l * 65536, 256, out_b + l * 256, F2, 256,
                 4096, 256, 256, 0);
    add_ln4<<<1024, 256, 0, stream>>>(X, F2, ln1_g + l * 256, ln1_b + l * 256, X, Xb);
    for (int ch = 0; ch < 2; ch++) {                    // FFN in 2048-row chunks
      mgemm<ushort>(stream, Xb + (long)ch * 2048 * 256, 256, ff1_W + l * 262144, 256,
                    ff1_b + l * 1024, FFBb, 1024, 2048, 1024, 256, 1);
      mgemm<float>(stream, FFBb, 1024, ff2_W + l * 262144, 1024, ff2_b + l * 256,
                   F2 + (long)ch * 2048 * 256, 256, 2048, 256, 1024, 0);
    }
    add_ln4<<<1024, 256, 0, stream>>>(X, F2, ln2_g + l * 256, ln2_b + l * 256, X, Xb);
  }

  // ---- final LN ----
  add_ln4<<<1024, 256, 0, stream>>>((const float*)nullptr, X, ln_g, ln_b, X, Xb);

  // ---- pooling ----
  mgemm<ushort>(stream, Xb, 256, pin_W + 65536, 256, pin_b + 256, KVb, 512, 4096, 512, 256, 0);
  pool_attn<<<32, 256, 0, stream>>>(q_emb, pin_W, pin_b, srand, KVb, ATTP);
  sgemm<16>(stream, ATTP, 256, pout_W, 256, pout_b, ATTO, Pk, 256, 2, 0);
  combined_kernel<<<4, 1024, 0, stream>>>(X, ATTO, CMB);

  // ---- MLP head (fp32, split-K skinny GEMMs) ----
  sgemm<4>(stream, CMB, 1280, m1_W, 1280, m1_b, Ha, Pk, 1024, 8, 1);
  add_ln_big<<<4, 256, 0, stream>>>(Ha, mln1_g, mln1_b, Ha);
  sgemm<4>(stream, Ha, 1024, m2_W, 1024, m2_b, Hb, Pk, 1024, 8, 1);
  add_ln_big<<<4, 256, 0, stream>>>(Hb, mln2_g, mln2_b, Hb);
  sgemm<4>(stream, Hb, 1024, m3_W, 1024, m3_b, Ha, Pk, 1024, 8, 0);
  sgemm<4>(stream, Ha, 1024, c1_W, 1024, c1_b, Hc, Pk, 1032, 8, 1);
  sgemm<4>(stream, Hc, 1032, c2_W, 1032, c2_b, Hd, Pk, 512, 8, 1);
  sgemm<4>(stream, Hd, 512, c3_W, 512, c3_b, He, Pk, 256, 4, 1);
  sgemm<4>(stream, He, 256, c4_W, 256, c4_b, Hf, Pk, 24, 2, 0);
  store_out<<<1, 128, 0, stream>>>(Hf, (float*)d_out, out_size);
}

// Round 8
// 915.276 us; speedup vs baseline: 4.3525x; 1.1536x over previous
//
#include <hip/hip_runtime.h>
#include <hip/hip_bf16.h>

// MILCellModel forward on MI355X. Round 8: split-K pooling attention
// (flash-decoding style: 8 key-chunks x 32 (b,nq,h) partials + rescale-merge).
// R7 profile: pool_attn 166us, 32 blocks, VALUBusy 0.5% -> latency-starved.
// B=4 N=1024 E=512 D=256 H=2 C=128 FF=1024 NQ=4 NCLS=24

typedef __bf16 bf16x8 __attribute__((ext_vector_type(8)));
typedef float  f32x4  __attribute__((ext_vector_type(4)));

__device__ __forceinline__ ushort f2b(float f) {
  __hip_bfloat16 h = __float2bfloat16(f);
  return *(ushort*)&h;
}
__device__ __forceinline__ float b2f(ushort u) {
  union { unsigned i; float f; } v; v.i = ((unsigned)u) << 16; return v.f;
}

// ---------- block reductions (256 threads) ----------
__device__ __forceinline__ float blk_sum256(float v, float* red) {
  int t = threadIdx.x;
  red[t] = v; __syncthreads();
  #pragma unroll
  for (int off = 128; off > 0; off >>= 1) {
    if (t < off) red[t] += red[t + off];
    __syncthreads();
  }
  float r = red[0]; __syncthreads();
  return r;
}

// ---------- fp32 -> bf16 convert ----------
__global__ __launch_bounds__(256) void cvt_f2b(const float* __restrict__ src,
                                               ushort* __restrict__ dst, int n) {
  int i = (blockIdx.x * 256 + threadIdx.x) * 4;
  if (i >= n) return;
  float4 v = *(const float4*)(src + i);
  ushort4 o;
  o.x = f2b(v.x); o.y = f2b(v.y); o.z = f2b(v.z); o.w = f2b(v.w);
  *(ushort4*)(dst + i) = o;
}

// ---------- staging helpers: 8 contiguous elements -> bf16 LDS ----------
__device__ __forceinline__ void stage8(const ushort* __restrict__ src, ushort* dst) {
  *(uint4*)dst = *(const uint4*)src;
}
__device__ __forceinline__ void stage8(const float* __restrict__ src, ushort* dst) {
  float4 a = ((const float4*)src)[0];
  float4 b = ((const float4*)src)[1];
  ushort4 o0, o1;
  o0.x = f2b(a.x); o0.y = f2b(a.y); o0.z = f2b(a.z); o0.w = f2b(a.w);
  o1.x = f2b(b.x); o1.y = f2b(b.y); o1.z = f2b(b.z); o1.w = f2b(b.w);
  *(ushort4*)dst = o0;
  *(ushort4*)(dst + 4) = o1;
}

// ---------- bf16 MFMA GEMM: C[M,N] = act(A[M,K] @ B^T + bias) ----------
template<typename CT, typename AT, typename WT, bool VSPLIT>
__global__ __launch_bounds__(256) void mfma_gemm(
    const AT* __restrict__ A, int lda,
    const WT* __restrict__ Bw, int ldb,
    const float* __restrict__ bias,
    CT* __restrict__ C, int ldc, int K, int relu,
    ushort* __restrict__ VT)
{
  __shared__ ushort As[64][40];
  __shared__ ushort Bs[128][40];
  int tid = threadIdx.x;
  int lane = tid & 63, wave = tid >> 6;
  int wm = wave >> 1, wn = wave & 1;
  int quad = lane >> 4, l16 = lane & 15;
  long mBase = blockIdx.y * 64, nBase = blockIdx.x * 128;

  f32x4 zero4 = {0.f, 0.f, 0.f, 0.f};
  f32x4 acc[2][4];
  #pragma unroll
  for (int i = 0; i < 2; i++)
    #pragma unroll
    for (int j = 0; j < 4; j++) acc[i][j] = zero4;

  for (int k0 = 0; k0 < K; k0 += 32) {
    {
      int r = tid >> 2, sg = (tid & 3) * 8;
      stage8(A + (mBase + r) * lda + k0 + sg, &As[r][sg]);
    }
    #pragma unroll
    for (int p = 0; p < 2; p++) {
      int idx = p * 256 + tid;
      int r = idx >> 2, sg = (idx & 3) * 8;
      stage8(Bw + (nBase + r) * ldb + k0 + sg, &Bs[r][sg]);
    }
    __syncthreads();
    bf16x8 af[2], bfr[4];
    #pragma unroll
    for (int i = 0; i < 2; i++)
      af[i] = *(const bf16x8*)&As[wm * 32 + i * 16 + l16][quad * 8];
    #pragma unroll
    for (int j = 0; j < 4; j++)
      bfr[j] = *(const bf16x8*)&Bs[wn * 64 + j * 16 + l16][quad * 8];
    #pragma unroll
    for (int i = 0; i < 2; i++)
      #pragma unroll
      for (int j = 0; j < 4; j++)
        acc[i][j] = __builtin_amdgcn_mfma_f32_16x16x32_bf16(af[i], bfr[j], acc[i][j], 0, 0, 0);
    __syncthreads();
  }
  #pragma unroll
  for (int i = 0; i < 2; i++) {
    #pragma unroll
    for (int j = 0; j < 4; j++) {
      long col = nBase + wn * 64 + j * 16 + l16;
      float bv = bias ? bias[col] : 0.f;
      long row0 = mBase + wm * 32 + i * 16 + quad * 4;
      if (VSPLIT && col >= 512) {
        int cm = (int)col - 512, hh = cm >> 7, cc = cm & 127;
        long bidx = row0 >> 10, n0 = row0 & 1023;
        ushort4 o;
        o.x = f2b(acc[i][j][0] + bv);
        o.y = f2b(acc[i][j][1] + bv);
        o.z = f2b(acc[i][j][2] + bv);
        o.w = f2b(acc[i][j][3] + bv);
        *(ushort4*)&VT[(((bidx * 2 + hh) * 128 + cc) << 10) + n0] = o;
      } else {
        #pragma unroll
        for (int r = 0; r < 4; r++) {
          float v = acc[i][j][r] + bv;
          if (relu) v = fmaxf(v, 0.f);
          if constexpr (sizeof(CT) == 2) C[(row0 + r) * ldc + col] = f2b(v);
          else                           C[(row0 + r) * ldc + col] = v;
        }
      }
    }
  }
}

template<typename CT, typename AT, typename WT>
static void mgemm(hipStream_t st, const AT* A, int lda, const WT* B, int ldb,
                  const float* bias, CT* C, int ldc, int M, int N, int K, int relu) {
  dim3 grid(N / 128, M / 64);
  mfma_gemm<CT, AT, WT, false><<<grid, 256, 0, st>>>(A, lda, B, ldb, bias, C, ldc, K, relu, nullptr);
}
template<typename AT, typename WT>
static void mgemm_vt(hipStream_t st, const AT* A, int lda, const WT* B, int ldb,
                     const float* bias, ushort* C, int ldc, int M, int N, int K, ushort* VT) {
  dim3 grid(N / 128, M / 64);
  mfma_gemm<ushort, AT, WT, true><<<grid, 256, 0, st>>>(A, lda, B, ldb, bias, C, ldc, K, 0, VT);
}

// ---------- split-K skinny GEMM (M rows <= 16) ----------
template<int M_>
__global__ __launch_bounds__(256) void skinny_gemm(
    const float* __restrict__ A, int lda,
    const float* __restrict__ W, int K,
    float* __restrict__ P, int N, int slice)
{
  __shared__ float Asl[M_ * 192];
  __shared__ float Pr[4][M_][64];
  int tid = threadIdx.x;
  int ks = blockIdx.y;
  int kbeg = ks * slice;
  int kend = min(K, kbeg + slice);
  int sl = kend - kbeg;
  for (int idx = tid; idx < M_ * sl; idx += 256) {
    int m = idx / sl, k = idx - m * sl;
    Asl[m * sl + k] = A[(long)m * lda + kbeg + k];
  }
  __syncthreads();
  int n = blockIdx.x * 64 + (tid & 63);
  int sub = tid >> 6;
  int sl4 = (sl + 3) >> 2;
  int k0 = kbeg + sub * sl4;
  int k1 = min(kend, k0 + sl4);
  float acc[M_];
  #pragma unroll
  for (int m = 0; m < M_; m++) acc[m] = 0.f;
  if (n < N) {
    const float* wr = W + (long)n * K;
    for (int k = k0; k < k1; k++) {
      float w = wr[k];
      int kl = k - kbeg;
      #pragma unroll
      for (int m = 0; m < M_; m++) acc[m] += w * Asl[m * sl + kl];
    }
  }
  #pragma unroll
  for (int m = 0; m < M_; m++) Pr[sub][m][tid & 63] = acc[m];
  __syncthreads();
  if (sub == 0 && n < N) {
    #pragma unroll
    for (int m = 0; m < M_; m++) {
      float s = Pr[0][m][tid] + Pr[1][m][tid] + Pr[2][m][tid] + Pr[3][m][tid];
      P[((long)(ks * M_ + m)) * N + n] = s;
    }
  }
}

__global__ __launch_bounds__(256) void skinny_epi(
    const float* __restrict__ P, const float* __restrict__ bias,
    float* __restrict__ out, int M, int N, int KS, int relu)
{
  int idx = blockIdx.x * 256 + threadIdx.x;
  if (idx >= M * N) return;
  int m = idx / N, n = idx - m * N;
  float s = bias[n];
  for (int ks = 0; ks < KS; ks++) s += P[((long)(ks * M + m)) * N + n];
  if (relu) s = fmaxf(s, 0.f);
  out[(long)m * N + n] = s;
}

template<int M_>
static void sgemm(hipStream_t st, const float* A, int lda, const float* W, int K,
                  const float* bias, float* out, float* P, int N, int KS, int relu) {
  int slice = (K + KS - 1) / KS;
  dim3 grid((N + 63) / 64, KS);
  skinny_gemm<M_><<<grid, 256, 0, st>>>(A, lda, W, K, P, N, slice);
  skinny_epi<<<(M_ * N + 255) / 256, 256, 0, st>>>(P, bias, out, M_, N, KS, relu);
}

// ---------- bag stats ----------
__global__ __launch_bounds__(256) void bag_stats(const float* __restrict__ cp, float* __restrict__ PN) {
  int b = blockIdx.x, tid = threadIdx.x;
  __shared__ float red[256];
  for (int c = 0; c < 2; c++) {
    float s = 0.f;
    for (int n = tid; n < 1024; n += 256) s += cp[((b << 10) + n) * 2 + c];
    float mean = blk_sum256(s, red) * (1.f / 1024.f);
    s = 0.f;
    for (int n = tid; n < 1024; n += 256) { float d = cp[((b << 10) + n) * 2 + c] - mean; s += d * d; }
    float var = blk_sum256(s, red) * (1.f / 1024.f);
    float inv = 1.f / (sqrtf(var) + 1e-8f);
    for (int n = tid; n < 1024; n += 256)
      PN[((b << 10) + n) * 2 + c] = (cp[((b << 10) + n) * 2 + c] - mean) * inv;
  }
}

// ---------- kNN: parallel stable top-8 ----------
__global__ __launch_bounds__(256) void knn_kernel(const float* __restrict__ PN, int* __restrict__ NBR) {
  int blk = blockIdx.x;
  int b = blk >> 5, tg = blk & 31;
  int tid = threadIdx.x;
  int tl = tid >> 3, chunk = tid & 7;
  __shared__ float px[1024], py[1024];
  __shared__ float candD[32][64];
  __shared__ int   candI[32][64];
  for (int i = tid; i < 1024; i += 256) {
    px[i] = PN[((b << 10) + i) * 2 + 0];
    py[i] = PN[((b << 10) + i) * 2 + 1];
  }
  __syncthreads();
  int t = tg * 32 + tl;
  float tx = px[t], ty = py[t];
  float d8[8]; int i8[8];
  #pragma unroll
  for (int i = 0; i < 8; i++) { d8[i] = 3.4e38f; i8[i] = 0x7fffffff; }
  int s0 = chunk * 128;
  for (int s = s0; s < s0 + 128; s++) {
    float dx = __fadd_rn(px[s], -tx), dy = __fadd_rn(py[s], -ty);
    float d2 = __fadd_rn(__fadd_rn(__fmul_rn(dx, dx), __fmul_rn(dy, dy)), 1e-12f);
    float d = sqrtf(d2);
    if (d < d8[7]) {
      d8[7] = d; i8[7] = s;
      #pragma unroll
      for (int p = 7; p > 0; p--) {
        if (d8[p] < d8[p - 1]) {
          float td = d8[p]; d8[p] = d8[p - 1]; d8[p - 1] = td;
          int ti = i8[p]; i8[p] = i8[p - 1]; i8[p - 1] = ti;
        }
      }
    }
  }
  #pragma unroll
  for (int i = 0; i < 8; i++) { candD[tl][chunk * 8 + i] = d8[i]; candI[tl][chunk * 8 + i] = i8[i]; }
  __syncthreads();
  if (chunk == 0) {
    float D[8]; int I[8];
    #pragma unroll
    for (int i = 0; i < 8; i++) { D[i] = candD[tl][i]; I[i] = candI[tl][i]; }
    for (int c = 1; c < 8; c++) {
      for (int j = 0; j < 8; j++) {
        float d = candD[tl][c * 8 + j]; int idx = candI[tl][c * 8 + j];
        bool better = (d < D[7]) || (d == D[7] && idx < I[7]);
        if (!better) break;
        D[7] = d; I[7] = idx;
        #pragma unroll
        for (int p = 7; p > 0; p--) {
          bool sw = (D[p] < D[p - 1]) || (D[p] == D[p - 1] && I[p] < I[p - 1]);
          if (sw) {
            float td = D[p]; D[p] = D[p - 1]; D[p - 1] = td;
            int ti = I[p]; I[p] = I[p - 1]; I[p - 1] = ti;
          }
        }
      }
    }
    #pragma unroll
    for (int i = 0; i < 8; i++) NBR[((long)((b << 10) + t)) * 8 + i] = I[i];
  }
}

// ---------- positional embedding MLP ----------
__global__ __launch_bounds__(128) void pos_embed(
    const float* __restrict__ cellp, const float* __restrict__ tab,
    const float* __restrict__ W1, const float* __restrict__ b1,
    const float* __restrict__ W2, const float* __restrict__ b2,
    float* __restrict__ X)
{
  int row = blockIdx.x, c = blockIdx.y, tid = threadIdx.x;
  __shared__ float e[128], h1[128];
  float pos = cellp[row * 2 + c];
  pos = fminf(fmaxf(pos, 0.f), 1000.f);
  int pi = (int)pos;
  e[tid] = tab[((long)(c * 1001 + pi)) * 128 + tid];
  __syncthreads();
  {
    const float* w1r = W1 + ((long)(c * 128 + tid)) * 128;
    float a = b1[c * 128 + tid];
    for (int i = 0; i < 128; i++) a += e[i] * w1r[i];
    h1[tid] = fmaxf(a, 0.f);
  }
  __syncthreads();
  {
    const float* w2r = W2 + ((long)(c * 128 + tid)) * 128;
    float o = b2[c * 128 + tid];
    for (int i = 0; i < 128; i++) o += h1[i] * w2r[i];
    X[(long)row * 256 + c * 128 + tid] += o;
  }
}

// ---------- GAT scores ----------
__global__ __launch_bounds__(256) void gat_scores(const float* __restrict__ Hh,
    const float* __restrict__ asrcW, const float* __restrict__ adstW,
    float* __restrict__ ASRC, float* __restrict__ ADST)
{
  int row = blockIdx.x, tid = threadIdx.x;
  __shared__ float red[256];
  float v = Hh[(long)row * 256 + tid];
  float s1 = v * asrcW[tid];
  float s2 = v * adstW[tid];
  red[tid] = s1; __syncthreads();
  for (int off = 64; off > 0; off >>= 1) { if ((tid & 127) < off) red[tid] += red[tid + off]; __syncthreads(); }
  if ((tid & 127) == 0) ASRC[row * 2 + (tid >> 7)] = red[tid];
  __syncthreads();
  red[tid] = s2; __syncthreads();
  for (int off = 64; off > 0; off >>= 1) { if ((tid & 127) < off) red[tid] += red[tid + off]; __syncthreads(); }
  if ((tid & 127) == 0) ADST[row * 2 + (tid >> 7)] = red[tid];
}

// ---------- GAT aggregate + residual + LN ----------
__global__ __launch_bounds__(256) void gat_aggr_ln(
    const float* __restrict__ Hh, const float* __restrict__ ASRC, const float* __restrict__ ADST,
    const int* __restrict__ NBR, const float* __restrict__ gbias,
    const float* __restrict__ lng, const float* __restrict__ lnb,
    float* __restrict__ X, ushort* __restrict__ Xb)
{
  int row = blockIdx.x, tid = threadIdx.x;
  int b = row >> 10;
  __shared__ int nb[8];
  __shared__ float w[2][8];
  __shared__ float red[256];
  if (tid < 8) {
    int v = NBR[(long)row * 8 + tid];
    nb[tid] = min(max(v, 0), 1023);
  }
  __syncthreads();
  if (tid < 16) {
    int i = tid & 7, h = tid >> 3;
    float e = ADST[row * 2 + h] + ASRC[((b << 10) + nb[i]) * 2 + h];
    w[h][i] = (e >= 0.f) ? e : 0.2f * e;
  }
  __syncthreads();
  if (tid < 2) {
    float m = -3.4e38f;
    for (int i = 0; i < 8; i++) m = fmaxf(m, w[tid][i]);
    float s = 0.f;
    for (int i = 0; i < 8; i++) { float e = expf(w[tid][i] - m); w[tid][i] = e; s += e; }
    float inv = 1.f / s;
    for (int i = 0; i < 8; i++) w[tid][i] *= inv;
  }
  __syncthreads();
  int h = tid >> 7, c = tid & 127;
  float acc = 0.f;
  #pragma unroll
  for (int i = 0; i < 8; i++)
    acc += w[h][i] * Hh[((long)((b << 10) + nb[i])) * 256 + h * 128 + c];
  float v = acc + gbias[tid] + X[(long)row * 256 + tid];
  float mean = blk_sum256(v, red) * (1.f / 256.f);
  float dv = v - mean;
  float var = blk_sum256(dv * dv, red) * (1.f / 256.f);
  float o = dv * rsqrtf(var + 1e-5f) * lng[tid] + lnb[tid];
  X[(long)row * 256 + tid] = o;
  Xb[(long)row * 256 + tid] = f2b(o);
}

// ---------- residual + LayerNorm, D=256, one wave per row ----------
__global__ __launch_bounds__(256) void add_ln4(const float* __restrict__ res,
    const float* __restrict__ Yv, const float* __restrict__ g, const float* __restrict__ b,
    float* __restrict__ out, ushort* __restrict__ outb)
{
  int wave = threadIdx.x >> 6, lane = threadIdx.x & 63;
  long row = blockIdx.x * 4 + wave;
  const float* yr = Yv + row * 256;
  const float* rr = res ? res + row * 256 : nullptr;
  float v[4];
  float s = 0.f;
  #pragma unroll
  for (int i = 0; i < 4; i++) {
    int d = lane + i * 64;
    float x = yr[d];
    if (rr) x += rr[d];
    v[i] = x; s += x;
  }
  #pragma unroll
  for (int off = 32; off > 0; off >>= 1) s += __shfl_xor(s, off);
  float mean = s * (1.f / 256.f);
  float vs = 0.f;
  #pragma unroll
  for (int i = 0; i < 4; i++) { float dv = v[i] - mean; vs += dv * dv; }
  #pragma unroll
  for (int off = 32; off > 0; off >>= 1) vs += __shfl_xor(vs, off);
  float rstd = rsqrtf(vs * (1.f / 256.f) + 1e-5f);
  #pragma unroll
  for (int i = 0; i < 4; i++) {
    int d = lane + i * 64;
    float o = (v[i] - mean) * rstd * g[d] + b[d];
    out[row * 256 + d] = o;
    if (outb) outb[row * 256 + d] = f2b(o);
  }
}

// ---------- LayerNorm (D=1024, head rows) ----------
__global__ __launch_bounds__(256) void add_ln_big(const float* __restrict__ Yv,
    const float* __restrict__ g, const float* __restrict__ b,
    float* __restrict__ out)
{
  int row = blockIdx.x, tid = threadIdx.x;
  __shared__ float red[256];
  float vals[4];
  float s = 0.f;
  #pragma unroll
  for (int i = 0; i < 4; i++) {
    int d = tid + (i << 8);
    float v = Yv[(long)row * 1024 + d];
    vals[i] = v; s += v;
  }
  float mean = blk_sum256(s, red) * (1.f / 1024.f);
  s = 0.f;
  #pragma unroll
  for (int i = 0; i < 4; i++) { float dv = vals[i] - mean; s += dv * dv; }
  float var = blk_sum256(s, red) * (1.f / 1024.f);
  float rstd = rsqrtf(var + 1e-5f);
  #pragma unroll
  for (int i = 0; i < 4; i++) {
    int d = tid + (i << 8);
    out[(long)row * 1024 + d] = (vals[i] - mean) * rstd * g[d] + b[d];
  }
}

// ---------- MFMA flash attention ----------
__global__ __launch_bounds__(256) void flash_mfma(const ushort* __restrict__ QKV,
                                                  const ushort* __restrict__ VT,
                                                  ushort* __restrict__ O)
{
  const float scale = 0.08838834764831845f;
  int blk = blockIdx.x;
  int qt = blk & 15, bh = blk >> 4;
  int b = bh >> 1, h = bh & 1;
  const ushort* qkg = QKV + (long)b * 1024 * 768 + h * 128;
  const ushort* vtg = VT + ((long)bh << 17);

  __shared__ ushort Qs[64][136];
  __shared__ ushort Ks[64][136];
  __shared__ ushort Vt[128][72];
  __shared__ ushort Ps[4][16][72];

  int tid = threadIdx.x;
  int wave = tid >> 6, lane = tid & 63;
  int quad = lane >> 4, l16 = lane & 15;

  #pragma unroll
  for (int p = 0; p < 4; p++) {
    int idx = p * 256 + tid;
    int r = idx >> 4, c8 = (idx & 15) * 8;
    *(uint4*)&Qs[r][c8] = *(const uint4*)(qkg + (long)(qt * 64 + r) * 768 + c8);
  }
  __syncthreads();
  bf16x8 af[4];
  #pragma unroll
  for (int ks = 0; ks < 4; ks++)
    af[ks] = *(const bf16x8*)&Qs[wave * 16 + l16][ks * 32 + quad * 8];

  f32x4 Oacc[8];
  f32x4 zero4 = {0.f, 0.f, 0.f, 0.f};
  #pragma unroll
  for (int j = 0; j < 8; j++) Oacc[j] = zero4;
  float mr[4], lr[4];
  #pragma unroll
  for (int r = 0; r < 4; r++) { mr[r] = -3.4e38f; lr[r] = 0.f; }

  for (int kt = 0; kt < 16; kt++) {
    __syncthreads();
    #pragma unroll
    for (int p = 0; p < 4; p++) {
      int idx = p * 256 + tid;
      int r = idx >> 4, c8 = (idx & 15) * 8;
      *(uint4*)&Ks[r][c8] = *(const uint4*)(qkg + (long)(kt * 64 + r) * 768 + 256 + c8);
      int c = idx >> 3, k8 = (idx & 7) * 8;
      *(uint4*)&Vt[c][k8] = *(const uint4*)(vtg + ((long)c << 10) + kt * 64 + k8);
    }
    __syncthreads();
    f32x4 acc[4];
    #pragma unroll
    for (int j = 0; j < 4; j++) acc[j] = zero4;
    #pragma unroll
    for (int ks = 0; ks < 4; ks++) {
      #pragma unroll
      for (int j = 0; j < 4; j++) {
        bf16x8 kb = *(const bf16x8*)&Ks[j * 16 + l16][ks * 32 + quad * 8];
        acc[j] = __builtin_amdgcn_mfma_f32_16x16x32_bf16(af[ks], kb, acc[j], 0, 0, 0);
      }
    }
    float sv[4][4], tmax[4];
    #pragma unroll
    for (int r = 0; r < 4; r++) tmax[r] = -3.4e38f;
    #pragma unroll
    for (int j = 0; j < 4; j++)
      #pragma unroll
      for (int r = 0; r < 4; r++) {
        float x = acc[j][r] * scale;
        sv[j][r] = x;
        tmax[r] = fmaxf(tmax[r], x);
      }
    #pragma unroll
    for (int off = 1; off < 16; off <<= 1)
      #pragma unroll
      for (int r = 0; r < 4; r++) tmax[r] = fmaxf(tmax[r], __shfl_xor(tmax[r], off));
    float alpha[4], rsum[4];
    #pragma unroll
    for (int r = 0; r < 4; r++) {
      float mn = fmaxf(mr[r], tmax[r]);
      alpha[r] = expf(mr[r] - mn);
      mr[r] = mn;
      rsum[r] = 0.f;
    }
    #pragma unroll
    for (int j = 0; j < 4; j++)
      #pragma unroll
      for (int r = 0; r < 4; r++) {
        float p = expf(sv[j][r] - mr[r]);
        sv[j][r] = p;
        rsum[r] += p;
      }
    #pragma unroll
    for (int off = 1; off < 16; off <<= 1)
      #pragma unroll
      for (int r = 0; r < 4; r++) rsum[r] += __shfl_xor(rsum[r], off);
    #pragma unroll
    for (int r = 0; r < 4; r++) lr[r] = lr[r] * alpha[r] + rsum[r];
    #pragma unroll
    for (int j = 0; j < 4; j++)
      #pragma unroll
      for (int r = 0; r < 4; r++)
        Ps[wave][quad * 4 + r][j * 16 + l16] = f2b(sv[j][r]);
    #pragma unroll
    for (int jj = 0; jj < 8; jj++)
      #pragma unroll
      for (int r = 0; r < 4; r++) Oacc[jj][r] *= alpha[r];
    __syncthreads();
    #pragma unroll
    for (int s = 0; s < 2; s++) {
      bf16x8 pa = *(const bf16x8*)&Ps[wave][l16][s * 32 + quad * 8];
      #pragma unroll
      for (int jj = 0; jj < 8; jj++) {
        bf16x8 vb = *(const bf16x8*)&Vt[jj * 16 + l16][s * 32 + quad * 8];
        Oacc[jj] = __builtin_amdgcn_mfma_f32_16x16x32_bf16(pa, vb, Oacc[jj], 0, 0, 0);
      }
    }
  }
  long row0 = (long)b * 1024 + qt * 64 + wave * 16 + quad * 4;
  #pragma unroll
  for (int jj = 0; jj < 8; jj++) {
    int col = h * 128 + jj * 16 + l16;
    #pragma unroll
    for (int r = 0; r < 4; r++)
      O[(row0 + r) * 256 + col] = f2b(Oacc[jj][r] / lr[r]);
  }
}

// ---------- split-K pooling attention: partials over 128-key chunks ----------
// grid (8 chunks, 32 id) x 128 threads. id = b*8 + nq*2 + h.
// Writes PM/PL (max, expsum) and PO[128] per (id, chunk).
__global__ __launch_bounds__(128) void pool_split(
    const float* __restrict__ qe, const float* __restrict__ pinW, const float* __restrict__ pinB,
    const float* __restrict__ srand, const ushort* __restrict__ KV,
    float* __restrict__ PM, float* __restrict__ PL, float* __restrict__ PO)
{
  int cid = blockIdx.x;            // key chunk 0..7
  int id = blockIdx.y;             // 0..31
  int h = id & 1, nq = (id >> 1) & 3, b = id >> 3;
  int tid = threadIdx.x;           // 128
  __shared__ float qs[128];
  __shared__ float eg[128];
  __shared__ float red[128];
  // q = queries[nq] @ Wq^T + bq  (redundant across chunks; 256 MACs)
  {
    float a = pinB[h * 128 + tid];
    const float* wr = pinW + ((long)(h * 128 + tid)) * 256;
    const float* qr = qe + nq * 256;
    for (int i = 0; i < 256; i++) a += qr[i] * wr[i];
    qs[tid] = a;
  }
  __syncthreads();
  const float scale = 0.08838834764831845f;
  // logits for this thread's key
  int s = cid * 128 + tid;
  float d = 0.f;
  {
    const ushort* kr = KV + ((long)((b << 10) + s)) * 512 + h * 128;
    #pragma unroll
    for (int c8 = 0; c8 < 128; c8 += 8) {
      uint4 kv4 = *(const uint4*)(kr + c8);
      const ushort* kp = (const ushort*)&kv4;
      #pragma unroll
      for (int j = 0; j < 8; j++) d += qs[c8 + j] * b2f(kp[j]);
    }
  }
  float lg = d * scale + ((srand[nq * 1024 + s] < 0.3f) ? 0.f : -1e9f);
  // chunk max
  red[tid] = lg; __syncthreads();
  for (int off = 64; off > 0; off >>= 1) { if (tid < off) red[tid] = fmaxf(red[tid], red[tid + off]); __syncthreads(); }
  float m = red[0]; __syncthreads();
  float e = expf(lg - m);
  eg[tid] = e;
  red[tid] = e; __syncthreads();
  for (int off = 64; off > 0; off >>= 1) { if (tid < off) red[tid] += red[tid + off]; __syncthreads(); }
  float l = red[0];
  __syncthreads();
  // partial PV: thread c sums over this chunk's 128 keys
  float o = 0.f;
  const ushort* vbase = KV + ((long)((b << 10) + cid * 128)) * 512 + 256 + h * 128 + tid;
  for (int ss = 0; ss < 128; ss++)
    o += eg[ss] * b2f(vbase[(long)ss * 512]);
  int part = id * 8 + cid;
  PO[(long)part * 128 + tid] = o;
  if (tid == 0) { PM[part] = m; PL[part] = l; }
}

// merge 8 chunk-partials with exp rescale -> ATTP
__global__ __launch_bounds__(128) void pool_merge(
    const float* __restrict__ PM, const float* __restrict__ PL, const float* __restrict__ PO,
    float* __restrict__ ATTP)
{
  int id = blockIdx.x;             // 0..31
  int h = id & 1, nq = (id >> 1) & 3, b = id >> 3;
  int tid = threadIdx.x;           // 128
  float m = -3.4e38f;
  #pragma unroll
  for (int c = 0; c < 8; c++) m = fmaxf(m, PM[id * 8 + c]);
  float l = 0.f, o = 0.f;
  #pragma unroll
  for (int c = 0; c < 8; c++) {
    float w = expf(PM[id * 8 + c] - m);
    l += PL[id * 8 + c] * w;
    o += PO[(long)(id * 8 + c) * 128 + tid] * w;
  }
  ATTP[(b * 4 + nq) * 256 + h * 128 + tid] = o / l;
}

// ---------- combined = [mean over N | pooled_att], 1024 threads ----------
__global__ __launch_bounds__(1024) void combined_kernel(const float* __restrict__ X,
    const float* __restrict__ ATTO, float* __restrict__ CMB)
{
  int b = blockIdx.x, tid = threadIdx.x;
  int d = tid & 255, ch = tid >> 8;
  __shared__ float part[4][256];
  float s = 0.f;
  int n0 = ch * 256;
  for (int n = n0; n < n0 + 256; n++) s += X[((long)((b << 10) + n)) * 256 + d];
  part[ch][d] = s;
  __syncthreads();
  if (ch == 0) {
    float tot = part[0][d] + part[1][d] + part[2][d] + part[3][d];
    CMB[b * 1280 + d] = tot * (1.f / 1024.f);
    #pragma unroll
    for (int q = 0; q < 4; q++)
      CMB[b * 1280 + 256 + q * 256 + d] = ATTO[(b * 4 + q) * 256 + d];
  }
}

__global__ void store_out(const float* __restrict__ src, float* __restrict__ dst, int n) {
  int i = blockIdx.x * blockDim.x + threadIdx.x;
  if (i < n) dst[i] = src[i];
}
__global__ void fill_out_zero(float* __restrict__ dst, int n) {
  int i = blockIdx.x * blockDim.x + threadIdx.x;
  if (i < n) dst[i] = 0.f;
}

extern "C" void kernel_launch(void* const* d_in, const int* in_sizes, int n_in,
                              void* d_out, int out_size, void* d_ws, size_t ws_size,
                              hipStream_t stream)
{
  const float* inp      = (const float*)d_in[0];
  const float* cellp    = (const float*)d_in[1];
  const float* srand    = (const float*)d_in[2];
  const float* emb_W    = (const float*)d_in[3];
  const float* emb_b    = (const float*)d_in[4];
  const float* pe_tab   = (const float*)d_in[5];
  const float* pe_W1    = (const float*)d_in[6];
  const float* pe_b1    = (const float*)d_in[7];
  const float* pe_W2    = (const float*)d_in[8];
  const float* pe_b2    = (const float*)d_in[9];
  const float* gat_W    = (const float*)d_in[10];
  const float* gat_asrc = (const float*)d_in[11];
  const float* gat_adst = (const float*)d_in[12];
  const float* gat_b    = (const float*)d_in[13];
  const float* ln_g     = (const float*)d_in[14];
  const float* ln_b     = (const float*)d_in[15];
  const float* qkv_W    = (const float*)d_in[16];
  const float* qkv_b    = (const float*)d_in[17];
  const float* out_W    = (const float*)d_in[18];
  const float* out_b    = (const float*)d_in[19];
  const float* ff1_W    = (const float*)d_in[20];
  const float* ff1_b    = (const float*)d_in[21];
  const float* ff2_W    = (const float*)d_in[22];
  const float* ff2_b    = (const float*)d_in[23];
  const float* ln1_g    = (const float*)d_in[24];
  const float* ln1_b    = (const float*)d_in[25];
  const float* ln2_g    = (const float*)d_in[26];
  const float* ln2_b    = (const float*)d_in[27];
  const float* q_emb    = (const float*)d_in[28];
  const float* pin_W    = (const float*)d_in[29];
  const float* pin_b    = (const float*)d_in[30];
  const float* pout_W   = (const float*)d_in[31];
  const float* pout_b   = (const float*)d_in[32];
  const float* m1_W     = (const float*)d_in[33];
  const float* m1_b     = (const float*)d_in[34];
  const float* mln1_g   = (const float*)d_in[35];
  const float* mln1_b   = (const float*)d_in[36];
  const float* m2_W     = (const float*)d_in[37];
  const float* m2_b     = (const float*)d_in[38];
  const float* mln2_g   = (const float*)d_in[39];
  const float* mln2_b   = (const float*)d_in[40];
  const float* m3_W     = (const float*)d_in[41];
  const float* m3_b     = (const float*)d_in[42];
  const float* c1_W     = (const float*)d_in[43];
  const float* c1_b     = (const float*)d_in[44];
  const float* c2_W     = (const float*)d_in[45];
  const float* c2_b     = (const float*)d_in[46];
  const float* c3_W     = (const float*)d_in[47];
  const float* c3_b     = (const float*)d_in[48];
  const float* c4_W     = (const float*)d_in[49];
  const float* c4_b     = (const float*)d_in[50];
  (void)in_sizes; (void)n_in;

  // ---- workspace (bytes, 256-aligned; ~20.5 MB) ----
  char* base = (char*)d_ws;
  size_t off = 0;
  auto alloc = [&](size_t bytes) { void* p = base + off; off += (bytes + 255) & ~size_t(255); return p; };
  float* PN    = (float*)alloc(32768);
  float* AS    = (float*)alloc(32768);
  float* AD    = (float*)alloc(32768);
  float* ATTP  = (float*)alloc(16384);
  float* ATTO  = (float*)alloc(16384);
  float* CMB   = (float*)alloc(20480);
  float* Ha    = (float*)alloc(16384);
  float* Hb    = (float*)alloc(16384);
  float* Hc    = (float*)alloc(16640);
  float* Hd    = (float*)alloc(8192);
  float* He    = (float*)alloc(4096);
  float* Hf    = (float*)alloc(512);
  float* Pk    = (float*)alloc(262144);           // split-K partials (head MLP)
  float* PPM   = (float*)alloc(1024);             // pool partial max [256]
  float* PPL   = (float*)alloc(1024);             // pool partial expsum [256]
  float* PPO   = (float*)alloc(131072);           // pool partial PV [256][128]
  int*   NBR   = (int*)alloc(131072);
  float* X     = (float*)alloc(4194304);          // fp32 residual stream [4096,256]
  ushort* Xb   = (ushort*)alloc(2097152);         // bf16 shadow of X
  char*  Rq    = (char*)alloc(6291456);           // QKVb bf16 | F2 fp32 | KVb bf16
  char*  Rf    = (char*)alloc(4194304);           // Ob | VT | FFBb (time-sliced)
  ushort* QKVb = (ushort*)Rq;
  float*  F2   = (float*)Rq;
  ushort* KVb  = (ushort*)Rq;
  ushort* Ob   = (ushort*)Rf;
  ushort* VT   = (ushort*)(Rf + 2097152);
  ushort* FFBb = (ushort*)Rf;
  float*  F1   = (float*)alloc(4194304);
  if (ws_size < off) { fill_out_zero<<<1, 128, 0, stream>>>((float*)d_out, out_size); return; }

  // ---- graph construction ----
  bag_stats<<<4, 256, 0, stream>>>(cellp, PN);
  knn_kernel<<<128, 256, 0, stream>>>(PN, NBR);

  // ---- embedding + positional MLP ----
  mgemm<float>(stream, inp, 512, emb_W, 512, emb_b, X, 256, 4096, 256, 512, 0);
  pos_embed<<<dim3(4096, 2), 128, 0, stream>>>(cellp, pe_tab, pe_W1, pe_b1, pe_W2, pe_b2, X);
  cvt_f2b<<<1024, 256, 0, stream>>>(X, Xb, 4096 * 256);

  // ---- 2x GAT ----
  for (int l = 0; l < 2; l++) {
    mgemm<float>(stream, Xb, 256, gat_W + l * 65536, 256, (const float*)nullptr, F1, 256,
                 4096, 256, 256, 0);
    gat_scores<<<4096, 256, 0, stream>>>(F1, gat_asrc + l * 256, gat_adst + l * 256, AS, AD);
    gat_aggr_ln<<<4096, 256, 0, stream>>>(F1, AS, AD, NBR, gat_b + l * 256, ln_g, ln_b, X, Xb);
  }

  // ---- 2x Transformer encoder layer ----
  for (int l = 0; l < 2; l++) {
    mgemm_vt(stream, Xb, 256, qkv_W + (long)l * 768 * 256, 256, qkv_b + l * 768,
             QKVb, 768, 4096, 768, 256, VT);
    flash_mfma<<<256, 256, 0, stream>>>(QKVb, VT, Ob);
    mgemm<float>(stream, Ob, 256, out_W + l * 65536, 256, out_b + l * 256, F2, 256,
                 4096, 256, 256, 0);
    add_ln4<<<1024, 256, 0, stream>>>(X, F2, ln1_g + l * 256, ln1_b + l * 256, X, Xb);
    for (int ch = 0; ch < 2; ch++) {
      mgemm<ushort>(stream, Xb + (long)ch * 2048 * 256, 256, ff1_W + l * 262144, 256,
                    ff1_b + l * 1024, FFBb, 1024, 2048, 1024, 256, 1);
      mgemm<float>(stream, FFBb, 1024, ff2_W + l * 262144, 1024, ff2_b + l * 256,
                   F2 + (long)ch * 2048 * 256, 256, 2048, 256, 1024, 0);
    }
    add_ln4<<<1024, 256, 0, stream>>>(X, F2, ln2_g + l * 256, ln2_b + l * 256, X, Xb);
  }

  // ---- final LN ----
  add_ln4<<<1024, 256, 0, stream>>>((const float*)nullptr, X, ln_g, ln_b, X, Xb);

  // ---- pooling (split-K flash-decode style) ----
  mgemm<ushort>(stream, Xb, 256, pin_W + 65536, 256, pin_b + 256, KVb, 512, 4096, 512, 256, 0);
  pool_split<<<dim3(8, 32), 128, 0, stream>>>(q_emb, pin_W, pin_b, srand, KVb, PPM, PPL, PPO);
  pool_merge<<<32, 128, 0, stream>>>(PPM, PPL, PPO, ATTP);
  sgemm<16>(stream, ATTP, 256, pout_W, 256, pout_b, ATTO, Pk, 256, 2, 0);
  combined_kernel<<<4, 1024, 0, stream>>>(X, ATTO, CMB);

  // ---- MLP head (fp32, split-K skinny GEMMs) ----
  sgemm<4>(stream, CMB, 1280, m1_W, 1280, m1_b, Ha, Pk, 1024, 8, 1);
  add_ln_big<<<4, 256, 0, stream>>>(Ha, mln1_g, mln1_b, Ha);
  sgemm<4>(stream, Ha, 1024, m2_W, 1024, m2_b, Hb, Pk, 1024, 8, 1);
  add_ln_big<<<4, 256, 0, stream>>>(Hb, mln2_g, mln2_b, Hb);
  sgemm<4>(stream, Hb, 1024, m3_W, 1024, m3_b, Ha, Pk, 1024, 8, 0);
  sgemm<4>(stream, Ha, 1024, c1_W, 1024, c1_b, Hc, Pk, 1032, 8, 1);
  sgemm<4>(stream, Hc, 1032, c2_W, 1032, c2_b, Hd, Pk, 512, 8, 1);
  sgemm<4>(stream, Hd, 512, c3_W, 512, c3_b, He, Pk, 256, 4, 1);
  sgemm<4>(stream, He, 256, c4_W, 256, c4_b, Hf, Pk, 24, 2, 0);
  store_out<<<1, 128, 0, stream>>>(Hf, (float*)d_out, out_size);
}

// Round 9
// 803.735 us; speedup vs baseline: 4.9566x; 1.1388x over previous
//
#include <hip/hip_runtime.h>
#include <hip/hip_bf16.h>

// MILCellModel forward on MI355X. Round 9: fused MFMA pos-embed MLP
// (gather + 2-layer per-coordinate MLP on matrix cores, weights LDS-resident).
// R8 profile: pos_embed 132us at 5.7% VALUBusy -- serial per-thread MACs.
// B=4 N=1024 E=512 D=256 H=2 C=128 FF=1024 NQ=4 NCLS=24

typedef __bf16 bf16x8 __attribute__((ext_vector_type(8)));
typedef float  f32x4  __attribute__((ext_vector_type(4)));

__device__ __forceinline__ ushort f2b(float f) {
  __hip_bfloat16 h = __float2bfloat16(f);
  return *(ushort*)&h;
}
__device__ __forceinline__ float b2f(ushort u) {
  union { unsigned i; float f; } v; v.i = ((unsigned)u) << 16; return v.f;
}

// ---------- block reductions (256 threads) ----------
__device__ __forceinline__ float blk_sum256(float v, float* red) {
  int t = threadIdx.x;
  red[t] = v; __syncthreads();
  #pragma unroll
  for (int off = 128; off > 0; off >>= 1) {
    if (t < off) red[t] += red[t + off];
    __syncthreads();
  }
  float r = red[0]; __syncthreads();
  return r;
}

// ---------- fp32 -> bf16 convert ----------
__global__ __launch_bounds__(256) void cvt_f2b(const float* __restrict__ src,
                                               ushort* __restrict__ dst, int n) {
  int i = (blockIdx.x * 256 + threadIdx.x) * 4;
  if (i >= n) return;
  float4 v = *(const float4*)(src + i);
  ushort4 o;
  o.x = f2b(v.x); o.y = f2b(v.y); o.z = f2b(v.z); o.w = f2b(v.w);
  *(ushort4*)(dst + i) = o;
}

// ---------- staging helpers: 8 contiguous elements -> bf16 LDS ----------
__device__ __forceinline__ void stage8(const ushort* __restrict__ src, ushort* dst) {
  *(uint4*)dst = *(const uint4*)src;
}
__device__ __forceinline__ void stage8(const float* __restrict__ src, ushort* dst) {
  float4 a = ((const float4*)src)[0];
  float4 b = ((const float4*)src)[1];
  ushort4 o0, o1;
  o0.x = f2b(a.x); o0.y = f2b(a.y); o0.z = f2b(a.z); o0.w = f2b(a.w);
  o1.x = f2b(b.x); o1.y = f2b(b.y); o1.z = f2b(b.z); o1.w = f2b(b.w);
  *(ushort4*)dst = o0;
  *(ushort4*)(dst + 4) = o1;
}

// ---------- bf16 MFMA GEMM: C[M,N] = act(A[M,K] @ B^T + bias) ----------
template<typename CT, typename AT, typename WT, bool VSPLIT>
__global__ __launch_bounds__(256) void mfma_gemm(
    const AT* __restrict__ A, int lda,
    const WT* __restrict__ Bw, int ldb,
    const float* __restrict__ bias,
    CT* __restrict__ C, int ldc, int K, int relu,
    ushort* __restrict__ VT)
{
  __shared__ ushort As[64][40];
  __shared__ ushort Bs[128][40];
  int tid = threadIdx.x;
  int lane = tid & 63, wave = tid >> 6;
  int wm = wave >> 1, wn = wave & 1;
  int quad = lane >> 4, l16 = lane & 15;
  long mBase = blockIdx.y * 64, nBase = blockIdx.x * 128;

  f32x4 zero4 = {0.f, 0.f, 0.f, 0.f};
  f32x4 acc[2][4];
  #pragma unroll
  for (int i = 0; i < 2; i++)
    #pragma unroll
    for (int j = 0; j < 4; j++) acc[i][j] = zero4;

  for (int k0 = 0; k0 < K; k0 += 32) {
    {
      int r = tid >> 2, sg = (tid & 3) * 8;
      stage8(A + (mBase + r) * lda + k0 + sg, &As[r][sg]);
    }
    #pragma unroll
    for (int p = 0; p < 2; p++) {
      int idx = p * 256 + tid;
      int r = idx >> 2, sg = (idx & 3) * 8;
      stage8(Bw + (nBase + r) * ldb + k0 + sg, &Bs[r][sg]);
    }
    __syncthreads();
    bf16x8 af[2], bfr[4];
    #pragma unroll
    for (int i = 0; i < 2; i++)
      af[i] = *(const bf16x8*)&As[wm * 32 + i * 16 + l16][quad * 8];
    #pragma unroll
    for (int j = 0; j < 4; j++)
      bfr[j] = *(const bf16x8*)&Bs[wn * 64 + j * 16 + l16][quad * 8];
    #pragma unroll
    for (int i = 0; i < 2; i++)
      #pragma unroll
      for (int j = 0; j < 4; j++)
        acc[i][j] = __builtin_amdgcn_mfma_f32_16x16x32_bf16(af[i], bfr[j], acc[i][j], 0, 0, 0);
    __syncthreads();
  }
  #pragma unroll
  for (int i = 0; i < 2; i++) {
    #pragma unroll
    for (int j = 0; j < 4; j++) {
      long col = nBase + wn * 64 + j * 16 + l16;
      float bv = bias ? bias[col] : 0.f;
      long row0 = mBase + wm * 32 + i * 16 + quad * 4;
      if (VSPLIT && col >= 512) {
        int cm = (int)col - 512, hh = cm >> 7, cc = cm & 127;
        long bidx = row0 >> 10, n0 = row0 & 1023;
        ushort4 o;
        o.x = f2b(acc[i][j][0] + bv);
        o.y = f2b(acc[i][j][1] + bv);
        o.z = f2b(acc[i][j][2] + bv);
        o.w = f2b(acc[i][j][3] + bv);
        *(ushort4*)&VT[(((bidx * 2 + hh) * 128 + cc) << 10) + n0] = o;
      } else {
        #pragma unroll
        for (int r = 0; r < 4; r++) {
          float v = acc[i][j][r] + bv;
          if (relu) v = fmaxf(v, 0.f);
          if constexpr (sizeof(CT) == 2) C[(row0 + r) * ldc + col] = f2b(v);
          else                           C[(row0 + r) * ldc + col] = v;
        }
      }
    }
  }
}

template<typename CT, typename AT, typename WT>
static void mgemm(hipStream_t st, const AT* A, int lda, const WT* B, int ldb,
                  const float* bias, CT* C, int ldc, int M, int N, int K, int relu) {
  dim3 grid(N / 128, M / 64);
  mfma_gemm<CT, AT, WT, false><<<grid, 256, 0, st>>>(A, lda, B, ldb, bias, C, ldc, K, relu, nullptr);
}
template<typename AT, typename WT>
static void mgemm_vt(hipStream_t st, const AT* A, int lda, const WT* B, int ldb,
                     const float* bias, ushort* C, int ldc, int M, int N, int K, ushort* VT) {
  dim3 grid(N / 128, M / 64);
  mfma_gemm<ushort, AT, WT, true><<<grid, 256, 0, st>>>(A, lda, B, ldb, bias, C, ldc, K, 0, VT);
}

// ---------- fused pos-embed MLP (MFMA, weights LDS-resident) ----------
// grid (64 row-tiles, 2 coords). Per block: gather 64 embedding rows (bf16),
// H1 = relu(E @ W1[c]^T + b1[c]), OUT = H1 @ W2[c]^T + b2[c], X += OUT.
__global__ __launch_bounds__(256) void pos_mlp(
    const float* __restrict__ cellp, const float* __restrict__ tab,
    const float* __restrict__ W1, const float* __restrict__ b1,
    const float* __restrict__ W2, const float* __restrict__ b2,
    float* __restrict__ X)
{
  __shared__ ushort Es[64][136];
  __shared__ ushort Bs[128][136];
  __shared__ ushort H1s[64][136];
  int tid = threadIdx.x;
  int lane = tid & 63, wave = tid >> 6;
  int wm = wave >> 1, wn = wave & 1;
  int quad = lane >> 4, l16 = lane & 15;
  int r0 = blockIdx.x * 64, c = blockIdx.y;

  // gather E rows (table lookup, fp32 -> bf16)
  #pragma unroll
  for (int p = 0; p < 4; p++) {
    int idx = p * 256 + tid;
    int r = idx >> 4, c8 = (idx & 15) * 8;
    float pos = cellp[(r0 + r) * 2 + c];
    pos = fminf(fmaxf(pos, 0.f), 1000.f);
    int pi = (int)pos;
    stage8(tab + ((long)(c * 1001 + pi)) * 128 + c8, &Es[r][c8]);
  }
  // stage W1[c] (128x128 fp32 -> bf16)
  #pragma unroll
  for (int p = 0; p < 8; p++) {
    int idx = p * 256 + tid;
    int r = idx >> 4, c8 = (idx & 15) * 8;
    stage8(W1 + ((long)(c * 128 + r)) * 128 + c8, &Bs[r][c8]);
  }
  __syncthreads();

  f32x4 zero4 = {0.f, 0.f, 0.f, 0.f};
  f32x4 acc[2][4];
  #pragma unroll
  for (int i = 0; i < 2; i++)
    #pragma unroll
    for (int j = 0; j < 4; j++) acc[i][j] = zero4;
  #pragma unroll
  for (int ks = 0; ks < 4; ks++) {
    bf16x8 af[2], bfr[4];
    #pragma unroll
    for (int i = 0; i < 2; i++)
      af[i] = *(const bf16x8*)&Es[wm * 32 + i * 16 + l16][ks * 32 + quad * 8];
    #pragma unroll
    for (int j = 0; j < 4; j++)
      bfr[j] = *(const bf16x8*)&Bs[wn * 64 + j * 16 + l16][ks * 32 + quad * 8];
    #pragma unroll
    for (int i = 0; i < 2; i++)
      #pragma unroll
      for (int j = 0; j < 4; j++)
        acc[i][j] = __builtin_amdgcn_mfma_f32_16x16x32_bf16(af[i], bfr[j], acc[i][j], 0, 0, 0);
  }
  // H1 = relu(acc + b1) -> LDS (bf16, A-operand layout for layer 2)
  #pragma unroll
  for (int i = 0; i < 2; i++)
    #pragma unroll
    for (int j = 0; j < 4; j++) {
      int col = wn * 64 + j * 16 + l16;
      float bv = b1[c * 128 + col];
      #pragma unroll
      for (int r = 0; r < 4; r++) {
        int row = wm * 32 + i * 16 + quad * 4 + r;
        H1s[row][col] = f2b(fmaxf(acc[i][j][r] + bv, 0.f));
      }
    }
  __syncthreads();
  // stage W2[c]
  #pragma unroll
  for (int p = 0; p < 8; p++) {
    int idx = p * 256 + tid;
    int r = idx >> 4, c8 = (idx & 15) * 8;
    stage8(W2 + ((long)(c * 128 + r)) * 128 + c8, &Bs[r][c8]);
  }
  __syncthreads();
  #pragma unroll
  for (int i = 0; i < 2; i++)
    #pragma unroll
    for (int j = 0; j < 4; j++) acc[i][j] = zero4;
  #pragma unroll
  for (int ks = 0; ks < 4; ks++) {
    bf16x8 af[2], bfr[4];
    #pragma unroll
    for (int i = 0; i < 2; i++)
      af[i] = *(const bf16x8*)&H1s[wm * 32 + i * 16 + l16][ks * 32 + quad * 8];
    #pragma unroll
    for (int j = 0; j < 4; j++)
      bfr[j] = *(const bf16x8*)&Bs[wn * 64 + j * 16 + l16][ks * 32 + quad * 8];
    #pragma unroll
    for (int i = 0; i < 2; i++)
      #pragma unroll
      for (int j = 0; j < 4; j++)
        acc[i][j] = __builtin_amdgcn_mfma_f32_16x16x32_bf16(af[i], bfr[j], acc[i][j], 0, 0, 0);
  }
  // X += acc + b2
  #pragma unroll
  for (int i = 0; i < 2; i++)
    #pragma unroll
    for (int j = 0; j < 4; j++) {
      int col = wn * 64 + j * 16 + l16;
      float bv = b2[c * 128 + col];
      #pragma unroll
      for (int r = 0; r < 4; r++) {
        long row = r0 + wm * 32 + i * 16 + quad * 4 + r;
        X[row * 256 + c * 128 + col] += acc[i][j][r] + bv;
      }
    }
}

// ---------- split-K skinny GEMM (M rows <= 16) ----------
template<int M_>
__global__ __launch_bounds__(256) void skinny_gemm(
    const float* __restrict__ A, int lda,
    const float* __restrict__ W, int K,
    float* __restrict__ P, int N, int slice)
{
  __shared__ float Asl[M_ * 192];
  __shared__ float Pr[4][M_][64];
  int tid = threadIdx.x;
  int ks = blockIdx.y;
  int kbeg = ks * slice;
  int kend = min(K, kbeg + slice);
  int sl = kend - kbeg;
  for (int idx = tid; idx < M_ * sl; idx += 256) {
    int m = idx / sl, k = idx - m * sl;
    Asl[m * sl + k] = A[(long)m * lda + kbeg + k];
  }
  __syncthreads();
  int n = blockIdx.x * 64 + (tid & 63);
  int sub = tid >> 6;
  int sl4 = (sl + 3) >> 2;
  int k0 = kbeg + sub * sl4;
  int k1 = min(kend, k0 + sl4);
  float acc[M_];
  #pragma unroll
  for (int m = 0; m < M_; m++) acc[m] = 0.f;
  if (n < N) {
    const float* wr = W + (long)n * K;
    for (int k = k0; k < k1; k++) {
      float w = wr[k];
      int kl = k - kbeg;
      #pragma unroll
      for (int m = 0; m < M_; m++) acc[m] += w * Asl[m * sl + kl];
    }
  }
  #pragma unroll
  for (int m = 0; m < M_; m++) Pr[sub][m][tid & 63] = acc[m];
  __syncthreads();
  if (sub == 0 && n < N) {
    #pragma unroll
    for (int m = 0; m < M_; m++) {
      float s = Pr[0][m][tid] + Pr[1][m][tid] + Pr[2][m][tid] + Pr[3][m][tid];
      P[((long)(ks * M_ + m)) * N + n] = s;
    }
  }
}

__global__ __launch_bounds__(256) void skinny_epi(
    const float* __restrict__ P, const float* __restrict__ bias,
    float* __restrict__ out, int M, int N, int KS, int relu)
{
  int idx = blockIdx.x * 256 + threadIdx.x;
  if (idx >= M * N) return;
  int m = idx / N, n = idx - m * N;
  float s = bias[n];
  for (int ks = 0; ks < KS; ks++) s += P[((long)(ks * M + m)) * N + n];
  if (relu) s = fmaxf(s, 0.f);
  out[(long)m * N + n] = s;
}

template<int M_>
static void sgemm(hipStream_t st, const float* A, int lda, const float* W, int K,
                  const float* bias, float* out, float* P, int N, int KS, int relu) {
  int slice = (K + KS - 1) / KS;
  dim3 grid((N + 63) / 64, KS);
  skinny_gemm<M_><<<grid, 256, 0, st>>>(A, lda, W, K, P, N, slice);
  skinny_epi<<<(M_ * N + 255) / 256, 256, 0, st>>>(P, bias, out, M_, N, KS, relu);
}

// ---------- bag stats ----------
__global__ __launch_bounds__(256) void bag_stats(const float* __restrict__ cp, float* __restrict__ PN) {
  int b = blockIdx.x, tid = threadIdx.x;
  __shared__ float red[256];
  for (int c = 0; c < 2; c++) {
    float s = 0.f;
    for (int n = tid; n < 1024; n += 256) s += cp[((b << 10) + n) * 2 + c];
    float mean = blk_sum256(s, red) * (1.f / 1024.f);
    s = 0.f;
    for (int n = tid; n < 1024; n += 256) { float d = cp[((b << 10) + n) * 2 + c] - mean; s += d * d; }
    float var = blk_sum256(s, red) * (1.f / 1024.f);
    float inv = 1.f / (sqrtf(var) + 1e-8f);
    for (int n = tid; n < 1024; n += 256)
      PN[((b << 10) + n) * 2 + c] = (cp[((b << 10) + n) * 2 + c] - mean) * inv;
  }
}

// ---------- kNN: parallel stable top-8 ----------
__global__ __launch_bounds__(256) void knn_kernel(const float* __restrict__ PN, int* __restrict__ NBR) {
  int blk = blockIdx.x;
  int b = blk >> 5, tg = blk & 31;
  int tid = threadIdx.x;
  int tl = tid >> 3, chunk = tid & 7;
  __shared__ float px[1024], py[1024];
  __shared__ float candD[32][64];
  __shared__ int   candI[32][64];
  for (int i = tid; i < 1024; i += 256) {
    px[i] = PN[((b << 10) + i) * 2 + 0];
    py[i] = PN[((b << 10) + i) * 2 + 1];
  }
  __syncthreads();
  int t = tg * 32 + tl;
  float tx = px[t], ty = py[t];
  float d8[8]; int i8[8];
  #pragma unroll
  for (int i = 0; i < 8; i++) { d8[i] = 3.4e38f; i8[i] = 0x7fffffff; }
  int s0 = chunk * 128;
  for (int s = s0; s < s0 + 128; s++) {
    float dx = __fadd_rn(px[s], -tx), dy = __fadd_rn(py[s], -ty);
    float d2 = __fadd_rn(__fadd_rn(__fmul_rn(dx, dx), __fmul_rn(dy, dy)), 1e-12f);
    float d = sqrtf(d2);
    if (d < d8[7]) {
      d8[7] = d; i8[7] = s;
      #pragma unroll
      for (int p = 7; p > 0; p--) {
        if (d8[p] < d8[p - 1]) {
          float td = d8[p]; d8[p] = d8[p - 1]; d8[p - 1] = td;
          int ti = i8[p]; i8[p] = i8[p - 1]; i8[p - 1] = ti;
        }
      }
    }
  }
  #pragma unroll
  for (int i = 0; i < 8; i++) { candD[tl][chunk * 8 + i] = d8[i]; candI[tl][chunk * 8 + i] = i8[i]; }
  __syncthreads();
  if (chunk == 0) {
    float D[8]; int I[8];
    #pragma unroll
    for (int i = 0; i < 8; i++) { D[i] = candD[tl][i]; I[i] = candI[tl][i]; }
    for (int c = 1; c < 8; c++) {
      for (int j = 0; j < 8; j++) {
        float d = candD[tl][c * 8 + j]; int idx = candI[tl][c * 8 + j];
        bool better = (d < D[7]) || (d == D[7] && idx < I[7]);
        if (!better) break;
        D[7] = d; I[7] = idx;
        #pragma unroll
        for (int p = 7; p > 0; p--) {
          bool sw = (D[p] < D[p - 1]) || (D[p] == D[p - 1] && I[p] < I[p - 1]);
          if (sw) {
            float td = D[p]; D[p] = D[p - 1]; D[p - 1] = td;
            int ti = I[p]; I[p] = I[p - 1]; I[p - 1] = ti;
          }
        }
      }
    }
    #pragma unroll
    for (int i = 0; i < 8; i++) NBR[((long)((b << 10) + t)) * 8 + i] = I[i];
  }
}

// ---------- GAT scores ----------
__global__ __launch_bounds__(256) void gat_scores(const float* __restrict__ Hh,
    const float* __restrict__ asrcW, const float* __restrict__ adstW,
    float* __restrict__ ASRC, float* __restrict__ ADST)
{
  int row = blockIdx.x, tid = threadIdx.x;
  __shared__ float red[256];
  float v = Hh[(long)row * 256 + tid];
  float s1 = v * asrcW[tid];
  float s2 = v * adstW[tid];
  red[tid] = s1; __syncthreads();
  for (int off = 64; off > 0; off >>= 1) { if ((tid & 127) < off) red[tid] += red[tid + off]; __syncthreads(); }
  if ((tid & 127) == 0) ASRC[row * 2 + (tid >> 7)] = red[tid];
  __syncthreads();
  red[tid] = s2; __syncthreads();
  for (int off = 64; off > 0; off >>= 1) { if ((tid & 127) < off) red[tid] += red[tid + off]; __syncthreads(); }
  if ((tid & 127) == 0) ADST[row * 2 + (tid >> 7)] = red[tid];
}

// ---------- GAT aggregate + residual + LN ----------
__global__ __launch_bounds__(256) void gat_aggr_ln(
    const float* __restrict__ Hh, const float* __restrict__ ASRC, const float* __restrict__ ADST,
    const int* __restrict__ NBR, const float* __restrict__ gbias,
    const float* __restrict__ lng, const float* __restrict__ lnb,
    float* __restrict__ X, ushort* __restrict__ Xb)
{
  int row = blockIdx.x, tid = threadIdx.x;
  int b = row >> 10;
  __shared__ int nb[8];
  __shared__ float w[2][8];
  __shared__ float red[256];
  if (tid < 8) {
    int v = NBR[(long)row * 8 + tid];
    nb[tid] = min(max(v, 0), 1023);
  }
  __syncthreads();
  if (tid < 16) {
    int i = tid & 7, h = tid >> 3;
    float e = ADST[row * 2 + h] + ASRC[((b << 10) + nb[i]) * 2 + h];
    w[h][i] = (e >= 0.f) ? e : 0.2f * e;
  }
  __syncthreads();
  if (tid < 2) {
    float m = -3.4e38f;
    for (int i = 0; i < 8; i++) m = fmaxf(m, w[tid][i]);
    float s = 0.f;
    for (int i = 0; i < 8; i++) { float e = expf(w[tid][i] - m); w[tid][i] = e; s += e; }
    float inv = 1.f / s;
    for (int i = 0; i < 8; i++) w[tid][i] *= inv;
  }
  __syncthreads();
  int h = tid >> 7, c = tid & 127;
  float acc = 0.f;
  #pragma unroll
  for (int i = 0; i < 8; i++)
    acc += w[h][i] * Hh[((long)((b << 10) + nb[i])) * 256 + h * 128 + c];
  float v = acc + gbias[tid] + X[(long)row * 256 + tid];
  float mean = blk_sum256(v, red) * (1.f / 256.f);
  float dv = v - mean;
  float var = blk_sum256(dv * dv, red) * (1.f / 256.f);
  float o = dv * rsqrtf(var + 1e-5f) * lng[tid] + lnb[tid];
  X[(long)row * 256 + tid] = o;
  Xb[(long)row * 256 + tid] = f2b(o);
}

// ---------- residual + LayerNorm, D=256, one wave per row ----------
__global__ __launch_bounds__(256) void add_ln4(const float* __restrict__ res,
    const float* __restrict__ Yv, const float* __restrict__ g, const float* __restrict__ b,
    float* __restrict__ out, ushort* __restrict__ outb)
{
  int wave = threadIdx.x >> 6, lane = threadIdx.x & 63;
  long row = blockIdx.x * 4 + wave;
  const float* yr = Yv + row * 256;
  const float* rr = res ? res + row * 256 : nullptr;
  float v[4];
  float s = 0.f;
  #pragma unroll
  for (int i = 0; i < 4; i++) {
    int d = lane + i * 64;
    float x = yr[d];
    if (rr) x += rr[d];
    v[i] = x; s += x;
  }
  #pragma unroll
  for (int off = 32; off > 0; off >>= 1) s += __shfl_xor(s, off);
  float mean = s * (1.f / 256.f);
  float vs = 0.f;
  #pragma unroll
  for (int i = 0; i < 4; i++) { float dv = v[i] - mean; vs += dv * dv; }
  #pragma unroll
  for (int off = 32; off > 0; off >>= 1) vs += __shfl_xor(vs, off);
  float rstd = rsqrtf(vs * (1.f / 256.f) + 1e-5f);
  #pragma unroll
  for (int i = 0; i < 4; i++) {
    int d = lane + i * 64;
    float o = (v[i] - mean) * rstd * g[d] + b[d];
    out[row * 256 + d] = o;
    if (outb) outb[row * 256 + d] = f2b(o);
  }
}

// ---------- LayerNorm (D=1024, head rows) ----------
__global__ __launch_bounds__(256) void add_ln_big(const float* __restrict__ Yv,
    const float* __restrict__ g, const float* __restrict__ b,
    float* __restrict__ out)
{
  int row = blockIdx.x, tid = threadIdx.x;
  __shared__ float red[256];
  float vals[4];
  float s = 0.f;
  #pragma unroll
  for (int i = 0; i < 4; i++) {
    int d = tid + (i << 8);
    float v = Yv[(long)row * 1024 + d];
    vals[i] = v; s += v;
  }
  float mean = blk_sum256(s, red) * (1.f / 1024.f);
  s = 0.f;
  #pragma unroll
  for (int i = 0; i < 4; i++) { float dv = vals[i] - mean; s += dv * dv; }
  float var = blk_sum256(s, red) * (1.f / 1024.f);
  float rstd = rsqrtf(var + 1e-5f);
  #pragma unroll
  for (int i = 0; i < 4; i++) {
    int d = tid + (i << 8);
    out[(long)row * 1024 + d] = (vals[i] - mean) * rstd * g[d] + b[d];
  }
}

// ---------- MFMA flash attention ----------
__global__ __launch_bounds__(256) void flash_mfma(const ushort* __restrict__ QKV,
                                                  const ushort* __restrict__ VT,
                                                  ushort* __restrict__ O)
{
  const float scale = 0.08838834764831845f;
  int blk = blockIdx.x;
  int qt = blk & 15, bh = blk >> 4;
  int b = bh >> 1, h = bh & 1;
  const ushort* qkg = QKV + (long)b * 1024 * 768 + h * 128;
  const ushort* vtg = VT + ((long)bh << 17);

  __shared__ ushort Qs[64][136];
  __shared__ ushort Ks[64][136];
  __shared__ ushort Vt[128][72];
  __shared__ ushort Ps[4][16][72];

  int tid = threadIdx.x;
  int wave = tid >> 6, lane = tid & 63;
  int quad = lane >> 4, l16 = lane & 15;

  #pragma unroll
  for (int p = 0; p < 4; p++) {
    int idx = p * 256 + tid;
    int r = idx >> 4, c8 = (idx & 15) * 8;
    *(uint4*)&Qs[r][c8] = *(const uint4*)(qkg + (long)(qt * 64 + r) * 768 + c8);
  }
  __syncthreads();
  bf16x8 af[4];
  #pragma unroll
  for (int ks = 0; ks < 4; ks++)
    af[ks] = *(const bf16x8*)&Qs[wave * 16 + l16][ks * 32 + quad * 8];

  f32x4 Oacc[8];
  f32x4 zero4 = {0.f, 0.f, 0.f, 0.f};
  #pragma unroll
  for (int j = 0; j < 8; j++) Oacc[j] = zero4;
  float mr[4], lr[4];
  #pragma unroll
  for (int r = 0; r < 4; r++) { mr[r] = -3.4e38f; lr[r] = 0.f; }

  for (int kt = 0; kt < 16; kt++) {
    __syncthreads();
    #pragma unroll
    for (int p = 0; p < 4; p++) {
      int idx = p * 256 + tid;
      int r = idx >> 4, c8 = (idx & 15) * 8;
      *(uint4*)&Ks[r][c8] = *(const uint4*)(qkg + (long)(kt * 64 + r) * 768 + 256 + c8);
      int c = idx >> 3, k8 = (idx & 7) * 8;
      *(uint4*)&Vt[c][k8] = *(const uint4*)(vtg + ((long)c << 10) + kt * 64 + k8);
    }
    __syncthreads();
    f32x4 acc[4];
    #pragma unroll
    for (int j = 0; j < 4; j++) acc[j] = zero4;
    #pragma unroll
    for (int ks = 0; ks < 4; ks++) {
      #pragma unroll
      for (int j = 0; j < 4; j++) {
        bf16x8 kb = *(const bf16x8*)&Ks[j * 16 + l16][ks * 32 + quad * 8];
        acc[j] = __builtin_amdgcn_mfma_f32_16x16x32_bf16(af[ks], kb, acc[j], 0, 0, 0);
      }
    }
    float sv[4][4], tmax[4];
    #pragma unroll
    for (int r = 0; r < 4; r++) tmax[r] = -3.4e38f;
    #pragma unroll
    for (int j = 0; j < 4; j++)
      #pragma unroll
      for (int r = 0; r < 4; r++) {
        float x = acc[j][r] * scale;
        sv[j][r] = x;
        tmax[r] = fmaxf(tmax[r], x);
      }
    #pragma unroll
    for (int off = 1; off < 16; off <<= 1)
      #pragma unroll
      for (int r = 0; r < 4; r++) tmax[r] = fmaxf(tmax[r], __shfl_xor(tmax[r], off));
    float alpha[4], rsum[4];
    #pragma unroll
    for (int r = 0; r < 4; r++) {
      float mn = fmaxf(mr[r], tmax[r]);
      alpha[r] = expf(mr[r] - mn);
      mr[r] = mn;
      rsum[r] = 0.f;
    }
    #pragma unroll
    for (int j = 0; j < 4; j++)
      #pragma unroll
      for (int r = 0; r < 4; r++) {
        float p = expf(sv[j][r] - mr[r]);
        sv[j][r] = p;
        rsum[r] += p;
      }
    #pragma unroll
    for (int off = 1; off < 16; off <<= 1)
      #pragma unroll
      for (int r = 0; r < 4; r++) rsum[r] += __shfl_xor(rsum[r], off);
    #pragma unroll
    for (int r = 0; r < 4; r++) lr[r] = lr[r] * alpha[r] + rsum[r];
    #pragma unroll
    for (int j = 0; j < 4; j++)
      #pragma unroll
      for (int r = 0; r < 4; r++)
        Ps[wave][quad * 4 + r][j * 16 + l16] = f2b(sv[j][r]);
    #pragma unroll
    for (int jj = 0; jj < 8; jj++)
      #pragma unroll
      for (int r = 0; r < 4; r++) Oacc[jj][r] *= alpha[r];
    __syncthreads();
    #pragma unroll
    for (int s = 0; s < 2; s++) {
      bf16x8 pa = *(const bf16x8*)&Ps[wave][l16][s * 32 + quad * 8];
      #pragma unroll
      for (int jj = 0; jj < 8; jj++) {
        bf16x8 vb = *(const bf16x8*)&Vt[jj * 16 + l16][s * 32 + quad * 8];
        Oacc[jj] = __builtin_amdgcn_mfma_f32_16x16x32_bf16(pa, vb, Oacc[jj], 0, 0, 0);
      }
    }
  }
  long row0 = (long)b * 1024 + qt * 64 + wave * 16 + quad * 4;
  #pragma unroll
  for (int jj = 0; jj < 8; jj++) {
    int col = h * 128 + jj * 16 + l16;
    #pragma unroll
    for (int r = 0; r < 4; r++)
      O[(row0 + r) * 256 + col] = f2b(Oacc[jj][r] / lr[r]);
  }
}

// ---------- split-K pooling attention ----------
__global__ __launch_bounds__(128) void pool_split(
    const float* __restrict__ qe, const float* __restrict__ pinW, const float* __restrict__ pinB,
    const float* __restrict__ srand, const ushort* __restrict__ KV,
    float* __restrict__ PM, float* __restrict__ PL, float* __restrict__ PO)
{
  int cid = blockIdx.x;
  int id = blockIdx.y;
  int h = id & 1, nq = (id >> 1) & 3, b = id >> 3;
  int tid = threadIdx.x;
  __shared__ float qs[128];
  __shared__ float eg[128];
  __shared__ float red[128];
  {
    float a = pinB[h * 128 + tid];
    const float* wr = pinW + ((long)(h * 128 + tid)) * 256;
    const float* qr = qe + nq * 256;
    for (int i = 0; i < 256; i++) a += qr[i] * wr[i];
    qs[tid] = a;
  }
  __syncthreads();
  const float scale = 0.08838834764831845f;
  int s = cid * 128 + tid;
  float d = 0.f;
  {
    const ushort* kr = KV + ((long)((b << 10) + s)) * 512 + h * 128;
    #pragma unroll
    for (int c8 = 0; c8 < 128; c8 += 8) {
      uint4 kv4 = *(const uint4*)(kr + c8);
      const ushort* kp = (const ushort*)&kv4;
      #pragma unroll
      for (int j = 0; j < 8; j++) d += qs[c8 + j] * b2f(kp[j]);
    }
  }
  float lg = d * scale + ((srand[nq * 1024 + s] < 0.3f) ? 0.f : -1e9f);
  red[tid] = lg; __syncthreads();
  for (int off = 64; off > 0; off >>= 1) { if (tid < off) red[tid] = fmaxf(red[tid], red[tid + off]); __syncthreads(); }
  float m = red[0]; __syncthreads();
  float e = expf(lg - m);
  eg[tid] = e;
  red[tid] = e; __syncthreads();
  for (int off = 64; off > 0; off >>= 1) { if (tid < off) red[tid] += red[tid + off]; __syncthreads(); }
  float l = red[0];
  __syncthreads();
  float o = 0.f;
  const ushort* vbase = KV + ((long)((b << 10) + cid * 128)) * 512 + 256 + h * 128 + tid;
  for (int ss = 0; ss < 128; ss++)
    o += eg[ss] * b2f(vbase[(long)ss * 512]);
  int part = id * 8 + cid;
  PO[(long)part * 128 + tid] = o;
  if (tid == 0) { PM[part] = m; PL[part] = l; }
}

__global__ __launch_bounds__(128) void pool_merge(
    const float* __restrict__ PM, const float* __restrict__ PL, const float* __restrict__ PO,
    float* __restrict__ ATTP)
{
  int id = blockIdx.x;
  int h = id & 1, nq = (id >> 1) & 3, b = id >> 3;
  int tid = threadIdx.x;
  float m = -3.4e38f;
  #pragma unroll
  for (int c = 0; c < 8; c++) m = fmaxf(m, PM[id * 8 + c]);
  float l = 0.f, o = 0.f;
  #pragma unroll
  for (int c = 0; c < 8; c++) {
    float w = expf(PM[id * 8 + c] - m);
    l += PL[id * 8 + c] * w;
    o += PO[(long)(id * 8 + c) * 128 + tid] * w;
  }
  ATTP[(b * 4 + nq) * 256 + h * 128 + tid] = o / l;
}

// ---------- combined = [mean over N | pooled_att], 1024 threads ----------
__global__ __launch_bounds__(1024) void combined_kernel(const float* __restrict__ X,
    const float* __restrict__ ATTO, float* __restrict__ CMB)
{
  int b = blockIdx.x, tid = threadIdx.x;
  int d = tid & 255, ch = tid >> 8;
  __shared__ float part[4][256];
  float s = 0.f;
  int n0 = ch * 256;
  for (int n = n0; n < n0 + 256; n++) s += X[((long)((b << 10) + n)) * 256 + d];
  part[ch][d] = s;
  __syncthreads();
  if (ch == 0) {
    float tot = part[0][d] + part[1][d] + part[2][d] + part[3][d];
    CMB[b * 1280 + d] = tot * (1.f / 1024.f);
    #pragma unroll
    for (int q = 0; q < 4; q++)
      CMB[b * 1280 + 256 + q * 256 + d] = ATTO[(b * 4 + q) * 256 + d];
  }
}

__global__ void store_out(const float* __restrict__ src, float* __restrict__ dst, int n) {
  int i = blockIdx.x * blockDim.x + threadIdx.x;
  if (i < n) dst[i] = src[i];
}
__global__ void fill_out_zero(float* __restrict__ dst, int n) {
  int i = blockIdx.x * blockDim.x + threadIdx.x;
  if (i < n) dst[i] = 0.f;
}

extern "C" void kernel_launch(void* const* d_in, const int* in_sizes, int n_in,
                              void* d_out, int out_size, void* d_ws, size_t ws_size,
                              hipStream_t stream)
{
  const float* inp      = (const float*)d_in[0];
  const float* cellp    = (const float*)d_in[1];
  const float* srand    = (const float*)d_in[2];
  const float* emb_W    = (const float*)d_in[3];
  const float* emb_b    = (const float*)d_in[4];
  const float* pe_tab   = (const float*)d_in[5];
  const float* pe_W1    = (const float*)d_in[6];
  const float* pe_b1    = (const float*)d_in[7];
  const float* pe_W2    = (const float*)d_in[8];
  const float* pe_b2    = (const float*)d_in[9];
  const float* gat_W    = (const float*)d_in[10];
  const float* gat_asrc = (const float*)d_in[11];
  const float* gat_adst = (const float*)d_in[12];
  const float* gat_b    = (const float*)d_in[13];
  const float* ln_g     = (const float*)d_in[14];
  const float* ln_b     = (const float*)d_in[15];
  const float* qkv_W    = (const float*)d_in[16];
  const float* qkv_b    = (const float*)d_in[17];
  const float* out_W    = (const float*)d_in[18];
  const float* out_b    = (const float*)d_in[19];
  const float* ff1_W    = (const float*)d_in[20];
  const float* ff1_b    = (const float*)d_in[21];
  const float* ff2_W    = (const float*)d_in[22];
  const float* ff2_b    = (const float*)d_in[23];
  const float* ln1_g    = (const float*)d_in[24];
  const float* ln1_b    = (const float*)d_in[25];
  const float* ln2_g    = (const float*)d_in[26];
  const float* ln2_b    = (const float*)d_in[27];
  const float* q_emb    = (const float*)d_in[28];
  const float* pin_W    = (const float*)d_in[29];
  const float* pin_b    = (const float*)d_in[30];
  const float* pout_W   = (const float*)d_in[31];
  const float* pout_b   = (const float*)d_in[32];
  const float* m1_W     = (const float*)d_in[33];
  const float* m1_b     = (const float*)d_in[34];
  const float* mln1_g   = (const float*)d_in[35];
  const float* mln1_b   = (const float*)d_in[36];
  const float* m2_W     = (const float*)d_in[37];
  const float* m2_b     = (const float*)d_in[38];
  const float* mln2_g   = (const float*)d_in[39];
  const float* mln2_b   = (const float*)d_in[40];
  const float* m3_W     = (const float*)d_in[41];
  const float* m3_b     = (const float*)d_in[42];
  const float* c1_W     = (const float*)d_in[43];
  const float* c1_b     = (const float*)d_in[44];
  const float* c2_W     = (const float*)d_in[45];
  const float* c2_b     = (const float*)d_in[46];
  const float* c3_W     = (const float*)d_in[47];
  const float* c3_b     = (const float*)d_in[48];
  const float* c4_W     = (const float*)d_in[49];
  const float* c4_b     = (const float*)d_in[50];
  (void)in_sizes; (void)n_in;

  // ---- workspace (bytes, 256-aligned; ~20.5 MB) ----
  char* base = (char*)d_ws;
  size_t off = 0;
  auto alloc = [&](size_t bytes) { void* p = base + off; off += (bytes + 255) & ~size_t(255); return p; };
  float* PN    = (float*)alloc(32768);
  float* AS    = (float*)alloc(32768);
  float* AD    = (float*)alloc(32768);
  float* ATTP  = (float*)alloc(16384);
  float* ATTO  = (float*)alloc(16384);
  float* CMB   = (float*)alloc(20480);
  float* Ha    = (float*)alloc(16384);
  float* Hb    = (float*)alloc(16384);
  float* Hc    = (float*)alloc(16640);
  float* Hd    = (float*)alloc(8192);
  float* He    = (float*)alloc(4096);
  float* Hf    = (float*)alloc(512);
  float* Pk    = (float*)alloc(262144);
  float* PPM   = (float*)alloc(1024);
  float* PPL   = (float*)alloc(1024);
  float* PPO   = (float*)alloc(131072);
  int*   NBR   = (int*)alloc(131072);
  float* X     = (float*)alloc(4194304);
  ushort* Xb   = (ushort*)alloc(2097152);
  char*  Rq    = (char*)alloc(6291456);
  char*  Rf    = (char*)alloc(4194304);
  ushort* QKVb = (ushort*)Rq;
  float*  F2   = (float*)Rq;
  ushort* KVb  = (ushort*)Rq;
  ushort* Ob   = (ushort*)Rf;
  ushort* VT   = (ushort*)(Rf + 2097152);
  ushort* FFBb = (ushort*)Rf;
  float*  F1   = (float*)alloc(4194304);
  if (ws_size < off) { fill_out_zero<<<1, 128, 0, stream>>>((float*)d_out, out_size); return; }

  // ---- graph construction ----
  bag_stats<<<4, 256, 0, stream>>>(cellp, PN);
  knn_kernel<<<128, 256, 0, stream>>>(PN, NBR);

  // ---- embedding + positional MLP (MFMA) ----
  mgemm<float>(stream, inp, 512, emb_W, 512, emb_b, X, 256, 4096, 256, 512, 0);
  pos_mlp<<<dim3(64, 2), 256, 0, stream>>>(cellp, pe_tab, pe_W1, pe_b1, pe_W2, pe_b2, X);
  cvt_f2b<<<1024, 256, 0, stream>>>(X, Xb, 4096 * 256);

  // ---- 2x GAT ----
  for (int l = 0; l < 2; l++) {
    mgemm<float>(stream, Xb, 256, gat_W + l * 65536, 256, (const float*)nullptr, F1, 256,
                 4096, 256, 256, 0);
    gat_scores<<<4096, 256, 0, stream>>>(F1, gat_asrc + l * 256, gat_adst + l * 256, AS, AD);
    gat_aggr_ln<<<4096, 256, 0, stream>>>(F1, AS, AD, NBR, gat_b + l * 256, ln_g, ln_b, X, Xb);
  }

  // ---- 2x Transformer encoder layer ----
  for (int l = 0; l < 2; l++) {
    mgemm_vt(stream, Xb, 256, qkv_W + (long)l * 768 * 256, 256, qkv_b + l * 768,
             QKVb, 768, 4096, 768, 256, VT);
    flash_mfma<<<256, 256, 0, stream>>>(QKVb, VT, Ob);
    mgemm<float>(stream, Ob, 256, out_W + l * 65536, 256, out_b + l * 256, F2, 256,
                 4096, 256, 256, 0);
    add_ln4<<<1024, 256, 0, stream>>>(X, F2, ln1_g + l * 256, ln1_b + l * 256, X, Xb);
    for (int ch = 0; ch < 2; ch++) {
      mgemm<ushort>(stream, Xb + (long)ch * 2048 * 256, 256, ff1_W + l * 262144, 256,
                    ff1_b + l * 1024, FFBb, 1024, 2048, 1024, 256, 1);
      mgemm<float>(stream, FFBb, 1024, ff2_W + l * 262144, 1024, ff2_b + l * 256,
                   F2 + (long)ch * 2048 * 256, 256, 2048, 256, 1024, 0);
    }
    add_ln4<<<1024, 256, 0, stream>>>(X, F2, ln2_g + l * 256, ln2_b + l * 256, X, Xb);
  }

  // ---- final LN ----
  add_ln4<<<1024, 256, 0, stream>>>((const float*)nullptr, X, ln_g, ln_b, X, Xb);

  // ---- pooling (split-K flash-decode style) ----
  mgemm<ushort>(stream, Xb, 256, pin_W + 65536, 256, pin_b + 256, KVb, 512, 4096, 512, 256, 0);
  pool_split<<<dim3(8, 32), 128, 0, stream>>>(q_emb, pin_W, pin_b, srand, KVb, PPM, PPL, PPO);
  pool_merge<<<32, 128, 0, stream>>>(PPM, PPL, PPO, ATTP);
  sgemm<16>(stream, ATTP, 256, pout_W, 256, pout_b, ATTO, Pk, 256, 2, 0);
  combined_kernel<<<4, 1024, 0, stream>>>(X, ATTO, CMB);

  // ---- MLP head (fp32, split-K skinny GEMMs) ----
  sgemm<4>(stream, CMB, 1280, m1_W, 1280, m1_b, Ha, Pk, 1024, 8, 1);
  add_ln_big<<<4, 256, 0, stream>>>(Ha, mln1_g, mln1_b, Ha);
  sgemm<4>(stream, Ha, 1024, m2_W, 1024, m2_b, Hb, Pk, 1024, 8, 1);
  add_ln_big<<<4, 256, 0, stream>>>(Hb, mln2_g, mln2_b, Hb);
  sgemm<4>(stream, Hb, 1024, m3_W, 1024, m3_b, Ha, Pk, 1024, 8, 0);
  sgemm<4>(stream, Ha, 1024, c1_W, 1024, c1_b, Hc, Pk, 1032, 8, 1);
  sgemm<4>(stream, Hc, 1032, c2_W, 1032, c2_b, Hd, Pk, 512, 8, 1);
  sgemm<4>(stream, Hd, 512, c3_W, 512, c3_b, He, Pk, 256, 4, 1);
  sgemm<4>(stream, He, 256, c4_W, 256, c4_b, Hf, Pk, 24, 2, 0);
  store_out<<<1, 128, 0, stream>>>(Hf, (float*)d_out, out_size);
}

// Round 10
// 735.967 us; speedup vs baseline: 5.4130x; 1.0921x over previous
//
#include <hip/hip_runtime.h>
#include <hip/hip_bf16.h>

// MILCellModel forward on MI355X. Round 10: parallel column-mean for the
// combined vector (R9 profile: combined_kernel 71us at 4 blocks / 0.13%
// VALUBusy -- serial over 256 rows). Split into 64-block partial sums + merge.
// B=4 N=1024 E=512 D=256 H=2 C=128 FF=1024 NQ=4 NCLS=24

typedef __bf16 bf16x8 __attribute__((ext_vector_type(8)));
typedef float  f32x4  __attribute__((ext_vector_type(4)));

__device__ __forceinline__ ushort f2b(float f) {
  __hip_bfloat16 h = __float2bfloat16(f);
  return *(ushort*)&h;
}
__device__ __forceinline__ float b2f(ushort u) {
  union { unsigned i; float f; } v; v.i = ((unsigned)u) << 16; return v.f;
}

// ---------- block reductions (256 threads) ----------
__device__ __forceinline__ float blk_sum256(float v, float* red) {
  int t = threadIdx.x;
  red[t] = v; __syncthreads();
  #pragma unroll
  for (int off = 128; off > 0; off >>= 1) {
    if (t < off) red[t] += red[t + off];
    __syncthreads();
  }
  float r = red[0]; __syncthreads();
  return r;
}

// ---------- fp32 -> bf16 convert ----------
__global__ __launch_bounds__(256) void cvt_f2b(const float* __restrict__ src,
                                               ushort* __restrict__ dst, int n) {
  int i = (blockIdx.x * 256 + threadIdx.x) * 4;
  if (i >= n) return;
  float4 v = *(const float4*)(src + i);
  ushort4 o;
  o.x = f2b(v.x); o.y = f2b(v.y); o.z = f2b(v.z); o.w = f2b(v.w);
  *(ushort4*)(dst + i) = o;
}

// ---------- staging helpers: 8 contiguous elements -> bf16 LDS ----------
__device__ __forceinline__ void stage8(const ushort* __restrict__ src, ushort* dst) {
  *(uint4*)dst = *(const uint4*)src;
}
__device__ __forceinline__ void stage8(const float* __restrict__ src, ushort* dst) {
  float4 a = ((const float4*)src)[0];
  float4 b = ((const float4*)src)[1];
  ushort4 o0, o1;
  o0.x = f2b(a.x); o0.y = f2b(a.y); o0.z = f2b(a.z); o0.w = f2b(a.w);
  o1.x = f2b(b.x); o1.y = f2b(b.y); o1.z = f2b(b.z); o1.w = f2b(b.w);
  *(ushort4*)dst = o0;
  *(ushort4*)(dst + 4) = o1;
}

// ---------- bf16 MFMA GEMM: C[M,N] = act(A[M,K] @ B^T + bias) ----------
template<typename CT, typename AT, typename WT, bool VSPLIT>
__global__ __launch_bounds__(256) void mfma_gemm(
    const AT* __restrict__ A, int lda,
    const WT* __restrict__ Bw, int ldb,
    const float* __restrict__ bias,
    CT* __restrict__ C, int ldc, int K, int relu,
    ushort* __restrict__ VT)
{
  __shared__ ushort As[64][40];
  __shared__ ushort Bs[128][40];
  int tid = threadIdx.x;
  int lane = tid & 63, wave = tid >> 6;
  int wm = wave >> 1, wn = wave & 1;
  int quad = lane >> 4, l16 = lane & 15;
  long mBase = blockIdx.y * 64, nBase = blockIdx.x * 128;

  f32x4 zero4 = {0.f, 0.f, 0.f, 0.f};
  f32x4 acc[2][4];
  #pragma unroll
  for (int i = 0; i < 2; i++)
    #pragma unroll
    for (int j = 0; j < 4; j++) acc[i][j] = zero4;

  for (int k0 = 0; k0 < K; k0 += 32) {
    {
      int r = tid >> 2, sg = (tid & 3) * 8;
      stage8(A + (mBase + r) * lda + k0 + sg, &As[r][sg]);
    }
    #pragma unroll
    for (int p = 0; p < 2; p++) {
      int idx = p * 256 + tid;
      int r = idx >> 2, sg = (idx & 3) * 8;
      stage8(Bw + (nBase + r) * ldb + k0 + sg, &Bs[r][sg]);
    }
    __syncthreads();
    bf16x8 af[2], bfr[4];
    #pragma unroll
    for (int i = 0; i < 2; i++)
      af[i] = *(const bf16x8*)&As[wm * 32 + i * 16 + l16][quad * 8];
    #pragma unroll
    for (int j = 0; j < 4; j++)
      bfr[j] = *(const bf16x8*)&Bs[wn * 64 + j * 16 + l16][quad * 8];
    #pragma unroll
    for (int i = 0; i < 2; i++)
      #pragma unroll
      for (int j = 0; j < 4; j++)
        acc[i][j] = __builtin_amdgcn_mfma_f32_16x16x32_bf16(af[i], bfr[j], acc[i][j], 0, 0, 0);
    __syncthreads();
  }
  #pragma unroll
  for (int i = 0; i < 2; i++) {
    #pragma unroll
    for (int j = 0; j < 4; j++) {
      long col = nBase + wn * 64 + j * 16 + l16;
      float bv = bias ? bias[col] : 0.f;
      long row0 = mBase + wm * 32 + i * 16 + quad * 4;
      if (VSPLIT && col >= 512) {
        int cm = (int)col - 512, hh = cm >> 7, cc = cm & 127;
        long bidx = row0 >> 10, n0 = row0 & 1023;
        ushort4 o;
        o.x = f2b(acc[i][j][0] + bv);
        o.y = f2b(acc[i][j][1] + bv);
        o.z = f2b(acc[i][j][2] + bv);
        o.w = f2b(acc[i][j][3] + bv);
        *(ushort4*)&VT[(((bidx * 2 + hh) * 128 + cc) << 10) + n0] = o;
      } else {
        #pragma unroll
        for (int r = 0; r < 4; r++) {
          float v = acc[i][j][r] + bv;
          if (relu) v = fmaxf(v, 0.f);
          if constexpr (sizeof(CT) == 2) C[(row0 + r) * ldc + col] = f2b(v);
          else                           C[(row0 + r) * ldc + col] = v;
        }
      }
    }
  }
}

template<typename CT, typename AT, typename WT>
static void mgemm(hipStream_t st, const AT* A, int lda, const WT* B, int ldb,
                  const float* bias, CT* C, int ldc, int M, int N, int K, int relu) {
  dim3 grid(N / 128, M / 64);
  mfma_gemm<CT, AT, WT, false><<<grid, 256, 0, st>>>(A, lda, B, ldb, bias, C, ldc, K, relu, nullptr);
}
template<typename AT, typename WT>
static void mgemm_vt(hipStream_t st, const AT* A, int lda, const WT* B, int ldb,
                     const float* bias, ushort* C, int ldc, int M, int N, int K, ushort* VT) {
  dim3 grid(N / 128, M / 64);
  mfma_gemm<ushort, AT, WT, true><<<grid, 256, 0, st>>>(A, lda, B, ldb, bias, C, ldc, K, 0, VT);
}

// ---------- fused pos-embed MLP (MFMA, weights LDS-resident) ----------
__global__ __launch_bounds__(256) void pos_mlp(
    const float* __restrict__ cellp, const float* __restrict__ tab,
    const float* __restrict__ W1, const float* __restrict__ b1,
    const float* __restrict__ W2, const float* __restrict__ b2,
    float* __restrict__ X)
{
  __shared__ ushort Es[64][136];
  __shared__ ushort Bs[128][136];
  __shared__ ushort H1s[64][136];
  int tid = threadIdx.x;
  int lane = tid & 63, wave = tid >> 6;
  int wm = wave >> 1, wn = wave & 1;
  int quad = lane >> 4, l16 = lane & 15;
  int r0 = blockIdx.x * 64, c = blockIdx.y;

  #pragma unroll
  for (int p = 0; p < 4; p++) {
    int idx = p * 256 + tid;
    int r = idx >> 4, c8 = (idx & 15) * 8;
    float pos = cellp[(r0 + r) * 2 + c];
    pos = fminf(fmaxf(pos, 0.f), 1000.f);
    int pi = (int)pos;
    stage8(tab + ((long)(c * 1001 + pi)) * 128 + c8, &Es[r][c8]);
  }
  #pragma unroll
  for (int p = 0; p < 8; p++) {
    int idx = p * 256 + tid;
    int r = idx >> 4, c8 = (idx & 15) * 8;
    stage8(W1 + ((long)(c * 128 + r)) * 128 + c8, &Bs[r][c8]);
  }
  __syncthreads();

  f32x4 zero4 = {0.f, 0.f, 0.f, 0.f};
  f32x4 acc[2][4];
  #pragma unroll
  for (int i = 0; i < 2; i++)
    #pragma unroll
    for (int j = 0; j < 4; j++) acc[i][j] = zero4;
  #pragma unroll
  for (int ks = 0; ks < 4; ks++) {
    bf16x8 af[2], bfr[4];
    #pragma unroll
    for (int i = 0; i < 2; i++)
      af[i] = *(const bf16x8*)&Es[wm * 32 + i * 16 + l16][ks * 32 + quad * 8];
    #pragma unroll
    for (int j = 0; j < 4; j++)
      bfr[j] = *(const bf16x8*)&Bs[wn * 64 + j * 16 + l16][ks * 32 + quad * 8];
    #pragma unroll
    for (int i = 0; i < 2; i++)
      #pragma unroll
      for (int j = 0; j < 4; j++)
        acc[i][j] = __builtin_amdgcn_mfma_f32_16x16x32_bf16(af[i], bfr[j], acc[i][j], 0, 0, 0);
  }
  #pragma unroll
  for (int i = 0; i < 2; i++)
    #pragma unroll
    for (int j = 0; j < 4; j++) {
      int col = wn * 64 + j * 16 + l16;
      float bv = b1[c * 128 + col];
      #pragma unroll
      for (int r = 0; r < 4; r++) {
        int row = wm * 32 + i * 16 + quad * 4 + r;
        H1s[row][col] = f2b(fmaxf(acc[i][j][r] + bv, 0.f));
      }
    }
  __syncthreads();
  #pragma unroll
  for (int p = 0; p < 8; p++) {
    int idx = p * 256 + tid;
    int r = idx >> 4, c8 = (idx & 15) * 8;
    stage8(W2 + ((long)(c * 128 + r)) * 128 + c8, &Bs[r][c8]);
  }
  __syncthreads();
  #pragma unroll
  for (int i = 0; i < 2; i++)
    #pragma unroll
    for (int j = 0; j < 4; j++) acc[i][j] = zero4;
  #pragma unroll
  for (int ks = 0; ks < 4; ks++) {
    bf16x8 af[2], bfr[4];
    #pragma unroll
    for (int i = 0; i < 2; i++)
      af[i] = *(const bf16x8*)&H1s[wm * 32 + i * 16 + l16][ks * 32 + quad * 8];
    #pragma unroll
    for (int j = 0; j < 4; j++)
      bfr[j] = *(const bf16x8*)&Bs[wn * 64 + j * 16 + l16][ks * 32 + quad * 8];
    #pragma unroll
    for (int i = 0; i < 2; i++)
      #pragma unroll
      for (int j = 0; j < 4; j++)
        acc[i][j] = __builtin_amdgcn_mfma_f32_16x16x32_bf16(af[i], bfr[j], acc[i][j], 0, 0, 0);
  }
  #pragma unroll
  for (int i = 0; i < 2; i++)
    #pragma unroll
    for (int j = 0; j < 4; j++) {
      int col = wn * 64 + j * 16 + l16;
      float bv = b2[c * 128 + col];
      #pragma unroll
      for (int r = 0; r < 4; r++) {
        long row = r0 + wm * 32 + i * 16 + quad * 4 + r;
        X[row * 256 + c * 128 + col] += acc[i][j][r] + bv;
      }
    }
}

// ---------- split-K skinny GEMM (M rows <= 16) ----------
template<int M_>
__global__ __launch_bounds__(256) void skinny_gemm(
    const float* __restrict__ A, int lda,
    const float* __restrict__ W, int K,
    float* __restrict__ P, int N, int slice)
{
  __shared__ float Asl[M_ * 192];
  __shared__ float Pr[4][M_][64];
  int tid = threadIdx.x;
  int ks = blockIdx.y;
  int kbeg = ks * slice;
  int kend = min(K, kbeg + slice);
  int sl = kend - kbeg;
  for (int idx = tid; idx < M_ * sl; idx += 256) {
    int m = idx / sl, k = idx - m * sl;
    Asl[m * sl + k] = A[(long)m * lda + kbeg + k];
  }
  __syncthreads();
  int n = blockIdx.x * 64 + (tid & 63);
  int sub = tid >> 6;
  int sl4 = (sl + 3) >> 2;
  int k0 = kbeg + sub * sl4;
  int k1 = min(kend, k0 + sl4);
  float acc[M_];
  #pragma unroll
  for (int m = 0; m < M_; m++) acc[m] = 0.f;
  if (n < N) {
    const float* wr = W + (long)n * K;
    for (int k = k0; k < k1; k++) {
      float w = wr[k];
      int kl = k - kbeg;
      #pragma unroll
      for (int m = 0; m < M_; m++) acc[m] += w * Asl[m * sl + kl];
    }
  }
  #pragma unroll
  for (int m = 0; m < M_; m++) Pr[sub][m][tid & 63] = acc[m];
  __syncthreads();
  if (sub == 0 && n < N) {
    #pragma unroll
    for (int m = 0; m < M_; m++) {
      float s = Pr[0][m][tid] + Pr[1][m][tid] + Pr[2][m][tid] + Pr[3][m][tid];
      P[((long)(ks * M_ + m)) * N + n] = s;
    }
  }
}

__global__ __launch_bounds__(256) void skinny_epi(
    const float* __restrict__ P, const float* __restrict__ bias,
    float* __restrict__ out, int M, int N, int KS, int relu)
{
  int idx = blockIdx.x * 256 + threadIdx.x;
  if (idx >= M * N) return;
  int m = idx / N, n = idx - m * N;
  float s = bias[n];
  for (int ks = 0; ks < KS; ks++) s += P[((long)(ks * M + m)) * N + n];
  if (relu) s = fmaxf(s, 0.f);
  out[(long)m * N + n] = s;
}

template<int M_>
static void sgemm(hipStream_t st, const float* A, int lda, const float* W, int K,
                  const float* bias, float* out, float* P, int N, int KS, int relu) {
  int slice = (K + KS - 1) / KS;
  dim3 grid((N + 63) / 64, KS);
  skinny_gemm<M_><<<grid, 256, 0, st>>>(A, lda, W, K, P, N, slice);
  skinny_epi<<<(M_ * N + 255) / 256, 256, 0, st>>>(P, bias, out, M_, N, KS, relu);
}

// ---------- bag stats ----------
__global__ __launch_bounds__(256) void bag_stats(const float* __restrict__ cp, float* __restrict__ PN) {
  int b = blockIdx.x, tid = threadIdx.x;
  __shared__ float red[256];
  for (int c = 0; c < 2; c++) {
    float s = 0.f;
    for (int n = tid; n < 1024; n += 256) s += cp[((b << 10) + n) * 2 + c];
    float mean = blk_sum256(s, red) * (1.f / 1024.f);
    s = 0.f;
    for (int n = tid; n < 1024; n += 256) { float d = cp[((b << 10) + n) * 2 + c] - mean; s += d * d; }
    float var = blk_sum256(s, red) * (1.f / 1024.f);
    float inv = 1.f / (sqrtf(var) + 1e-8f);
    for (int n = tid; n < 1024; n += 256)
      PN[((b << 10) + n) * 2 + c] = (cp[((b << 10) + n) * 2 + c] - mean) * inv;
  }
}

// ---------- kNN: parallel stable top-8 ----------
__global__ __launch_bounds__(256) void knn_kernel(const float* __restrict__ PN, int* __restrict__ NBR) {
  int blk = blockIdx.x;
  int b = blk >> 5, tg = blk & 31;
  int tid = threadIdx.x;
  int tl = tid >> 3, chunk = tid & 7;
  __shared__ float px[1024], py[1024];
  __shared__ float candD[32][64];
  __shared__ int   candI[32][64];
  for (int i = tid; i < 1024; i += 256) {
    px[i] = PN[((b << 10) + i) * 2 + 0];
    py[i] = PN[((b << 10) + i) * 2 + 1];
  }
  __syncthreads();
  int t = tg * 32 + tl;
  float tx = px[t], ty = py[t];
  float d8[8]; int i8[8];
  #pragma unroll
  for (int i = 0; i < 8; i++) { d8[i] = 3.4e38f; i8[i] = 0x7fffffff; }
  int s0 = chunk * 128;
  for (int s = s0; s < s0 + 128; s++) {
    float dx = __fadd_rn(px[s], -tx), dy = __fadd_rn(py[s], -ty);
    float d2 = __fadd_rn(__fadd_rn(__fmul_rn(dx, dx), __fmul_rn(dy, dy)), 1e-12f);
    float d = sqrtf(d2);
    if (d < d8[7]) {
      d8[7] = d; i8[7] = s;
      #pragma unroll
      for (int p = 7; p > 0; p--) {
        if (d8[p] < d8[p - 1]) {
          float td = d8[p]; d8[p] = d8[p - 1]; d8[p - 1] = td;
          int ti = i8[p]; i8[p] = i8[p - 1]; i8[p - 1] = ti;
        }
      }
    }
  }
  #pragma unroll
  for (int i = 0; i < 8; i++) { candD[tl][chunk * 8 + i] = d8[i]; candI[tl][chunk * 8 + i] = i8[i]; }
  __syncthreads();
  if (chunk == 0) {
    float D[8]; int I[8];
    #pragma unroll
    for (int i = 0; i < 8; i++) { D[i] = candD[tl][i]; I[i] = candI[tl][i]; }
    for (int c = 1; c < 8; c++) {
      for (int j = 0; j < 8; j++) {
        float d = candD[tl][c * 8 + j]; int idx = candI[tl][c * 8 + j];
        bool better = (d < D[7]) || (d == D[7] && idx < I[7]);
        if (!better) break;
        D[7] = d; I[7] = idx;
        #pragma unroll
        for (int p = 7; p > 0; p--) {
          bool sw = (D[p] < D[p - 1]) || (D[p] == D[p - 1] && I[p] < I[p - 1]);
          if (sw) {
            float td = D[p]; D[p] = D[p - 1]; D[p - 1] = td;
            int ti = I[p]; I[p] = I[p - 1]; I[p - 1] = ti;
          }
        }
      }
    }
    #pragma unroll
    for (int i = 0; i < 8; i++) NBR[((long)((b << 10) + t)) * 8 + i] = I[i];
  }
}

// ---------- GAT scores ----------
__global__ __launch_bounds__(256) void gat_scores(const float* __restrict__ Hh,
    const float* __restrict__ asrcW, const float* __restrict__ adstW,
    float* __restrict__ ASRC, float* __restrict__ ADST)
{
  int row = blockIdx.x, tid = threadIdx.x;
  __shared__ float red[256];
  float v = Hh[(long)row * 256 + tid];
  float s1 = v * asrcW[tid];
  float s2 = v * adstW[tid];
  red[tid] = s1; __syncthreads();
  for (int off = 64; off > 0; off >>= 1) { if ((tid & 127) < off) red[tid] += red[tid + off]; __syncthreads(); }
  if ((tid & 127) == 0) ASRC[row * 2 + (tid >> 7)] = red[tid];
  __syncthreads();
  red[tid] = s2; __syncthreads();
  for (int off = 64; off > 0; off >>= 1) { if ((tid & 127) < off) red[tid] += red[tid + off]; __syncthreads(); }
  if ((tid & 127) == 0) ADST[row * 2 + (tid >> 7)] = red[tid];
}

// ---------- GAT aggregate + residual + LN ----------
__global__ __launch_bounds__(256) void gat_aggr_ln(
    const float* __restrict__ Hh, const float* __restrict__ ASRC, const float* __restrict__ ADST,
    const int* __restrict__ NBR, const float* __restrict__ gbias,
    const float* __restrict__ lng, const float* __restrict__ lnb,
    float* __restrict__ X, ushort* __restrict__ Xb)
{
  int row = blockIdx.x, tid = threadIdx.x;
  int b = row >> 10;
  __shared__ int nb[8];
  __shared__ float w[2][8];
  __shared__ float red[256];
  if (tid < 8) {
    int v = NBR[(long)row * 8 + tid];
    nb[tid] = min(max(v, 0), 1023);
  }
  __syncthreads();
  if (tid < 16) {
    int i = tid & 7, h = tid >> 3;
    float e = ADST[row * 2 + h] + ASRC[((b << 10) + nb[i]) * 2 + h];
    w[h][i] = (e >= 0.f) ? e : 0.2f * e;
  }
  __syncthreads();
  if (tid < 2) {
    float m = -3.4e38f;
    for (int i = 0; i < 8; i++) m = fmaxf(m, w[tid][i]);
    float s = 0.f;
    for (int i = 0; i < 8; i++) { float e = expf(w[tid][i] - m); w[tid][i] = e; s += e; }
    float inv = 1.f / s;
    for (int i = 0; i < 8; i++) w[tid][i] *= inv;
  }
  __syncthreads();
  int h = tid >> 7, c = tid & 127;
  float acc = 0.f;
  #pragma unroll
  for (int i = 0; i < 8; i++)
    acc += w[h][i] * Hh[((long)((b << 10) + nb[i])) * 256 + h * 128 + c];
  float v = acc + gbias[tid] + X[(long)row * 256 + tid];
  float mean = blk_sum256(v, red) * (1.f / 256.f);
  float dv = v - mean;
  float var = blk_sum256(dv * dv, red) * (1.f / 256.f);
  float o = dv * rsqrtf(var + 1e-5f) * lng[tid] + lnb[tid];
  X[(long)row * 256 + tid] = o;
  Xb[(long)row * 256 + tid] = f2b(o);
}

// ---------- residual + LayerNorm, D=256, one wave per row ----------
__global__ __launch_bounds__(256) void add_ln4(const float* __restrict__ res,
    const float* __restrict__ Yv, const float* __restrict__ g, const float* __restrict__ b,
    float* __restrict__ out, ushort* __restrict__ outb)
{
  int wave = threadIdx.x >> 6, lane = threadIdx.x & 63;
  long row = blockIdx.x * 4 + wave;
  const float* yr = Yv + row * 256;
  const float* rr = res ? res + row * 256 : nullptr;
  float v[4];
  float s = 0.f;
  #pragma unroll
  for (int i = 0; i < 4; i++) {
    int d = lane + i * 64;
    float x = yr[d];
    if (rr) x += rr[d];
    v[i] = x; s += x;
  }
  #pragma unroll
  for (int off = 32; off > 0; off >>= 1) s += __shfl_xor(s, off);
  float mean = s * (1.f / 256.f);
  float vs = 0.f;
  #pragma unroll
  for (int i = 0; i < 4; i++) { float dv = v[i] - mean; vs += dv * dv; }
  #pragma unroll
  for (int off = 32; off > 0; off >>= 1) vs += __shfl_xor(vs, off);
  float rstd = rsqrtf(vs * (1.f / 256.f) + 1e-5f);
  #pragma unroll
  for (int i = 0; i < 4; i++) {
    int d = lane + i * 64;
    float o = (v[i] - mean) * rstd * g[d] + b[d];
    out[row * 256 + d] = o;
    if (outb) outb[row * 256 + d] = f2b(o);
  }
}

// ---------- LayerNorm (D=1024, head rows) ----------
__global__ __launch_bounds__(256) void add_ln_big(const float* __restrict__ Yv,
    const float* __restrict__ g, const float* __restrict__ b,
    float* __restrict__ out)
{
  int row = blockIdx.x, tid = threadIdx.x;
  __shared__ float red[256];
  float vals[4];
  float s = 0.f;
  #pragma unroll
  for (int i = 0; i < 4; i++) {
    int d = tid + (i << 8);
    float v = Yv[(long)row * 1024 + d];
    vals[i] = v; s += v;
  }
  float mean = blk_sum256(s, red) * (1.f / 1024.f);
  s = 0.f;
  #pragma unroll
  for (int i = 0; i < 4; i++) { float dv = vals[i] - mean; s += dv * dv; }
  float var = blk_sum256(s, red) * (1.f / 1024.f);
  float rstd = rsqrtf(var + 1e-5f);
  #pragma unroll
  for (int i = 0; i < 4; i++) {
    int d = tid + (i << 8);
    out[(long)row * 1024 + d] = (vals[i] - mean) * rstd * g[d] + b[d];
  }
}

// ---------- MFMA flash attention ----------
__global__ __launch_bounds__(256) void flash_mfma(const ushort* __restrict__ QKV,
                                                  const ushort* __restrict__ VT,
                                                  ushort* __restrict__ O)
{
  const float scale = 0.08838834764831845f;
  int blk = blockIdx.x;
  int qt = blk & 15, bh = blk >> 4;
  int b = bh >> 1, h = bh & 1;
  const ushort* qkg = QKV + (long)b * 1024 * 768 + h * 128;
  const ushort* vtg = VT + ((long)bh << 17);

  __shared__ ushort Qs[64][136];
  __shared__ ushort Ks[64][136];
  __shared__ ushort Vt[128][72];
  __shared__ ushort Ps[4][16][72];

  int tid = threadIdx.x;
  int wave = tid >> 6, lane = tid & 63;
  int quad = lane >> 4, l16 = lane & 15;

  #pragma unroll
  for (int p = 0; p < 4; p++) {
    int idx = p * 256 + tid;
    int r = idx >> 4, c8 = (idx & 15) * 8;
    *(uint4*)&Qs[r][c8] = *(const uint4*)(qkg + (long)(qt * 64 + r) * 768 + c8);
  }
  __syncthreads();
  bf16x8 af[4];
  #pragma unroll
  for (int ks = 0; ks < 4; ks++)
    af[ks] = *(const bf16x8*)&Qs[wave * 16 + l16][ks * 32 + quad * 8];

  f32x4 Oacc[8];
  f32x4 zero4 = {0.f, 0.f, 0.f, 0.f};
  #pragma unroll
  for (int j = 0; j < 8; j++) Oacc[j] = zero4;
  float mr[4], lr[4];
  #pragma unroll
  for (int r = 0; r < 4; r++) { mr[r] = -3.4e38f; lr[r] = 0.f; }

  for (int kt = 0; kt < 16; kt++) {
    __syncthreads();
    #pragma unroll
    for (int p = 0; p < 4; p++) {
      int idx = p * 256 + tid;
      int r = idx >> 4, c8 = (idx & 15) * 8;
      *(uint4*)&Ks[r][c8] = *(const uint4*)(qkg + (long)(kt * 64 + r) * 768 + 256 + c8);
      int c = idx >> 3, k8 = (idx & 7) * 8;
      *(uint4*)&Vt[c][k8] = *(const uint4*)(vtg + ((long)c << 10) + kt * 64 + k8);
    }
    __syncthreads();
    f32x4 acc[4];
    #pragma unroll
    for (int j = 0; j < 4; j++) acc[j] = zero4;
    #pragma unroll
    for (int ks = 0; ks < 4; ks++) {
      #pragma unroll
      for (int j = 0; j < 4; j++) {
        bf16x8 kb = *(const bf16x8*)&Ks[j * 16 + l16][ks * 32 + quad * 8];
        acc[j] = __builtin_amdgcn_mfma_f32_16x16x32_bf16(af[ks], kb, acc[j], 0, 0, 0);
      }
    }
    float sv[4][4], tmax[4];
    #pragma unroll
    for (int r = 0; r < 4; r++) tmax[r] = -3.4e38f;
    #pragma unroll
    for (int j = 0; j < 4; j++)
      #pragma unroll
      for (int r = 0; r < 4; r++) {
        float x = acc[j][r] * scale;
        sv[j][r] = x;
        tmax[r] = fmaxf(tmax[r], x);
      }
    #pragma unroll
    for (int off = 1; off < 16; off <<= 1)
      #pragma unroll
      for (int r = 0; r < 4; r++) tmax[r] = fmaxf(tmax[r], __shfl_xor(tmax[r], off));
    float alpha[4], rsum[4];
    #pragma unroll
    for (int r = 0; r < 4; r++) {
      float mn = fmaxf(mr[r], tmax[r]);
      alpha[r] = expf(mr[r] - mn);
      mr[r] = mn;
      rsum[r] = 0.f;
    }
    #pragma unroll
    for (int j = 0; j < 4; j++)
      #pragma unroll
      for (int r = 0; r < 4; r++) {
        float p = expf(sv[j][r] - mr[r]);
        sv[j][r] = p;
        rsum[r] += p;
      }
    #pragma unroll
    for (int off = 1; off < 16; off <<= 1)
      #pragma unroll
      for (int r = 0; r < 4; r++) rsum[r] += __shfl_xor(rsum[r], off);
    #pragma unroll
    for (int r = 0; r < 4; r++) lr[r] = lr[r] * alpha[r] + rsum[r];
    #pragma unroll
    for (int j = 0; j < 4; j++)
      #pragma unroll
      for (int r = 0; r < 4; r++)
        Ps[wave][quad * 4 + r][j * 16 + l16] = f2b(sv[j][r]);
    #pragma unroll
    for (int jj = 0; jj < 8; jj++)
      #pragma unroll
      for (int r = 0; r < 4; r++) Oacc[jj][r] *= alpha[r];
    __syncthreads();
    #pragma unroll
    for (int s = 0; s < 2; s++) {
      bf16x8 pa = *(const bf16x8*)&Ps[wave][l16][s * 32 + quad * 8];
      #pragma unroll
      for (int jj = 0; jj < 8; jj++) {
        bf16x8 vb = *(const bf16x8*)&Vt[jj * 16 + l16][s * 32 + quad * 8];
        Oacc[jj] = __builtin_amdgcn_mfma_f32_16x16x32_bf16(pa, vb, Oacc[jj], 0, 0, 0);
      }
    }
  }
  long row0 = (long)b * 1024 + qt * 64 + wave * 16 + quad * 4;
  #pragma unroll
  for (int jj = 0; jj < 8; jj++) {
    int col = h * 128 + jj * 16 + l16;
    #pragma unroll
    for (int r = 0; r < 4; r++)
      O[(row0 + r) * 256 + col] = f2b(Oacc[jj][r] / lr[r]);
  }
}

// ---------- split-K pooling attention ----------
__global__ __launch_bounds__(128) void pool_split(
    const float* __restrict__ qe, const float* __restrict__ pinW, const float* __restrict__ pinB,
    const float* __restrict__ srand, const ushort* __restrict__ KV,
    float* __restrict__ PM, float* __restrict__ PL, float* __restrict__ PO)
{
  int cid = blockIdx.x;
  int id = blockIdx.y;
  int h = id & 1, nq = (id >> 1) & 3, b = id >> 3;
  int tid = threadIdx.x;
  __shared__ float qs[128];
  __shared__ float eg[128];
  __shared__ float red[128];
  {
    float a = pinB[h * 128 + tid];
    const float* wr = pinW + ((long)(h * 128 + tid)) * 256;
    const float* qr = qe + nq * 256;
    for (int i = 0; i < 256; i++) a += qr[i] * wr[i];
    qs[tid] = a;
  }
  __syncthreads();
  const float scale = 0.08838834764831845f;
  int s = cid * 128 + tid;
  float d = 0.f;
  {
    const ushort* kr = KV + ((long)((b << 10) + s)) * 512 + h * 128;
    #pragma unroll
    for (int c8 = 0; c8 < 128; c8 += 8) {
      uint4 kv4 = *(const uint4*)(kr + c8);
      const ushort* kp = (const ushort*)&kv4;
      #pragma unroll
      for (int j = 0; j < 8; j++) d += qs[c8 + j] * b2f(kp[j]);
    }
  }
  float lg = d * scale + ((srand[nq * 1024 + s] < 0.3f) ? 0.f : -1e9f);
  red[tid] = lg; __syncthreads();
  for (int off = 64; off > 0; off >>= 1) { if (tid < off) red[tid] = fmaxf(red[tid], red[tid + off]); __syncthreads(); }
  float m = red[0]; __syncthreads();
  float e = expf(lg - m);
  eg[tid] = e;
  red[tid] = e; __syncthreads();
  for (int off = 64; off > 0; off >>= 1) { if (tid < off) red[tid] += red[tid + off]; __syncthreads(); }
  float l = red[0];
  __syncthreads();
  float o = 0.f;
  const ushort* vbase = KV + ((long)((b << 10) + cid * 128)) * 512 + 256 + h * 128 + tid;
  for (int ss = 0; ss < 128; ss++)
    o += eg[ss] * b2f(vbase[(long)ss * 512]);
  int part = id * 8 + cid;
  PO[(long)part * 128 + tid] = o;
  if (tid == 0) { PM[part] = m; PL[part] = l; }
}

__global__ __launch_bounds__(128) void pool_merge(
    const float* __restrict__ PM, const float* __restrict__ PL, const float* __restrict__ PO,
    float* __restrict__ ATTP)
{
  int id = blockIdx.x;
  int h = id & 1, nq = (id >> 1) & 3, b = id >> 3;
  int tid = threadIdx.x;
  float m = -3.4e38f;
  #pragma unroll
  for (int c = 0; c < 8; c++) m = fmaxf(m, PM[id * 8 + c]);
  float l = 0.f, o = 0.f;
  #pragma unroll
  for (int c = 0; c < 8; c++) {
    float w = expf(PM[id * 8 + c] - m);
    l += PL[id * 8 + c] * w;
    o += PO[(long)(id * 8 + c) * 128 + tid] * w;
  }
  ATTP[(b * 4 + nq) * 256 + h * 128 + tid] = o / l;
}

// ---------- column-mean partials: PSUM[b*16+ch][256] = sum of 64 rows ----------
__global__ __launch_bounds__(256) void col_mean_part(const float* __restrict__ X,
                                                     float* __restrict__ PSUM)
{
  int blk = blockIdx.x;           // 64 blocks: b*16 + ch
  int b = blk >> 4, ch = blk & 15;
  int d = threadIdx.x;
  float s = 0.f;
  int n0 = ch * 64;
  const float* xr = X + ((long)((b << 10) + n0)) * 256 + d;
  #pragma unroll 4
  for (int n = 0; n < 64; n++) s += xr[(long)n * 256];
  PSUM[(long)blk * 256 + d] = s;
}

// ---------- merge partials + copy pooled_att -> CMB ----------
__global__ __launch_bounds__(256) void combined_merge(const float* __restrict__ PSUM,
    const float* __restrict__ ATTO, float* __restrict__ CMB)
{
  int b = blockIdx.x, d = threadIdx.x;
  float s = 0.f;
  #pragma unroll
  for (int ch = 0; ch < 16; ch++) s += PSUM[(long)(b * 16 + ch) * 256 + d];
  CMB[b * 1280 + d] = s * (1.f / 1024.f);
  #pragma unroll
  for (int q = 0; q < 4; q++)
    CMB[b * 1280 + 256 + q * 256 + d] = ATTO[(b * 4 + q) * 256 + d];
}

__global__ void store_out(const float* __restrict__ src, float* __restrict__ dst, int n) {
  int i = blockIdx.x * blockDim.x + threadIdx.x;
  if (i < n) dst[i] = src[i];
}
__global__ void fill_out_zero(float* __restrict__ dst, int n) {
  int i = blockIdx.x * blockDim.x + threadIdx.x;
  if (i < n) dst[i] = 0.f;
}

extern "C" void kernel_launch(void* const* d_in, const int* in_sizes, int n_in,
                              void* d_out, int out_size, void* d_ws, size_t ws_size,
                              hipStream_t stream)
{
  const float* inp      = (const float*)d_in[0];
  const float* cellp    = (const float*)d_in[1];
  const float* srand    = (const float*)d_in[2];
  const float* emb_W    = (const float*)d_in[3];
  const float* emb_b    = (const float*)d_in[4];
  const float* pe_tab   = (const float*)d_in[5];
  const float* pe_W1    = (const float*)d_in[6];
  const float* pe_b1    = (const float*)d_in[7];
  const float* pe_W2    = (const float*)d_in[8];
  const float* pe_b2    = (const float*)d_in[9];
  const float* gat_W    = (const float*)d_in[10];
  const float* gat_asrc = (const float*)d_in[11];
  const float* gat_adst = (const float*)d_in[12];
  const float* gat_b    = (const float*)d_in[13];
  const float* ln_g     = (const float*)d_in[14];
  const float* ln_b     = (const float*)d_in[15];
  const float* qkv_W    = (const float*)d_in[16];
  const float* qkv_b    = (const float*)d_in[17];
  const float* out_W    = (const float*)d_in[18];
  const float* out_b    = (const float*)d_in[19];
  const float* ff1_W    = (const float*)d_in[20];
  const float* ff1_b    = (const float*)d_in[21];
  const float* ff2_W    = (const float*)d_in[22];
  const float* ff2_b    = (const float*)d_in[23];
  const float* ln1_g    = (const float*)d_in[24];
  const float* ln1_b    = (const float*)d_in[25];
  const float* ln2_g    = (const float*)d_in[26];
  const float* ln2_b    = (const float*)d_in[27];
  const float* q_emb    = (const float*)d_in[28];
  const float* pin_W    = (const float*)d_in[29];
  const float* pin_b    = (const float*)d_in[30];
  const float* pout_W   = (const float*)d_in[31];
  const float* pout_b   = (const float*)d_in[32];
  const float* m1_W     = (const float*)d_in[33];
  const float* m1_b     = (const float*)d_in[34];
  const float* mln1_g   = (const float*)d_in[35];
  const float* mln1_b   = (const float*)d_in[36];
  const float* m2_W     = (const float*)d_in[37];
  const float* m2_b     = (const float*)d_in[38];
  const float* mln2_g   = (const float*)d_in[39];
  const float* mln2_b   = (const float*)d_in[40];
  const float* m3_W     = (const float*)d_in[41];
  const float* m3_b     = (const float*)d_in[42];
  const float* c1_W     = (const float*)d_in[43];
  const float* c1_b     = (const float*)d_in[44];
  const float* c2_W     = (const float*)d_in[45];
  const float* c2_b     = (const float*)d_in[46];
  const float* c3_W     = (const float*)d_in[47];
  const float* c3_b     = (const float*)d_in[48];
  const float* c4_W     = (const float*)d_in[49];
  const float* c4_b     = (const float*)d_in[50];
  (void)in_sizes; (void)n_in;

  // ---- workspace (bytes, 256-aligned; ~20.6 MB) ----
  char* base = (char*)d_ws;
  size_t off = 0;
  auto alloc = [&](size_t bytes) { void* p = base + off; off += (bytes + 255) & ~size_t(255); return p; };
  float* PN    = (float*)alloc(32768);
  float* AS    = (float*)alloc(32768);
  float* AD    = (float*)alloc(32768);
  float* ATTP  = (float*)alloc(16384);
  float* ATTO  = (float*)alloc(16384);
  float* CMB   = (float*)alloc(20480);
  float* Ha    = (float*)alloc(16384);
  float* Hb    = (float*)alloc(16384);
  float* Hc    = (float*)alloc(16640);
  float* Hd    = (float*)alloc(8192);
  float* He    = (float*)alloc(4096);
  float* Hf    = (float*)alloc(512);
  float* Pk    = (float*)alloc(262144);
  float* PPM   = (float*)alloc(1024);
  float* PPL   = (float*)alloc(1024);
  float* PPO   = (float*)alloc(131072);
  float* PSUM  = (float*)alloc(65536);            // col-mean partials [64][256]
  int*   NBR   = (int*)alloc(131072);
  float* X     = (float*)alloc(4194304);
  ushort* Xb   = (ushort*)alloc(2097152);
  char*  Rq    = (char*)alloc(6291456);
  char*  Rf    = (char*)alloc(4194304);
  ushort* QKVb = (ushort*)Rq;
  float*  F2   = (float*)Rq;
  ushort* KVb  = (ushort*)Rq;
  ushort* Ob   = (ushort*)Rf;
  ushort* VT   = (ushort*)(Rf + 2097152);
  ushort* FFBb = (ushort*)Rf;
  float*  F1   = (float*)alloc(4194304);
  if (ws_size < off) { fill_out_zero<<<1, 128, 0, stream>>>((float*)d_out, out_size); return; }

  // ---- graph construction ----
  bag_stats<<<4, 256, 0, stream>>>(cellp, PN);
  knn_kernel<<<128, 256, 0, stream>>>(PN, NBR);

  // ---- embedding + positional MLP (MFMA) ----
  mgemm<float>(stream, inp, 512, emb_W, 512, emb_b, X, 256, 4096, 256, 512, 0);
  pos_mlp<<<dim3(64, 2), 256, 0, stream>>>(cellp, pe_tab, pe_W1, pe_b1, pe_W2, pe_b2, X);
  cvt_f2b<<<1024, 256, 0, stream>>>(X, Xb, 4096 * 256);

  // ---- 2x GAT ----
  for (int l = 0; l < 2; l++) {
    mgemm<float>(stream, Xb, 256, gat_W + l * 65536, 256, (const float*)nullptr, F1, 256,
                 4096, 256, 256, 0);
    gat_scores<<<4096, 256, 0, stream>>>(F1, gat_asrc + l * 256, gat_adst + l * 256, AS, AD);
    gat_aggr_ln<<<4096, 256, 0, stream>>>(F1, AS, AD, NBR, gat_b + l * 256, ln_g, ln_b, X, Xb);
  }

  // ---- 2x Transformer encoder layer ----
  for (int l = 0; l < 2; l++) {
    mgemm_vt(stream, Xb, 256, qkv_W + (long)l * 768 * 256, 256, qkv_b + l * 768,
             QKVb, 768, 4096, 768, 256, VT);
    flash_mfma<<<256, 256, 0, stream>>>(QKVb, VT, Ob);
    mgemm<float>(stream, Ob, 256, out_W + l * 65536, 256, out_b + l * 256, F2, 256,
                 4096, 256, 256, 0);
    add_ln4<<<1024, 256, 0, stream>>>(X, F2, ln1_g + l * 256, ln1_b + l * 256, X, Xb);
    for (int ch = 0; ch < 2; ch++) {
      mgemm<ushort>(stream, Xb + (long)ch * 2048 * 256, 256, ff1_W + l * 262144, 256,
                    ff1_b + l * 1024, FFBb, 1024, 2048, 1024, 256, 1);
      mgemm<float>(stream, FFBb, 1024, ff2_W + l * 262144, 1024, ff2_b + l * 256,
                   F2 + (long)ch * 2048 * 256, 256, 2048, 256, 1024, 0);
    }
    add_ln4<<<1024, 256, 0, stream>>>(X, F2, ln2_g + l * 256, ln2_b + l * 256, X, Xb);
  }

  // ---- final LN ----
  add_ln4<<<1024, 256, 0, stream>>>((const float*)nullptr, X, ln_g, ln_b, X, Xb);

  // ---- pooling (split-K flash-decode style) ----
  mgemm<ushort>(stream, Xb, 256, pin_W + 65536, 256, pin_b + 256, KVb, 512, 4096, 512, 256, 0);
  pool_split<<<dim3(8, 32), 128, 0, stream>>>(q_emb, pin_W, pin_b, srand, KVb, PPM, PPL, PPO);
  pool_merge<<<32, 128, 0, stream>>>(PPM, PPL, PPO, ATTP);
  sgemm<16>(stream, ATTP, 256, pout_W, 256, pout_b, ATTO, Pk, 256, 2, 0);
  col_mean_part<<<64, 256, 0, stream>>>(X, PSUM);
  combined_merge<<<4, 256, 0, stream>>>(PSUM, ATTO, CMB);

  // ---- MLP head (fp32, split-K skinny GEMMs) ----
  sgemm<4>(stream, CMB, 1280, m1_W, 1280, m1_b, Ha, Pk, 1024, 8, 1);
  add_ln_big<<<4, 256, 0, stream>>>(Ha, mln1_g, mln1_b, Ha);
  sgemm<4>(stream, Ha, 1024, m2_W, 1024, m2_b, Hb, Pk, 1024, 8, 1);
  add_ln_big<<<4, 256, 0, stream>>>(Hb, mln2_g, mln2_b, Hb);
  sgemm<4>(stream, Hb, 1024, m3_W, 1024, m3_b, Ha, Pk, 1024, 8, 0);
  sgemm<4>(stream, Ha, 1024, c1_W, 1024, c1_b, Hc, Pk, 1032, 8, 1);
  sgemm<4>(stream, Hc, 1032, c2_W, 1032, c2_b, Hd, Pk, 512, 8, 1);
  sgemm<4>(stream, Hd, 512, c3_W, 512, c3_b, He, Pk, 256, 4, 1);
  sgemm<4>(stream, He, 256, c4_W, 256, c4_b, Hf, Pk, 24, 2, 0);
  store_out<<<1, 128, 0, stream>>>(Hf, (float*)d_out, out_size);
}

// Round 11
// 727.569 us; speedup vs baseline: 5.4754x; 1.0115x over previous
//
#include <hip/hip_runtime.h>
#include <hip/hip_bf16.h>

// MILCellModel forward on MI355X. Round 11: kNN rework — strided conflict-free
// chunk scan (R10: 1.97e6 LDS bank-conflict cycles from stride-128 chunks),
// 512 blocks (was 128), transposed candidate layout, 2-stage parallel merge.
// B=4 N=1024 E=512 D=256 H=2 C=128 FF=1024 NQ=4 NCLS=24

typedef __bf16 bf16x8 __attribute__((ext_vector_type(8)));
typedef float  f32x4  __attribute__((ext_vector_type(4)));

__device__ __forceinline__ ushort f2b(float f) {
  __hip_bfloat16 h = __float2bfloat16(f);
  return *(ushort*)&h;
}
__device__ __forceinline__ float b2f(ushort u) {
  union { unsigned i; float f; } v; v.i = ((unsigned)u) << 16; return v.f;
}

// ---------- block reductions (256 threads) ----------
__device__ __forceinline__ float blk_sum256(float v, float* red) {
  int t = threadIdx.x;
  red[t] = v; __syncthreads();
  #pragma unroll
  for (int off = 128; off > 0; off >>= 1) {
    if (t < off) red[t] += red[t + off];
    __syncthreads();
  }
  float r = red[0]; __syncthreads();
  return r;
}

// ---------- fp32 -> bf16 convert ----------
__global__ __launch_bounds__(256) void cvt_f2b(const float* __restrict__ src,
                                               ushort* __restrict__ dst, int n) {
  int i = (blockIdx.x * 256 + threadIdx.x) * 4;
  if (i >= n) return;
  float4 v = *(const float4*)(src + i);
  ushort4 o;
  o.x = f2b(v.x); o.y = f2b(v.y); o.z = f2b(v.z); o.w = f2b(v.w);
  *(ushort4*)(dst + i) = o;
}

// ---------- staging helpers: 8 contiguous elements -> bf16 LDS ----------
__device__ __forceinline__ void stage8(const ushort* __restrict__ src, ushort* dst) {
  *(uint4*)dst = *(const uint4*)src;
}
__device__ __forceinline__ void stage8(const float* __restrict__ src, ushort* dst) {
  float4 a = ((const float4*)src)[0];
  float4 b = ((const float4*)src)[1];
  ushort4 o0, o1;
  o0.x = f2b(a.x); o0.y = f2b(a.y); o0.z = f2b(a.z); o0.w = f2b(a.w);
  o1.x = f2b(b.x); o1.y = f2b(b.y); o1.z = f2b(b.z); o1.w = f2b(b.w);
  *(ushort4*)dst = o0;
  *(ushort4*)(dst + 4) = o1;
}

// ---------- bf16 MFMA GEMM: C[M,N] = act(A[M,K] @ B^T + bias) ----------
template<typename CT, typename AT, typename WT, bool VSPLIT>
__global__ __launch_bounds__(256) void mfma_gemm(
    const AT* __restrict__ A, int lda,
    const WT* __restrict__ Bw, int ldb,
    const float* __restrict__ bias,
    CT* __restrict__ C, int ldc, int K, int relu,
    ushort* __restrict__ VT)
{
  __shared__ ushort As[64][40];
  __shared__ ushort Bs[128][40];
  int tid = threadIdx.x;
  int lane = tid & 63, wave = tid >> 6;
  int wm = wave >> 1, wn = wave & 1;
  int quad = lane >> 4, l16 = lane & 15;
  long mBase = blockIdx.y * 64, nBase = blockIdx.x * 128;

  f32x4 zero4 = {0.f, 0.f, 0.f, 0.f};
  f32x4 acc[2][4];
  #pragma unroll
  for (int i = 0; i < 2; i++)
    #pragma unroll
    for (int j = 0; j < 4; j++) acc[i][j] = zero4;

  for (int k0 = 0; k0 < K; k0 += 32) {
    {
      int r = tid >> 2, sg = (tid & 3) * 8;
      stage8(A + (mBase + r) * lda + k0 + sg, &As[r][sg]);
    }
    #pragma unroll
    for (int p = 0; p < 2; p++) {
      int idx = p * 256 + tid;
      int r = idx >> 2, sg = (idx & 3) * 8;
      stage8(Bw + (nBase + r) * ldb + k0 + sg, &Bs[r][sg]);
    }
    __syncthreads();
    bf16x8 af[2], bfr[4];
    #pragma unroll
    for (int i = 0; i < 2; i++)
      af[i] = *(const bf16x8*)&As[wm * 32 + i * 16 + l16][quad * 8];
    #pragma unroll
    for (int j = 0; j < 4; j++)
      bfr[j] = *(const bf16x8*)&Bs[wn * 64 + j * 16 + l16][quad * 8];
    #pragma unroll
    for (int i = 0; i < 2; i++)
      #pragma unroll
      for (int j = 0; j < 4; j++)
        acc[i][j] = __builtin_amdgcn_mfma_f32_16x16x32_bf16(af[i], bfr[j], acc[i][j], 0, 0, 0);
    __syncthreads();
  }
  #pragma unroll
  for (int i = 0; i < 2; i++) {
    #pragma unroll
    for (int j = 0; j < 4; j++) {
      long col = nBase + wn * 64 + j * 16 + l16;
      float bv = bias ? bias[col] : 0.f;
      long row0 = mBase + wm * 32 + i * 16 + quad * 4;
      if (VSPLIT && col >= 512) {
        int cm = (int)col - 512, hh = cm >> 7, cc = cm & 127;
        long bidx = row0 >> 10, n0 = row0 & 1023;
        ushort4 o;
        o.x = f2b(acc[i][j][0] + bv);
        o.y = f2b(acc[i][j][1] + bv);
        o.z = f2b(acc[i][j][2] + bv);
        o.w = f2b(acc[i][j][3] + bv);
        *(ushort4*)&VT[(((bidx * 2 + hh) * 128 + cc) << 10) + n0] = o;
      } else {
        #pragma unroll
        for (int r = 0; r < 4; r++) {
          float v = acc[i][j][r] + bv;
          if (relu) v = fmaxf(v, 0.f);
          if constexpr (sizeof(CT) == 2) C[(row0 + r) * ldc + col] = f2b(v);
          else                           C[(row0 + r) * ldc + col] = v;
        }
      }
    }
  }
}

template<typename CT, typename AT, typename WT>
static void mgemm(hipStream_t st, const AT* A, int lda, const WT* B, int ldb,
                  const float* bias, CT* C, int ldc, int M, int N, int K, int relu) {
  dim3 grid(N / 128, M / 64);
  mfma_gemm<CT, AT, WT, false><<<grid, 256, 0, st>>>(A, lda, B, ldb, bias, C, ldc, K, relu, nullptr);
}
template<typename AT, typename WT>
static void mgemm_vt(hipStream_t st, const AT* A, int lda, const WT* B, int ldb,
                     const float* bias, ushort* C, int ldc, int M, int N, int K, ushort* VT) {
  dim3 grid(N / 128, M / 64);
  mfma_gemm<ushort, AT, WT, true><<<grid, 256, 0, st>>>(A, lda, B, ldb, bias, C, ldc, K, 0, VT);
}

// ---------- fused pos-embed MLP (MFMA, weights LDS-resident) ----------
__global__ __launch_bounds__(256) void pos_mlp(
    const float* __restrict__ cellp, const float* __restrict__ tab,
    const float* __restrict__ W1, const float* __restrict__ b1,
    const float* __restrict__ W2, const float* __restrict__ b2,
    float* __restrict__ X)
{
  __shared__ ushort Es[64][136];
  __shared__ ushort Bs[128][136];
  __shared__ ushort H1s[64][136];
  int tid = threadIdx.x;
  int lane = tid & 63, wave = tid >> 6;
  int wm = wave >> 1, wn = wave & 1;
  int quad = lane >> 4, l16 = lane & 15;
  int r0 = blockIdx.x * 64, c = blockIdx.y;

  #pragma unroll
  for (int p = 0; p < 4; p++) {
    int idx = p * 256 + tid;
    int r = idx >> 4, c8 = (idx & 15) * 8;
    float pos = cellp[(r0 + r) * 2 + c];
    pos = fminf(fmaxf(pos, 0.f), 1000.f);
    int pi = (int)pos;
    stage8(tab + ((long)(c * 1001 + pi)) * 128 + c8, &Es[r][c8]);
  }
  #pragma unroll
  for (int p = 0; p < 8; p++) {
    int idx = p * 256 + tid;
    int r = idx >> 4, c8 = (idx & 15) * 8;
    stage8(W1 + ((long)(c * 128 + r)) * 128 + c8, &Bs[r][c8]);
  }
  __syncthreads();

  f32x4 zero4 = {0.f, 0.f, 0.f, 0.f};
  f32x4 acc[2][4];
  #pragma unroll
  for (int i = 0; i < 2; i++)
    #pragma unroll
    for (int j = 0; j < 4; j++) acc[i][j] = zero4;
  #pragma unroll
  for (int ks = 0; ks < 4; ks++) {
    bf16x8 af[2], bfr[4];
    #pragma unroll
    for (int i = 0; i < 2; i++)
      af[i] = *(const bf16x8*)&Es[wm * 32 + i * 16 + l16][ks * 32 + quad * 8];
    #pragma unroll
    for (int j = 0; j < 4; j++)
      bfr[j] = *(const bf16x8*)&Bs[wn * 64 + j * 16 + l16][ks * 32 + quad * 8];
    #pragma unroll
    for (int i = 0; i < 2; i++)
      #pragma unroll
      for (int j = 0; j < 4; j++)
        acc[i][j] = __builtin_amdgcn_mfma_f32_16x16x32_bf16(af[i], bfr[j], acc[i][j], 0, 0, 0);
  }
  #pragma unroll
  for (int i = 0; i < 2; i++)
    #pragma unroll
    for (int j = 0; j < 4; j++) {
      int col = wn * 64 + j * 16 + l16;
      float bv = b1[c * 128 + col];
      #pragma unroll
      for (int r = 0; r < 4; r++) {
        int row = wm * 32 + i * 16 + quad * 4 + r;
        H1s[row][col] = f2b(fmaxf(acc[i][j][r] + bv, 0.f));
      }
    }
  __syncthreads();
  #pragma unroll
  for (int p = 0; p < 8; p++) {
    int idx = p * 256 + tid;
    int r = idx >> 4, c8 = (idx & 15) * 8;
    stage8(W2 + ((long)(c * 128 + r)) * 128 + c8, &Bs[r][c8]);
  }
  __syncthreads();
  #pragma unroll
  for (int i = 0; i < 2; i++)
    #pragma unroll
    for (int j = 0; j < 4; j++) acc[i][j] = zero4;
  #pragma unroll
  for (int ks = 0; ks < 4; ks++) {
    bf16x8 af[2], bfr[4];
    #pragma unroll
    for (int i = 0; i < 2; i++)
      af[i] = *(const bf16x8*)&H1s[wm * 32 + i * 16 + l16][ks * 32 + quad * 8];
    #pragma unroll
    for (int j = 0; j < 4; j++)
      bfr[j] = *(const bf16x8*)&Bs[wn * 64 + j * 16 + l16][ks * 32 + quad * 8];
    #pragma unroll
    for (int i = 0; i < 2; i++)
      #pragma unroll
      for (int j = 0; j < 4; j++)
        acc[i][j] = __builtin_amdgcn_mfma_f32_16x16x32_bf16(af[i], bfr[j], acc[i][j], 0, 0, 0);
  }
  #pragma unroll
  for (int i = 0; i < 2; i++)
    #pragma unroll
    for (int j = 0; j < 4; j++) {
      int col = wn * 64 + j * 16 + l16;
      float bv = b2[c * 128 + col];
      #pragma unroll
      for (int r = 0; r < 4; r++) {
        long row = r0 + wm * 32 + i * 16 + quad * 4 + r;
        X[row * 256 + c * 128 + col] += acc[i][j][r] + bv;
      }
    }
}

// ---------- split-K skinny GEMM (M rows <= 16) ----------
template<int M_>
__global__ __launch_bounds__(256) void skinny_gemm(
    const float* __restrict__ A, int lda,
    const float* __restrict__ W, int K,
    float* __restrict__ P, int N, int slice)
{
  __shared__ float Asl[M_ * 192];
  __shared__ float Pr[4][M_][64];
  int tid = threadIdx.x;
  int ks = blockIdx.y;
  int kbeg = ks * slice;
  int kend = min(K, kbeg + slice);
  int sl = kend - kbeg;
  for (int idx = tid; idx < M_ * sl; idx += 256) {
    int m = idx / sl, k = idx - m * sl;
    Asl[m * sl + k] = A[(long)m * lda + kbeg + k];
  }
  __syncthreads();
  int n = blockIdx.x * 64 + (tid & 63);
  int sub = tid >> 6;
  int sl4 = (sl + 3) >> 2;
  int k0 = kbeg + sub * sl4;
  int k1 = min(kend, k0 + sl4);
  float acc[M_];
  #pragma unroll
  for (int m = 0; m < M_; m++) acc[m] = 0.f;
  if (n < N) {
    const float* wr = W + (long)n * K;
    for (int k = k0; k < k1; k++) {
      float w = wr[k];
      int kl = k - kbeg;
      #pragma unroll
      for (int m = 0; m < M_; m++) acc[m] += w * Asl[m * sl + kl];
    }
  }
  #pragma unroll
  for (int m = 0; m < M_; m++) Pr[sub][m][tid & 63] = acc[m];
  __syncthreads();
  if (sub == 0 && n < N) {
    #pragma unroll
    for (int m = 0; m < M_; m++) {
      float s = Pr[0][m][tid] + Pr[1][m][tid] + Pr[2][m][tid] + Pr[3][m][tid];
      P[((long)(ks * M_ + m)) * N + n] = s;
    }
  }
}

__global__ __launch_bounds__(256) void skinny_epi(
    const float* __restrict__ P, const float* __restrict__ bias,
    float* __restrict__ out, int M, int N, int KS, int relu)
{
  int idx = blockIdx.x * 256 + threadIdx.x;
  if (idx >= M * N) return;
  int m = idx / N, n = idx - m * N;
  float s = bias[n];
  for (int ks = 0; ks < KS; ks++) s += P[((long)(ks * M + m)) * N + n];
  if (relu) s = fmaxf(s, 0.f);
  out[(long)m * N + n] = s;
}

template<int M_>
static void sgemm(hipStream_t st, const float* A, int lda, const float* W, int K,
                  const float* bias, float* out, float* P, int N, int KS, int relu) {
  int slice = (K + KS - 1) / KS;
  dim3 grid((N + 63) / 64, KS);
  skinny_gemm<M_><<<grid, 256, 0, st>>>(A, lda, W, K, P, N, slice);
  skinny_epi<<<(M_ * N + 255) / 256, 256, 0, st>>>(P, bias, out, M_, N, KS, relu);
}

// ---------- bag stats ----------
__global__ __launch_bounds__(256) void bag_stats(const float* __restrict__ cp, float* __restrict__ PN) {
  int b = blockIdx.x, tid = threadIdx.x;
  __shared__ float red[256];
  for (int c = 0; c < 2; c++) {
    float s = 0.f;
    for (int n = tid; n < 1024; n += 256) s += cp[((b << 10) + n) * 2 + c];
    float mean = blk_sum256(s, red) * (1.f / 1024.f);
    s = 0.f;
    for (int n = tid; n < 1024; n += 256) { float d = cp[((b << 10) + n) * 2 + c] - mean; s += d * d; }
    float var = blk_sum256(s, red) * (1.f / 1024.f);
    float inv = 1.f / (sqrtf(var) + 1e-8f);
    for (int n = tid; n < 1024; n += 256)
      PN[((b << 10) + n) * 2 + c] = (cp[((b << 10) + n) * 2 + c] - mean) * inv;
  }
}

// ---------- lexicographic merge of a sorted-8 list into D/I (early break) ----------
__device__ __forceinline__ void merge8(float* D, int* I,
                                       const float* cd, const int* ci, int stride) {
  #pragma unroll 1
  for (int j = 0; j < 8; j++) {
    float d = cd[j * stride]; int idx = ci[j * stride];
    bool better = (d < D[7]) || (d == D[7] && idx < I[7]);
    if (!better) break;   // incoming sorted -> rest also fail
    D[7] = d; I[7] = idx;
    #pragma unroll
    for (int p = 7; p > 0; p--) {
      bool sw = (D[p] < D[p - 1]) || (D[p] == D[p - 1] && I[p] < I[p - 1]);
      if (sw) {
        float td = D[p]; D[p] = D[p - 1]; D[p - 1] = td;
        int ti = I[p]; I[p] = I[p - 1]; I[p - 1] = ti;
      }
    }
  }
}

// ---------- kNN: 512 blocks, 8 targets x 32 strided chunks, 2-stage merge ----------
__global__ __launch_bounds__(256) void knn_kernel(const float* __restrict__ PN, int* __restrict__ NBR) {
  int blk = blockIdx.x;               // 512 blocks
  int b = blk >> 7, grp = blk & 127;  // 8 targets per block
  int tid = threadIdx.x;
  int tl = tid >> 5, chunk = tid & 31;
  __shared__ float px[1024], py[1024];
  __shared__ float candD[8][8][32];   // [target][rank][chunk] -> bank = chunk
  __shared__ int   candI[8][8][32];
  for (int i = tid; i < 1024; i += 256) {
    px[i] = PN[((b << 10) + i) * 2 + 0];
    py[i] = PN[((b << 10) + i) * 2 + 1];
  }
  __syncthreads();
  int t = grp * 8 + tl;
  float tx = px[t], ty = py[t];
  float d8[8]; int i8[8];
  #pragma unroll
  for (int i = 0; i < 8; i++) { d8[i] = 3.4e38f; i8[i] = 0x7fffffff; }
  // strided scan: ascending index order -> (d,idx)-lexicographic list
  for (int s = chunk; s < 1024; s += 32) {
    float dx = __fadd_rn(px[s], -tx), dy = __fadd_rn(py[s], -ty);
    float d2 = __fadd_rn(__fadd_rn(__fmul_rn(dx, dx), __fmul_rn(dy, dy)), 1e-12f);
    float d = sqrtf(d2);
    if (d < d8[7]) {
      d8[7] = d; i8[7] = s;
      #pragma unroll
      for (int p = 7; p > 0; p--) {
        if (d8[p] < d8[p - 1]) {
          float td = d8[p]; d8[p] = d8[p - 1]; d8[p - 1] = td;
          int ti = i8[p]; i8[p] = i8[p - 1]; i8[p - 1] = ti;
        }
      }
    }
  }
  #pragma unroll
  for (int i = 0; i < 8; i++) { candD[tl][i][chunk] = d8[i]; candI[tl][i][chunk] = i8[i]; }
  __syncthreads();
  // stage A: 4 threads/target, each merges its group of 8 chunk-lists
  if ((chunk & 7) == 0) {
    float D[8]; int I[8];
    #pragma unroll
    for (int i = 0; i < 8; i++) { D[i] = candD[tl][i][chunk]; I[i] = candI[tl][i][chunk]; }
    for (int c = chunk + 1; c < chunk + 8; c++)
      merge8(D, I, &candD[tl][0][c], &candI[tl][0][c], 32);
    #pragma unroll
    for (int i = 0; i < 8; i++) { candD[tl][i][chunk] = D[i]; candI[tl][i][chunk] = I[i]; }
  }
  __syncthreads();
  // stage B: thread 0 of each target merges the 4 partials
  if (chunk == 0) {
    float D[8]; int I[8];
    #pragma unroll
    for (int i = 0; i < 8; i++) { D[i] = candD[tl][i][0]; I[i] = candI[tl][i][0]; }
    merge8(D, I, &candD[tl][0][8], &candI[tl][0][8], 32);
    merge8(D, I, &candD[tl][0][16], &candI[tl][0][16], 32);
    merge8(D, I, &candD[tl][0][24], &candI[tl][0][24], 32);
    #pragma unroll
    for (int i = 0; i < 8; i++) NBR[((long)((b << 10) + t)) * 8 + i] = I[i];
  }
}

// ---------- GAT scores ----------
__global__ __launch_bounds__(256) void gat_scores(const float* __restrict__ Hh,
    const float* __restrict__ asrcW, const float* __restrict__ adstW,
    float* __restrict__ ASRC, float* __restrict__ ADST)
{
  int row = blockIdx.x, tid = threadIdx.x;
  __shared__ float red[256];
  float v = Hh[(long)row * 256 + tid];
  float s1 = v * asrcW[tid];
  float s2 = v * adstW[tid];
  red[tid] = s1; __syncthreads();
  for (int off = 64; off > 0; off >>= 1) { if ((tid & 127) < off) red[tid] += red[tid + off]; __syncthreads(); }
  if ((tid & 127) == 0) ASRC[row * 2 + (tid >> 7)] = red[tid];
  __syncthreads();
  red[tid] = s2; __syncthreads();
  for (int off = 64; off > 0; off >>= 1) { if ((tid & 127) < off) red[tid] += red[tid + off]; __syncthreads(); }
  if ((tid & 127) == 0) ADST[row * 2 + (tid >> 7)] = red[tid];
}

// ---------- GAT aggregate + residual + LN ----------
__global__ __launch_bounds__(256) void gat_aggr_ln(
    const float* __restrict__ Hh, const float* __restrict__ ASRC, const float* __restrict__ ADST,
    const int* __restrict__ NBR, const float* __restrict__ gbias,
    const float* __restrict__ lng, const float* __restrict__ lnb,
    float* __restrict__ X, ushort* __restrict__ Xb)
{
  int row = blockIdx.x, tid = threadIdx.x;
  int b = row >> 10;
  __shared__ int nb[8];
  __shared__ float w[2][8];
  __shared__ float red[256];
  if (tid < 8) {
    int v = NBR[(long)row * 8 + tid];
    nb[tid] = min(max(v, 0), 1023);
  }
  __syncthreads();
  if (tid < 16) {
    int i = tid & 7, h = tid >> 3;
    float e = ADST[row * 2 + h] + ASRC[((b << 10) + nb[i]) * 2 + h];
    w[h][i] = (e >= 0.f) ? e : 0.2f * e;
  }
  __syncthreads();
  if (tid < 2) {
    float m = -3.4e38f;
    for (int i = 0; i < 8; i++) m = fmaxf(m, w[tid][i]);
    float s = 0.f;
    for (int i = 0; i < 8; i++) { float e = expf(w[tid][i] - m); w[tid][i] = e; s += e; }
    float inv = 1.f / s;
    for (int i = 0; i < 8; i++) w[tid][i] *= inv;
  }
  __syncthreads();
  int h = tid >> 7, c = tid & 127;
  float acc = 0.f;
  #pragma unroll
  for (int i = 0; i < 8; i++)
    acc += w[h][i] * Hh[((long)((b << 10) + nb[i])) * 256 + h * 128 + c];
  float v = acc + gbias[tid] + X[(long)row * 256 + tid];
  float mean = blk_sum256(v, red) * (1.f / 256.f);
  float dv = v - mean;
  float var = blk_sum256(dv * dv, red) * (1.f / 256.f);
  float o = dv * rsqrtf(var + 1e-5f) * lng[tid] + lnb[tid];
  X[(long)row * 256 + tid] = o;
  Xb[(long)row * 256 + tid] = f2b(o);
}

// ---------- residual + LayerNorm, D=256, one wave per row ----------
__global__ __launch_bounds__(256) void add_ln4(const float* __restrict__ res,
    const float* __restrict__ Yv, const float* __restrict__ g, const float* __restrict__ b,
    float* __restrict__ out, ushort* __restrict__ outb)
{
  int wave = threadIdx.x >> 6, lane = threadIdx.x & 63;
  long row = blockIdx.x * 4 + wave;
  const float* yr = Yv + row * 256;
  const float* rr = res ? res + row * 256 : nullptr;
  float v[4];
  float s = 0.f;
  #pragma unroll
  for (int i = 0; i < 4; i++) {
    int d = lane + i * 64;
    float x = yr[d];
    if (rr) x += rr[d];
    v[i] = x; s += x;
  }
  #pragma unroll
  for (int off = 32; off > 0; off >>= 1) s += __shfl_xor(s, off);
  float mean = s * (1.f / 256.f);
  float vs = 0.f;
  #pragma unroll
  for (int i = 0; i < 4; i++) { float dv = v[i] - mean; vs += dv * dv; }
  #pragma unroll
  for (int off = 32; off > 0; off >>= 1) vs += __shfl_xor(vs, off);
  float rstd = rsqrtf(vs * (1.f / 256.f) + 1e-5f);
  #pragma unroll
  for (int i = 0; i < 4; i++) {
    int d = lane + i * 64;
    float o = (v[i] - mean) * rstd * g[d] + b[d];
    out[row * 256 + d] = o;
    if (outb) outb[row * 256 + d] = f2b(o);
  }
}

// ---------- LayerNorm (D=1024, head rows) ----------
__global__ __launch_bounds__(256) void add_ln_big(const float* __restrict__ Yv,
    const float* __restrict__ g, const float* __restrict__ b,
    float* __restrict__ out)
{
  int row = blockIdx.x, tid = threadIdx.x;
  __shared__ float red[256];
  float vals[4];
  float s = 0.f;
  #pragma unroll
  for (int i = 0; i < 4; i++) {
    int d = tid + (i << 8);
    float v = Yv[(long)row * 1024 + d];
    vals[i] = v; s += v;
  }
  float mean = blk_sum256(s, red) * (1.f / 1024.f);
  s = 0.f;
  #pragma unroll
  for (int i = 0; i < 4; i++) { float dv = vals[i] - mean; s += dv * dv; }
  float var = blk_sum256(s, red) * (1.f / 1024.f);
  float rstd = rsqrtf(var + 1e-5f);
  #pragma unroll
  for (int i = 0; i < 4; i++) {
    int d = tid + (i << 8);
    out[(long)row * 1024 + d] = (vals[i] - mean) * rstd * g[d] + b[d];
  }
}

// ---------- MFMA flash attention ----------
__global__ __launch_bounds__(256) void flash_mfma(const ushort* __restrict__ QKV,
                                                  const ushort* __restrict__ VT,
                                                  ushort* __restrict__ O)
{
  const float scale = 0.08838834764831845f;
  int blk = blockIdx.x;
  int qt = blk & 15, bh = blk >> 4;
  int b = bh >> 1, h = bh & 1;
  const ushort* qkg = QKV + (long)b * 1024 * 768 + h * 128;
  const ushort* vtg = VT + ((long)bh << 17);

  __shared__ ushort Qs[64][136];
  __shared__ ushort Ks[64][136];
  __shared__ ushort Vt[128][72];
  __shared__ ushort Ps[4][16][72];

  int tid = threadIdx.x;
  int wave = tid >> 6, lane = tid & 63;
  int quad = lane >> 4, l16 = lane & 15;

  #pragma unroll
  for (int p = 0; p < 4; p++) {
    int idx = p * 256 + tid;
    int r = idx >> 4, c8 = (idx & 15) * 8;
    *(uint4*)&Qs[r][c8] = *(const uint4*)(qkg + (long)(qt * 64 + r) * 768 + c8);
  }
  __syncthreads();
  bf16x8 af[4];
  #pragma unroll
  for (int ks = 0; ks < 4; ks++)
    af[ks] = *(const bf16x8*)&Qs[wave * 16 + l16][ks * 32 + quad * 8];

  f32x4 Oacc[8];
  f32x4 zero4 = {0.f, 0.f, 0.f, 0.f};
  #pragma unroll
  for (int j = 0; j < 8; j++) Oacc[j] = zero4;
  float mr[4], lr[4];
  #pragma unroll
  for (int r = 0; r < 4; r++) { mr[r] = -3.4e38f; lr[r] = 0.f; }

  for (int kt = 0; kt < 16; kt++) {
    __syncthreads();
    #pragma unroll
    for (int p = 0; p < 4; p++) {
      int idx = p * 256 + tid;
      int r = idx >> 4, c8 = (idx & 15) * 8;
      *(uint4*)&Ks[r][c8] = *(const uint4*)(qkg + (long)(kt * 64 + r) * 768 + 256 + c8);
      int c = idx >> 3, k8 = (idx & 7) * 8;
      *(uint4*)&Vt[c][k8] = *(const uint4*)(vtg + ((long)c << 10) + kt * 64 + k8);
    }
    __syncthreads();
    f32x4 acc[4];
    #pragma unroll
    for (int j = 0; j < 4; j++) acc[j] = zero4;
    #pragma unroll
    for (int ks = 0; ks < 4; ks++) {
      #pragma unroll
      for (int j = 0; j < 4; j++) {
        bf16x8 kb = *(const bf16x8*)&Ks[j * 16 + l16][ks * 32 + quad * 8];
        acc[j] = __builtin_amdgcn_mfma_f32_16x16x32_bf16(af[ks], kb, acc[j], 0, 0, 0);
      }
    }
    float sv[4][4], tmax[4];
    #pragma unroll
    for (int r = 0; r < 4; r++) tmax[r] = -3.4e38f;
    #pragma unroll
    for (int j = 0; j < 4; j++)
      #pragma unroll
      for (int r = 0; r < 4; r++) {
        float x = acc[j][r] * scale;
        sv[j][r] = x;
        tmax[r] = fmaxf(tmax[r], x);
      }
    #pragma unroll
    for (int off = 1; off < 16; off <<= 1)
      #pragma unroll
      for (int r = 0; r < 4; r++) tmax[r] = fmaxf(tmax[r], __shfl_xor(tmax[r], off));
    float alpha[4], rsum[4];
    #pragma unroll
    for (int r = 0; r < 4; r++) {
      float mn = fmaxf(mr[r], tmax[r]);
      alpha[r] = expf(mr[r] - mn);
      mr[r] = mn;
      rsum[r] = 0.f;
    }
    #pragma unroll
    for (int j = 0; j < 4; j++)
      #pragma unroll
      for (int r = 0; r < 4; r++) {
        float p = expf(sv[j][r] - mr[r]);
        sv[j][r] = p;
        rsum[r] += p;
      }
    #pragma unroll
    for (int off = 1; off < 16; off <<= 1)
      #pragma unroll
      for (int r = 0; r < 4; r++) rsum[r] += __shfl_xor(rsum[r], off);
    #pragma unroll
    for (int r = 0; r < 4; r++) lr[r] = lr[r] * alpha[r] + rsum[r];
    #pragma unroll
    for (int j = 0; j < 4; j++)
      #pragma unroll
      for (int r = 0; r < 4; r++)
        Ps[wave][quad * 4 + r][j * 16 + l16] = f2b(sv[j][r]);
    #pragma unroll
    for (int jj = 0; jj < 8; jj++)
      #pragma unroll
      for (int r = 0; r < 4; r++) Oacc[jj][r] *= alpha[r];
    __syncthreads();
    #pragma unroll
    for (int s = 0; s < 2; s++) {
      bf16x8 pa = *(const bf16x8*)&Ps[wave][l16][s * 32 + quad * 8];
      #pragma unroll
      for (int jj = 0; jj < 8; jj++) {
        bf16x8 vb = *(const bf16x8*)&Vt[jj * 16 + l16][s * 32 + quad * 8];
        Oacc[jj] = __builtin_amdgcn_mfma_f32_16x16x32_bf16(pa, vb, Oacc[jj], 0, 0, 0);
      }
    }
  }
  long row0 = (long)b * 1024 + qt * 64 + wave * 16 + quad * 4;
  #pragma unroll
  for (int jj = 0; jj < 8; jj++) {
    int col = h * 128 + jj * 16 + l16;
    #pragma unroll
    for (int r = 0; r < 4; r++)
      O[(row0 + r) * 256 + col] = f2b(Oacc[jj][r] / lr[r]);
  }
}

// ---------- split-K pooling attention ----------
__global__ __launch_bounds__(128) void pool_split(
    const float* __restrict__ qe, const float* __restrict__ pinW, const float* __restrict__ pinB,
    const float* __restrict__ srand, const ushort* __restrict__ KV,
    float* __restrict__ PM, float* __restrict__ PL, float* __restrict__ PO)
{
  int cid = blockIdx.x;
  int id = blockIdx.y;
  int h = id & 1, nq = (id >> 1) & 3, b = id >> 3;
  int tid = threadIdx.x;
  __shared__ float qs[128];
  __shared__ float eg[128];
  __shared__ float red[128];
  {
    float a = pinB[h * 128 + tid];
    const float* wr = pinW + ((long)(h * 128 + tid)) * 256;
    const float* qr = qe + nq * 256;
    for (int i = 0; i < 256; i++) a += qr[i] * wr[i];
    qs[tid] = a;
  }
  __syncthreads();
  const float scale = 0.08838834764831845f;
  int s = cid * 128 + tid;
  float d = 0.f;
  {
    const ushort* kr = KV + ((long)((b << 10) + s)) * 512 + h * 128;
    #pragma unroll
    for (int c8 = 0; c8 < 128; c8 += 8) {
      uint4 kv4 = *(const uint4*)(kr + c8);
      const ushort* kp = (const ushort*)&kv4;
      #pragma unroll
      for (int j = 0; j < 8; j++) d += qs[c8 + j] * b2f(kp[j]);
    }
  }
  float lg = d * scale + ((srand[nq * 1024 + s] < 0.3f) ? 0.f : -1e9f);
  red[tid] = lg; __syncthreads();
  for (int off = 64; off > 0; off >>= 1) { if (tid < off) red[tid] = fmaxf(red[tid], red[tid + off]); __syncthreads(); }
  float m = red[0]; __syncthreads();
  float e = expf(lg - m);
  eg[tid] = e;
  red[tid] = e; __syncthreads();
  for (int off = 64; off > 0; off >>= 1) { if (tid < off) red[tid] += red[tid + off]; __syncthreads(); }
  float l = red[0];
  __syncthreads();
  float o = 0.f;
  const ushort* vbase = KV + ((long)((b << 10) + cid * 128)) * 512 + 256 + h * 128 + tid;
  for (int ss = 0; ss < 128; ss++)
    o += eg[ss] * b2f(vbase[(long)ss * 512]);
  int part = id * 8 + cid;
  PO[(long)part * 128 + tid] = o;
  if (tid == 0) { PM[part] = m; PL[part] = l; }
}

__global__ __launch_bounds__(128) void pool_merge(
    const float* __restrict__ PM, const float* __restrict__ PL, const float* __restrict__ PO,
    float* __restrict__ ATTP)
{
  int id = blockIdx.x;
  int h = id & 1, nq = (id >> 1) & 3, b = id >> 3;
  int tid = threadIdx.x;
  float m = -3.4e38f;
  #pragma unroll
  for (int c = 0; c < 8; c++) m = fmaxf(m, PM[id * 8 + c]);
  float l = 0.f, o = 0.f;
  #pragma unroll
  for (int c = 0; c < 8; c++) {
    float w = expf(PM[id * 8 + c] - m);
    l += PL[id * 8 + c] * w;
    o += PO[(long)(id * 8 + c) * 128 + tid] * w;
  }
  ATTP[(b * 4 + nq) * 256 + h * 128 + tid] = o / l;
}

// ---------- column-mean partials ----------
__global__ __launch_bounds__(256) void col_mean_part(const float* __restrict__ X,
                                                     float* __restrict__ PSUM)
{
  int blk = blockIdx.x;
  int b = blk >> 4, ch = blk & 15;
  int d = threadIdx.x;
  float s = 0.f;
  int n0 = ch * 64;
  const float* xr = X + ((long)((b << 10) + n0)) * 256 + d;
  #pragma unroll 4
  for (int n = 0; n < 64; n++) s += xr[(long)n * 256];
  PSUM[(long)blk * 256 + d] = s;
}

__global__ __launch_bounds__(256) void combined_merge(const float* __restrict__ PSUM,
    const float* __restrict__ ATTO, float* __restrict__ CMB)
{
  int b = blockIdx.x, d = threadIdx.x;
  float s = 0.f;
  #pragma unroll
  for (int ch = 0; ch < 16; ch++) s += PSUM[(long)(b * 16 + ch) * 256 + d];
  CMB[b * 1280 + d] = s * (1.f / 1024.f);
  #pragma unroll
  for (int q = 0; q < 4; q++)
    CMB[b * 1280 + 256 + q * 256 + d] = ATTO[(b * 4 + q) * 256 + d];
}

__global__ void store_out(const float* __restrict__ src, float* __restrict__ dst, int n) {
  int i = blockIdx.x * blockDim.x + threadIdx.x;
  if (i < n) dst[i] = src[i];
}
__global__ void fill_out_zero(float* __restrict__ dst, int n) {
  int i = blockIdx.x * blockDim.x + threadIdx.x;
  if (i < n) dst[i] = 0.f;
}

extern "C" void kernel_launch(void* const* d_in, const int* in_sizes, int n_in,
                              void* d_out, int out_size, void* d_ws, size_t ws_size,
                              hipStream_t stream)
{
  const float* inp      = (const float*)d_in[0];
  const float* cellp    = (const float*)d_in[1];
  const float* srand    = (const float*)d_in[2];
  const float* emb_W    = (const float*)d_in[3];
  const float* emb_b    = (const float*)d_in[4];
  const float* pe_tab   = (const float*)d_in[5];
  const float* pe_W1    = (const float*)d_in[6];
  const float* pe_b1    = (const float*)d_in[7];
  const float* pe_W2    = (const float*)d_in[8];
  const float* pe_b2    = (const float*)d_in[9];
  const float* gat_W    = (const float*)d_in[10];
  const float* gat_asrc = (const float*)d_in[11];
  const float* gat_adst = (const float*)d_in[12];
  const float* gat_b    = (const float*)d_in[13];
  const float* ln_g     = (const float*)d_in[14];
  const float* ln_b     = (const float*)d_in[15];
  const float* qkv_W    = (const float*)d_in[16];
  const float* qkv_b    = (const float*)d_in[17];
  const float* out_W    = (const float*)d_in[18];
  const float* out_b    = (const float*)d_in[19];
  const float* ff1_W    = (const float*)d_in[20];
  const float* ff1_b    = (const float*)d_in[21];
  const float* ff2_W    = (const float*)d_in[22];
  const float* ff2_b    = (const float*)d_in[23];
  const float* ln1_g    = (const float*)d_in[24];
  const float* ln1_b    = (const float*)d_in[25];
  const float* ln2_g    = (const float*)d_in[26];
  const float* ln2_b    = (const float*)d_in[27];
  const float* q_emb    = (const float*)d_in[28];
  const float* pin_W    = (const float*)d_in[29];
  const float* pin_b    = (const float*)d_in[30];
  const float* pout_W   = (const float*)d_in[31];
  const float* pout_b   = (const float*)d_in[32];
  const float* m1_W     = (const float*)d_in[33];
  const float* m1_b     = (const float*)d_in[34];
  const float* mln1_g   = (const float*)d_in[35];
  const float* mln1_b   = (const float*)d_in[36];
  const float* m2_W     = (const float*)d_in[37];
  const float* m2_b     = (const float*)d_in[38];
  const float* mln2_g   = (const float*)d_in[39];
  const float* mln2_b   = (const float*)d_in[40];
  const float* m3_W     = (const float*)d_in[41];
  const float* m3_b     = (const float*)d_in[42];
  const float* c1_W     = (const float*)d_in[43];
  const float* c1_b     = (const float*)d_in[44];
  const float* c2_W     = (const float*)d_in[45];
  const float* c2_b     = (const float*)d_in[46];
  const float* c3_W     = (const float*)d_in[47];
  const float* c3_b     = (const float*)d_in[48];
  const float* c4_W     = (const float*)d_in[49];
  const float* c4_b     = (const float*)d_in[50];
  (void)in_sizes; (void)n_in;

  // ---- workspace (bytes, 256-aligned; ~20.6 MB) ----
  char* base = (char*)d_ws;
  size_t off = 0;
  auto alloc = [&](size_t bytes) { void* p = base + off; off += (bytes + 255) & ~size_t(255); return p; };
  float* PN    = (float*)alloc(32768);
  float* AS    = (float*)alloc(32768);
  float* AD    = (float*)alloc(32768);
  float* ATTP  = (float*)alloc(16384);
  float* ATTO  = (float*)alloc(16384);
  float* CMB   = (float*)alloc(20480);
  float* Ha    = (float*)alloc(16384);
  float* Hb    = (float*)alloc(16384);
  float* Hc    = (float*)alloc(16640);
  float* Hd    = (float*)alloc(8192);
  float* He    = (float*)alloc(4096);
  float* Hf    = (float*)alloc(512);
  float* Pk    = (float*)alloc(262144);
  float* PPM   = (float*)alloc(1024);
  float* PPL   = (float*)alloc(1024);
  float* PPO   = (float*)alloc(131072);
  float* PSUM  = (float*)alloc(65536);
  int*   NBR   = (int*)alloc(131072);
  float* X     = (float*)alloc(4194304);
  ushort* Xb   = (ushort*)alloc(2097152);
  char*  Rq    = (char*)alloc(6291456);
  char*  Rf    = (char*)alloc(4194304);
  ushort* QKVb = (ushort*)Rq;
  float*  F2   = (float*)Rq;
  ushort* KVb  = (ushort*)Rq;
  ushort* Ob   = (ushort*)Rf;
  ushort* VT   = (ushort*)(Rf + 2097152);
  ushort* FFBb = (ushort*)Rf;
  float*  F1   = (float*)alloc(4194304);
  if (ws_size < off) { fill_out_zero<<<1, 128, 0, stream>>>((float*)d_out, out_size); return; }

  // ---- graph construction ----
  bag_stats<<<4, 256, 0, stream>>>(cellp, PN);
  knn_kernel<<<512, 256, 0, stream>>>(PN, NBR);

  // ---- embedding + positional MLP (MFMA) ----
  mgemm<float>(stream, inp, 512, emb_W, 512, emb_b, X, 256, 4096, 256, 512, 0);
  pos_mlp<<<dim3(64, 2), 256, 0, stream>>>(cellp, pe_tab, pe_W1, pe_b1, pe_W2, pe_b2, X);
  cvt_f2b<<<1024, 256, 0, stream>>>(X, Xb, 4096 * 256);

  // ---- 2x GAT ----
  for (int l = 0; l < 2; l++) {
    mgemm<float>(stream, Xb, 256, gat_W + l * 65536, 256, (const float*)nullptr, F1, 256,
                 4096, 256, 256, 0);
    gat_scores<<<4096, 256, 0, stream>>>(F1, gat_asrc + l * 256, gat_adst + l * 256, AS, AD);
    gat_aggr_ln<<<4096, 256, 0, stream>>>(F1, AS, AD, NBR, gat_b + l * 256, ln_g, ln_b, X, Xb);
  }

  // ---- 2x Transformer encoder layer ----
  for (int l = 0; l < 2; l++) {
    mgemm_vt(stream, Xb, 256, qkv_W + (long)l * 768 * 256, 256, qkv_b + l * 768,
             QKVb, 768, 4096, 768, 256, VT);
    flash_mfma<<<256, 256, 0, stream>>>(QKVb, VT, Ob);
    mgemm<float>(stream, Ob, 256, out_W + l * 65536, 256, out_b + l * 256, F2, 256,
                 4096, 256, 256, 0);
    add_ln4<<<1024, 256, 0, stream>>>(X, F2, ln1_g + l * 256, ln1_b + l * 256, X, Xb);
    for (int ch = 0; ch < 2; ch++) {
      mgemm<ushort>(stream, Xb + (long)ch * 2048 * 256, 256, ff1_W + l * 262144, 256,
                    ff1_b + l * 1024, FFBb, 1024, 2048, 1024, 256, 1);
      mgemm<float>(stream, FFBb, 1024, ff2_W + l * 262144, 1024, ff2_b + l * 256,
                   F2 + (long)ch * 2048 * 256, 256, 2048, 256, 1024, 0);
    }
    add_ln4<<<1024, 256, 0, stream>>>(X, F2, ln2_g + l * 256, ln2_b + l * 256, X, Xb);
  }

  // ---- final LN ----
  add_ln4<<<1024, 256, 0, stream>>>((const float*)nullptr, X, ln_g, ln_b, X, Xb);

  // ---- pooling (split-K flash-decode style) ----
  mgemm<ushort>(stream, Xb, 256, pin_W + 65536, 256, pin_b + 256, KVb, 512, 4096, 512, 256, 0);
  pool_split<<<dim3(8, 32), 128, 0, stream>>>(q_emb, pin_W, pin_b, srand, KVb, PPM, PPL, PPO);
  pool_merge<<<32, 128, 0, stream>>>(PPM, PPL, PPO, ATTP);
  sgemm<16>(stream, ATTP, 256, pout_W, 256, pout_b, ATTO, Pk, 256, 2, 0);
  col_mean_part<<<64, 256, 0, stream>>>(X, PSUM);
  combined_merge<<<4, 256, 0, stream>>>(PSUM, ATTO, CMB);

  // ---- MLP head (fp32, split-K skinny GEMMs) ----
  sgemm<4>(stream, CMB, 1280, m1_W, 1280, m1_b, Ha, Pk, 1024, 8, 1);
  add_ln_big<<<4, 256, 0, stream>>>(Ha, mln1_g, mln1_b, Ha);
  sgemm<4>(stream, Ha, 1024, m2_W, 1024, m2_b, Hb, Pk, 1024, 8, 1);
  add_ln_big<<<4, 256, 0, stream>>>(Hb, mln2_g, mln2_b, Hb);
  sgemm<4>(stream, Hb, 1024, m3_W, 1024, m3_b, Ha, Pk, 1024, 8, 0);
  sgemm<4>(stream, Ha, 1024, c1_W, 1024, c1_b, Hc, Pk, 1032, 8, 1);
  sgemm<4>(stream, Hc, 1032, c2_W, 1032, c2_b, Hd, Pk, 512, 8, 1);
  sgemm<4>(stream, Hd, 512, c3_W, 512, c3_b, He, Pk, 256, 4, 1);
  sgemm<4>(stream, He, 256, c4_W, 256, c4_b, Hf, Pk, 24, 2, 0);
  store_out<<<1, 128, 0, stream>>>(Hf, (float*)d_out, out_size);
}